// Round 2
// baseline (807.103 us; speedup 1.0000x reference)
//
#include <hip/hip_runtime.h>

typedef unsigned int u32;

#define H    128
#define C    16
#define ODIM 128

// ---------------- init ----------------
__global__ __launch_bounds__(256) void k_zero(int4* p, int n4){
  int i = blockIdx.x*256 + threadIdx.x;
  if (i < n4) p[i] = make_int4(0,0,0,0);
}

__global__ __launch_bounds__(256) void k_embed(const float* __restrict__ emb,
    const int* __restrict__ deg, float* __restrict__ x, int N){
  int i = blockIdx.x*256 + threadIdx.x;
  if (i >= N*32) return;               // one float4 per thread
  int n = i >> 5, q = i & 31;
  int d = deg[n];
  ((float4*)(x + (size_t)n*H))[q] = ((const float4*)(emb + (size_t)d*H))[q];
}

// graph start offsets from sorted batch
__global__ __launch_bounds__(256) void k_bounds(const int* __restrict__ batch,
    int* __restrict__ gs, int N, int B){
  int n = blockIdx.x*256 + threadIdx.x;
  if (n >= N) return;
  int b = batch[n];
  if (n == 0){ for (int g = 0; g <= b; g++) gs[g] = 0; }
  else {
    int pb = batch[n-1];
    for (int g = pb+1; g <= b; g++) gs[g] = n;
  }
  if (n == N-1){ for (int g = b+1; g <= B; g++) gs[g] = N; }
}

// ---------------- CSR build ----------------
__global__ __launch_bounds__(256) void k_count(const int* __restrict__ ei,
    int* __restrict__ cnt, int E){
  int e = blockIdx.x*256 + threadIdx.x;
  if (e < E) atomicAdd(&cnt[ei[E + e]], 1);
}

__global__ __launch_bounds__(256) void k_scanA(const int* __restrict__ cnt,
    int* __restrict__ rowptr, int* __restrict__ bsum, int N){
  __shared__ int wsum[4];
  int tid = threadIdx.x;
  int base = blockIdx.x*1024 + tid*4;
  int v0 = (base+0 < N) ? cnt[base+0] : 0;
  int v1 = (base+1 < N) ? cnt[base+1] : 0;
  int v2 = (base+2 < N) ? cnt[base+2] : 0;
  int v3 = (base+3 < N) ? cnt[base+3] : 0;
  int tsum = v0+v1+v2+v3;
  int lane = tid & 63, w = tid >> 6;
  int incl = tsum;
  for (int d = 1; d < 64; d <<= 1){
    int t = __shfl_up(incl, d, 64);
    if (lane >= d) incl += t;
  }
  if (lane == 63) wsum[w] = incl;
  __syncthreads();
  int woff = 0;
  for (int i = 0; i < w; i++) woff += wsum[i];
  int excl = woff + incl - tsum;
  if (base+0 < N) rowptr[base+0] = excl;
  if (base+1 < N) rowptr[base+1] = excl + v0;
  if (base+2 < N) rowptr[base+2] = excl + v0 + v1;
  if (base+3 < N) rowptr[base+3] = excl + v0 + v1 + v2;
  if (tid == 255) bsum[blockIdx.x] = woff + incl;
}

__global__ __launch_bounds__(64) void k_scanB(const int* __restrict__ bsum,
    int* __restrict__ boff, int nb){
  int tid = threadIdx.x;
  int v = (tid < nb) ? bsum[tid] : 0;
  int incl = v;
  for (int d = 1; d < 64; d <<= 1){
    int t = __shfl_up(incl, d, 64);
    if (tid >= d) incl += t;
  }
  boff[tid] = incl - v;
}

__global__ __launch_bounds__(256) void k_scanC(const int* __restrict__ cnt,
    int* __restrict__ rowptr, int* __restrict__ rowfill,
    const int* __restrict__ boff, int N){
  int i = blockIdx.x*256 + threadIdx.x;
  if (i < N){
    int r = rowptr[i] + boff[i >> 10];
    rowptr[i] = r;
    rowfill[i] = r;
    if (i == N-1) rowptr[N] = r + cnt[i];
  }
}

__global__ __launch_bounds__(256) void k_scatter(const int* __restrict__ ei,
    int* __restrict__ rowfill, int* __restrict__ col, int E){
  int e = blockIdx.x*256 + threadIdx.x;
  if (e >= E) return;
  int s = ei[e], d = ei[E + e];
  int p = atomicAdd(&rowfill[d], 1);
  col[p] = s;
}

// ---------------- per-layer ----------------
// wave per node: lane holds feature pair (2*lane, 2*lane+1)
__global__ __launch_bounds__(256) void k_agg(const float* __restrict__ x,
    const int* __restrict__ rowptr, const int* __restrict__ col,
    float* __restrict__ mean, int N){
  int wid  = (blockIdx.x*256 + threadIdx.x) >> 6;
  int lane = threadIdx.x & 63;
  if (wid >= N) return;
  int r0 = rowptr[wid], r1 = rowptr[wid+1];
  float ax = 0.f, ay = 0.f;
  for (int e = r0; e < r1; e++){
    int s = col[e];
    float2 v = *(const float2*)(x + (size_t)s*H + lane*2);
    ax += v.x; ay += v.y;
  }
  float invc = 1.0f / (float)max(r1 - r0, 1);
  float2 o; o.x = ax*invc; o.y = ay*invc;
  *(float2*)(mean + (size_t)wid*H + lane*2) = o;
}

// x2[n][h] = bl[h] + sum_k mean[n][k]*Wl[k][h] + sum_k x[n][k]*Wr[k][h]
// 64-node tile, K-major f32 LDS (broadcast ds_read_b128 reads).
// NOTE: x2 may alias mean — all global reads of this block's mean rows happen
// before __syncthreads(); writes only touch the block's own rows.
__global__ __launch_bounds__(256) void k_linear(const float* __restrict__ mean,
    const float* __restrict__ x, const float* __restrict__ Wl,
    const float* __restrict__ bl, const float* __restrict__ Wr,
    float* __restrict__ x2, int N){
  __shared__ float xmT[256][64];       // 64 KB: k 0..127 = mean, 128..255 = x
  int tid = threadIdx.x;
  int n0 = blockIdx.x * 64;
  #pragma unroll
  for (int j = 0; j < 16; j++){
    int u = tid + j*256;               // 0..4095
    int row = u & 63, seg = u >> 6;    // seg 0..63
    int node = n0 + row;
    float4 v = make_float4(0.f,0.f,0.f,0.f);
    int k;
    if (seg < 32){                     // mean
      if (node < N) v = ((const float4*)(mean + (size_t)node*H))[seg];
      k = seg*4;
    } else {                           // x
      if (node < N) v = ((const float4*)(x + (size_t)node*H))[seg-32];
      k = 128 + (seg-32)*4;
    }
    xmT[k+0][row]=v.x; xmT[k+1][row]=v.y; xmT[k+2][row]=v.z; xmT[k+3][row]=v.w;
  }
  __syncthreads();
  int h0 = tid & 63, sub = tid >> 6;
  int nb = sub * 16;
  float b0 = bl[h0], b1 = bl[h0 + 64];
  float acc0[16], acc1[16];
  #pragma unroll
  for (int j = 0; j < 16; j++){ acc0[j] = b0; acc1[j] = b1; }
  for (int half = 0; half < 2; half++){
    const float* W = half ? Wr : Wl;
    int kb = half * 128;
    #pragma unroll 4
    for (int k = 0; k < 128; k++){
      float w0 = W[k*H + h0];
      float w1 = W[k*H + h0 + 64];
      const float4* p = (const float4*)&xmT[kb + k][nb];
      float4 a = p[0], b = p[1], c2 = p[2], d = p[3];
      float xv[16] = {a.x,a.y,a.z,a.w, b.x,b.y,b.z,b.w,
                      c2.x,c2.y,c2.z,c2.w, d.x,d.y,d.z,d.w};
      #pragma unroll
      for (int j = 0; j < 16; j++){
        acc0[j] = fmaf(xv[j], w0, acc0[j]);
        acc1[j] = fmaf(xv[j], w1, acc1[j]);
      }
    }
  }
  #pragma unroll
  for (int j = 0; j < 16; j++){
    int node = n0 + nb + j;
    if (node < N){
      x2[(size_t)node*H + h0]      = acc0[j];
      x2[(size_t)node*H + h0 + 64] = acc1[j];
    }
  }
}

__global__ __launch_bounds__(256) void k_bnstats(const float* __restrict__ x2,
    float* __restrict__ stats, int N){
  __shared__ float S[H], Q[H];
  int h = threadIdx.x & 127, sub = threadIdx.x >> 7;
  float s = 0.f, q = 0.f;
  for (int n = blockIdx.x*2 + sub; n < N; n += gridDim.x*2){
    float v = x2[(size_t)n*H + h];
    s += v; q = fmaf(v, v, q);
  }
  if (sub == 1){ S[h] = s; Q[h] = q; }
  __syncthreads();
  if (sub == 0){
    atomicAdd(&stats[h],     s + S[h]);
    atomicAdd(&stats[H + h], q + Q[h]);
  }
}

__global__ __launch_bounds__(256) void k_bnrelu(const float* __restrict__ x2,
    const float* __restrict__ stats, const float* __restrict__ gamma,
    const float* __restrict__ beta, float* __restrict__ x, int N, float invN){
  int i = blockIdx.x*256 + threadIdx.x;
  if (i >= N*32) return;               // 4 elems per thread
  int h = (i & 31) * 4;
  float4 v = ((const float4*)x2)[i];
  float vv[4] = {v.x, v.y, v.z, v.w};
  float r[4];
  #pragma unroll
  for (int j = 0; j < 4; j++){
    float mu  = stats[h+j] * invN;
    float var = fmaf(-mu, mu, stats[H + h + j] * invN);
    float sc  = rsqrtf(var + 1e-5f) * gamma[h+j];
    float bi  = beta[h+j];
    r[j] = fmaxf(fmaf(vv[j] - mu, sc, bi), 0.0f);
  }
  ((float4*)x)[i] = make_float4(r[0], r[1], r[2], r[3]);
}

// ---------------- attention pooling ----------------
// escore[n][c] = exp(x[n]·attn_W[:,c] + attn_b[c])   (softmax shift skipped:
// scores are O(+-1), shift-invariant)
__global__ __launch_bounds__(256) void k_scores(const float* __restrict__ x,
    const float* __restrict__ attn_W, const float* __restrict__ attn_b,
    float* __restrict__ escore, int N){
  __shared__ float xs[64][133];
  __shared__ float aw[H*C];
  int tid = threadIdx.x;
  int n0 = blockIdx.x * 64;
  #pragma unroll
  for (int j = 0; j < 8; j++){
    int u = tid + j*256;
    aw[u] = attn_W[u];
  }
  #pragma unroll
  for (int j = 0; j < 8; j++){
    int u = tid + j*256;               // 0..2047
    int row = u & 63, seg = u >> 6;    // 32 float4 per row
    int node = n0 + row;
    float4 v = make_float4(0.f,0.f,0.f,0.f);
    if (node < N) v = ((const float4*)(x + (size_t)node*H))[seg];
    int k = seg*4;
    xs[row][k+0]=v.x; xs[row][k+1]=v.y; xs[row][k+2]=v.z; xs[row][k+3]=v.w;
  }
  __syncthreads();
  int c = tid & 15, sub = tid >> 4;
  float bias = attn_b[c];
  float acc[4] = {bias, bias, bias, bias};
  for (int k = 0; k < H; k++){
    float w = aw[k*C + c];
    acc[0] = fmaf(xs[sub     ][k], w, acc[0]);
    acc[1] = fmaf(xs[sub + 16][k], w, acc[1]);
    acc[2] = fmaf(xs[sub + 32][k], w, acc[2]);
    acc[3] = fmaf(xs[sub + 48][k], w, acc[3]);
  }
  #pragma unroll
  for (int j = 0; j < 4; j++){
    int node = n0 + sub + 16*j;
    if (node < N) escore[(size_t)node*C + c] = __expf(acc[j]);
  }
}

__global__ __launch_bounds__(256) void k_denom(const float* __restrict__ escore,
    const int* __restrict__ gs, float* __restrict__ gsum){
  int g = blockIdx.x;
  int c = threadIdx.x & 15, sub = threadIdx.x >> 4;
  int a = gs[g], b = gs[g+1];
  float s = 0.f;
  for (int n = a + sub; n < b; n += 16) s += escore[(size_t)n*C + c];
  __shared__ float part[16][17];
  part[sub][c] = s;
  for (int off2 = 8; off2 > 0; off2 >>= 1){
    __syncthreads();
    if (sub < off2) part[sub][c] += part[sub + off2][c];
  }
  __syncthreads();
  if (threadIdx.x < C) gsum[(size_t)g*C + threadIdx.x] = part[0][threadIdx.x];
}

// clustsum[g][c][h] = sum_n escore[n][c] * x[n][h]   (divide by denom in k_out)
__global__ __launch_bounds__(256) void k_clust(const float* __restrict__ x,
    const float* __restrict__ escore, const int* __restrict__ gs,
    float* __restrict__ clustsum){
  int g = blockIdx.x >> 4, b = blockIdx.x & 15;
  int h = threadIdx.x & 127, cg = threadIdx.x >> 7;
  int a = gs[g], e2 = gs[g+1];
  float acc[8] = {0,0,0,0,0,0,0,0};
  for (int n = a + b; n < e2; n += 16){
    float xv = x[(size_t)n*H + h];
    const float4* ep = (const float4*)(escore + (size_t)n*C) + cg*2;
    float4 e0 = ep[0], e1 = ep[1];
    acc[0] = fmaf(e0.x, xv, acc[0]);
    acc[1] = fmaf(e0.y, xv, acc[1]);
    acc[2] = fmaf(e0.z, xv, acc[2]);
    acc[3] = fmaf(e0.w, xv, acc[3]);
    acc[4] = fmaf(e1.x, xv, acc[4]);
    acc[5] = fmaf(e1.y, xv, acc[5]);
    acc[6] = fmaf(e1.z, xv, acc[6]);
    acc[7] = fmaf(e1.w, xv, acc[7]);
  }
  int c0 = cg*8;
  #pragma unroll
  for (int r = 0; r < 8; r++)
    atomicAdd(&clustsum[((size_t)(g*C + c0 + r))*H + h], acc[r]);
}

__global__ __launch_bounds__(256) void k_out(const float* __restrict__ clustsum,
    const float* __restrict__ gsum, const float* __restrict__ out_W,
    const float* __restrict__ out_b, float* __restrict__ out){
  int o = threadIdx.x & 127, r = threadIdx.x >> 7;
  int row = blockIdx.x*2 + r;          // (g,c) flat
  float gden = gsum[row];
  float inv = gden > 0.f ? 1.0f / gden : 0.f;
  const float* cs = clustsum + (size_t)row*H;
  float acc = 0.f;
  for (int hh = 0; hh < H; hh++)
    acc = fmaf(cs[hh], out_W[hh*ODIM + o], acc);
  out[(size_t)row*ODIM + o] = fmaf(acc, inv, out_b[o]);
}

// ---------------- host ----------------
extern "C" void kernel_launch(void* const* d_in, const int* in_sizes, int n_in,
                              void* d_out, int out_size, void* d_ws, size_t ws_size,
                              hipStream_t stream){
  const float* emb    = (const float*)d_in[0];
  const float* Wl     = (const float*)d_in[1];
  const float* bl     = (const float*)d_in[2];
  const float* Wr     = (const float*)d_in[3];
  const float* gamma  = (const float*)d_in[4];
  const float* beta   = (const float*)d_in[5];
  const float* attn_W = (const float*)d_in[6];
  const float* attn_b = (const float*)d_in[7];
  const float* out_W  = (const float*)d_in[8];
  const float* out_b  = (const float*)d_in[9];
  const int* deg    = (const int*)d_in[10];
  const int* ei     = (const int*)d_in[11];
  const int* batch  = (const int*)d_in[12];
  float* out = (float*)d_out;

  const int N = in_sizes[10];
  const int E = in_sizes[11] / 2;
  const int L = in_sizes[1] / (H*H);
  const int B = out_size / (C*ODIM);

  size_t off = 0;
  auto alloc = [&](size_t bytes) -> void* {
    void* p = (char*)d_ws + off;
    off += (bytes + 255) & ~(size_t)255;
    return p;
  };
  float* x      = (float*)alloc((size_t)N*H*4);
  float* mean   = (float*)alloc((size_t)N*H*4);   // x2 aliases mean
  float* x2     = mean;
  float* escore = (float*)alloc((size_t)N*C*4);
  int*   col    = (int*)  alloc((size_t)E*4);
  int*   rowptr = (int*)  alloc((size_t)(N+1)*4);
  int*   bsum   = (int*)  alloc(64*4);
  int*   boff   = (int*)  alloc(64*4);
  int*   gs     = (int*)  alloc((size_t)(B+1)*4);
  float* gsum   = (float*)alloc((size_t)B*C*4);
  int*   rowfill= (int*)  alloc((size_t)N*4);
  int    Zw     = N + L*2*H + B*C*H;            // cnt | stats | clustsum (zeroed)
  int*   zbase  = (int*)  alloc((size_t)Zw*4);
  int*   cnt      = zbase;
  float* stats    = (float*)(zbase + N);
  float* clustsum = (float*)(zbase + N + L*2*H);

  int z4 = (Zw + 3) / 4;
  hipLaunchKernelGGL(k_zero,   dim3((z4+255)/256),   dim3(256), 0, stream, (int4*)zbase, z4);
  hipLaunchKernelGGL(k_embed,  dim3((N*32+255)/256), dim3(256), 0, stream, emb, deg, x, N);
  hipLaunchKernelGGL(k_bounds, dim3((N+255)/256),    dim3(256), 0, stream, batch, gs, N, B);
  hipLaunchKernelGGL(k_count,  dim3((E+255)/256),    dim3(256), 0, stream, ei, cnt, E);
  int nblk = (N + 1023)/1024;
  hipLaunchKernelGGL(k_scanA,  dim3(nblk), dim3(256), 0, stream, cnt, rowptr, bsum, N);
  hipLaunchKernelGGL(k_scanB,  dim3(1),    dim3(64),  0, stream, bsum, boff, nblk);
  hipLaunchKernelGGL(k_scanC,  dim3((N+255)/256), dim3(256), 0, stream, cnt, rowptr, rowfill, boff, N);
  hipLaunchKernelGGL(k_scatter,dim3((E+255)/256), dim3(256), 0, stream, ei, rowfill, col, E);

  float invN = 1.0f / (float)N;
  for (int l = 0; l < L; l++){
    hipLaunchKernelGGL(k_agg,    dim3((N+3)/4),  dim3(256), 0, stream, x, rowptr, col, mean, N);
    hipLaunchKernelGGL(k_linear, dim3((N+63)/64),dim3(256), 0, stream,
                       mean, x, Wl + (size_t)l*H*H, bl + (size_t)l*H,
                       Wr + (size_t)l*H*H, x2, N);
    hipLaunchKernelGGL(k_bnstats,dim3(256),      dim3(256), 0, stream, x2, stats + l*2*H, N);
    hipLaunchKernelGGL(k_bnrelu, dim3((N*32+255)/256), dim3(256), 0, stream,
                       x2, stats + l*2*H, gamma + (size_t)l*H, beta + (size_t)l*H, x, N, invN);
  }
  hipLaunchKernelGGL(k_scores, dim3((N+63)/64), dim3(256), 0, stream, x, attn_W, attn_b, escore, N);
  hipLaunchKernelGGL(k_denom,  dim3(B),         dim3(256), 0, stream, escore, gs, gsum);
  hipLaunchKernelGGL(k_clust,  dim3(B*16),      dim3(256), 0, stream, x, escore, gs, clustsum);
  hipLaunchKernelGGL(k_out,    dim3(B*C/2),     dim3(256), 0, stream, clustsum, gsum, out_W, out_b, out);
}

// Round 3
// 586.199 us; speedup vs baseline: 1.3768x; 1.3768x over previous
//
#include <hip/hip_runtime.h>

typedef unsigned short u16;
typedef unsigned int   u32;

#define H    128
#define C    16
#define ODIM 128

typedef short bf16x8 __attribute__((ext_vector_type(8)));
typedef float f32x4  __attribute__((ext_vector_type(4)));

__device__ __forceinline__ float bf2f(u32 v){
  union { u32 i; float f; } t; t.i = v << 16; return t.f;
}
__device__ __forceinline__ u16 f2bf(float f){
  u32 u = __float_as_uint(f);
  u32 r = u + 0x7fffu + ((u >> 16) & 1u);   // RNE
  return (u16)(r >> 16);
}
__device__ __forceinline__ u32 pack2(float a, float b){
  return (u32)f2bf(a) | ((u32)f2bf(b) << 16);
}

// ---------------- init ----------------
__global__ __launch_bounds__(256) void k_zero(int4* p, int n4){
  int i = blockIdx.x*256 + threadIdx.x;
  if (i < n4) p[i] = make_int4(0,0,0,0);
}

__global__ __launch_bounds__(256) void k_embed(const float* __restrict__ emb,
    const int* __restrict__ deg, u16* __restrict__ xb, int N){
  int i = blockIdx.x*256 + threadIdx.x;
  if (i >= N*32) return;               // 4 values per thread
  int n = i >> 5, q = i & 31;
  int d = deg[n];
  float4 v = ((const float4*)(emb + (size_t)d*H))[q];
  uint2 o; o.x = pack2(v.x, v.y); o.y = pack2(v.z, v.w);
  ((uint2*)(xb + (size_t)n*H))[q] = o;
}

// graph start offsets from sorted batch
__global__ __launch_bounds__(256) void k_bounds(const int* __restrict__ batch,
    int* __restrict__ gs, int N, int B){
  int n = blockIdx.x*256 + threadIdx.x;
  if (n >= N) return;
  int b = batch[n];
  if (n == 0){ for (int g = 0; g <= b; g++) gs[g] = 0; }
  else {
    int pb = batch[n-1];
    for (int g = pb+1; g <= b; g++) gs[g] = n;
  }
  if (n == N-1){ for (int g = b+1; g <= B; g++) gs[g] = N; }
}

// W^T prep: Wt[l][h][k] bf16, k<128 = Wl[l][k][h], k>=128 = Wr[l][k-128][h]
__global__ __launch_bounds__(256) void k_wprep(const float* __restrict__ Wl,
    const float* __restrict__ Wr, u16* __restrict__ Wt){
  __shared__ u16 T[128][18];
  int b = blockIdx.x;
  int strip = b & 7, half = (b >> 3) & 1, l = b >> 4;
  const float* M = (half ? Wr : Wl) + (size_t)l*H*H;
  int k0 = strip * 16;
  int tid = threadIdx.x;
  #pragma unroll
  for (int j = 0; j < 8; j++){
    int u = tid + j*256;               // 0..2047 = 16 k x 128 h
    int kk = u >> 7, h = u & 127;
    T[h][kk] = f2bf(M[(size_t)(k0 + kk)*H + h]);
  }
  __syncthreads();
  #pragma unroll
  for (int j = 0; j < 8; j++){
    int u = tid + j*256;
    int h = u >> 4, k16 = u & 15;
    Wt[((size_t)(l*H + h))*256 + half*128 + k0 + k16] = T[h][k16];
  }
}

// ---------------- CSR build ----------------
__global__ __launch_bounds__(256) void k_count(const int* __restrict__ ei,
    int* __restrict__ cnt, int E){
  int e = blockIdx.x*256 + threadIdx.x;
  if (e < E) atomicAdd(&cnt[ei[E + e]], 1);
}

__global__ __launch_bounds__(256) void k_scanA(const int* __restrict__ cnt,
    int* __restrict__ rowptr, int* __restrict__ bsum, int N){
  __shared__ int wsum[4];
  int tid = threadIdx.x;
  int base = blockIdx.x*1024 + tid*4;
  int v0 = (base+0 < N) ? cnt[base+0] : 0;
  int v1 = (base+1 < N) ? cnt[base+1] : 0;
  int v2 = (base+2 < N) ? cnt[base+2] : 0;
  int v3 = (base+3 < N) ? cnt[base+3] : 0;
  int tsum = v0+v1+v2+v3;
  int lane = tid & 63, w = tid >> 6;
  int incl = tsum;
  for (int d = 1; d < 64; d <<= 1){
    int t = __shfl_up(incl, d, 64);
    if (lane >= d) incl += t;
  }
  if (lane == 63) wsum[w] = incl;
  __syncthreads();
  int woff = 0;
  for (int i = 0; i < w; i++) woff += wsum[i];
  int excl = woff + incl - tsum;
  if (base+0 < N) rowptr[base+0] = excl;
  if (base+1 < N) rowptr[base+1] = excl + v0;
  if (base+2 < N) rowptr[base+2] = excl + v0 + v1;
  if (base+3 < N) rowptr[base+3] = excl + v0 + v1 + v2;
  if (tid == 255) bsum[blockIdx.x] = woff + incl;
}

__global__ __launch_bounds__(64) void k_scanB(const int* __restrict__ bsum,
    int* __restrict__ boff, int nb){
  int tid = threadIdx.x;
  int v = (tid < nb) ? bsum[tid] : 0;
  int incl = v;
  for (int d = 1; d < 64; d <<= 1){
    int t = __shfl_up(incl, d, 64);
    if (tid >= d) incl += t;
  }
  boff[tid] = incl - v;
}

__global__ __launch_bounds__(256) void k_scanC(const int* __restrict__ cnt,
    int* __restrict__ rowptr, int* __restrict__ rowfill,
    const int* __restrict__ boff, int N){
  int i = blockIdx.x*256 + threadIdx.x;
  if (i < N){
    int r = rowptr[i] + boff[i >> 10];
    rowptr[i] = r;
    rowfill[i] = r;
    if (i == N-1) rowptr[N] = r + cnt[i];
  }
}

__global__ __launch_bounds__(256) void k_scatter(const int* __restrict__ ei,
    int* __restrict__ rowfill, int* __restrict__ col, int E){
  int e = blockIdx.x*256 + threadIdx.x;
  if (e >= E) return;
  int s = ei[e], d = ei[E + e];
  int p = atomicAdd(&rowfill[d], 1);
  col[p] = s;
}

// ---------------- per-layer ----------------
// wave per node: lane holds bf16 feature pair (2*lane, 2*lane+1); unroll 4
__global__ __launch_bounds__(256) void k_agg(const u16* __restrict__ x,
    const int* __restrict__ rowptr, const int* __restrict__ col,
    u16* __restrict__ meanb, int N){
  int wid  = (blockIdx.x*256 + threadIdx.x) >> 6;
  int lane = threadIdx.x & 63;
  if (wid >= N) return;
  int r0 = rowptr[wid], r1 = rowptr[wid+1];
  const u16* xl = x + lane*2;
  float ax = 0.f, ay = 0.f;
  int e = r0;
  for (; e + 4 <= r1; e += 4){
    int s0 = col[e], s1 = col[e+1], s2 = col[e+2], s3 = col[e+3];
    u32 v0 = *(const u32*)(xl + (size_t)s0*H);
    u32 v1 = *(const u32*)(xl + (size_t)s1*H);
    u32 v2 = *(const u32*)(xl + (size_t)s2*H);
    u32 v3 = *(const u32*)(xl + (size_t)s3*H);
    ax += bf2f(v0 & 0xffff) + bf2f(v1 & 0xffff)
        + bf2f(v2 & 0xffff) + bf2f(v3 & 0xffff);
    ay += bf2f(v0 >> 16) + bf2f(v1 >> 16) + bf2f(v2 >> 16) + bf2f(v3 >> 16);
  }
  for (; e < r1; e++){
    u32 v = *(const u32*)(xl + (size_t)col[e]*H);
    ax += bf2f(v & 0xffff);
    ay += bf2f(v >> 16);
  }
  float invc = 1.0f / (float)max(r1 - r0, 1);
  *(u32*)(meanb + (size_t)wid*H + lane*2) = pack2(ax*invc, ay*invc);
}

// x2[n][h] = bl[h] + [meanb|xb] @ Wt^T   via mfma_f32_16x16x32_bf16.
// A (nodes) in LDS [64][256+8] bf16; B frags straight from global Wt[h][k]
// (16B per lane, quad-coalesced, L1/L2 resident).
// Layouts (verified, learn_hip m89/m91/m120): A: m=lane&15, k=quad*8+j;
// B: n=lane&15, k=quad*8+j; D: col(n)=lane&15, row(m)=quad*4+r.
__global__ __launch_bounds__(256) void k_linear(const u16* __restrict__ meanb,
    const u16* __restrict__ xb, const u16* __restrict__ Wt,
    const float* __restrict__ bl, float* __restrict__ x2, int N){
  __shared__ u16 As[64][264];          // 33.8 KB, +8 pad -> bank-balanced b128
  int tid = threadIdx.x;
  int n0 = blockIdx.x * 64;
  #pragma unroll
  for (int j = 0; j < 16; j++){
    int u = tid + j*256;               // 0..4095 (4 bf16 each)
    int seg = u & 63, row = u >> 6;
    int node = n0 + row;
    uint2 v = make_uint2(0,0);
    if (node < N){
      if (seg < 32) v = ((const uint2*)(meanb + (size_t)node*H))[seg];
      else          v = ((const uint2*)(xb   + (size_t)node*H))[seg-32];
    }
    *(uint2*)&As[row][seg*4] = v;
  }
  __syncthreads();
  int lane = tid & 63, w = tid >> 6;
  int mlane = lane & 15, quad = lane >> 4;
  const u16* arow = &As[w*16 + mlane][0];
  f32x4 acc[8];
  #pragma unroll
  for (int t = 0; t < 8; t++) acc[t] = (f32x4){0.f, 0.f, 0.f, 0.f};
  #pragma unroll
  for (int kk = 0; kk < 8; kk++){
    bf16x8 a = *(const bf16x8*)(arow + kk*32 + quad*8);
    #pragma unroll
    for (int t = 0; t < 8; t++){
      const u16* bp = Wt + ((size_t)(t*16 + mlane))*256 + kk*32 + quad*8;
      bf16x8 b = *(const bf16x8*)bp;
      acc[t] = __builtin_amdgcn_mfma_f32_16x16x32_bf16(a, b, acc[t], 0, 0, 0);
    }
  }
  #pragma unroll
  for (int t = 0; t < 8; t++){
    int h = t*16 + mlane;
    float bv = bl[h];
    #pragma unroll
    for (int r = 0; r < 4; r++){
      int node = n0 + w*16 + quad*4 + r;
      if (node < N) x2[(size_t)node*H + h] = acc[t][r] + bv;
    }
  }
}

__global__ __launch_bounds__(256) void k_bnstats(const float* __restrict__ x2,
    float* __restrict__ stats, int N){
  __shared__ float S[H], Q[H];
  int h = threadIdx.x & 127, sub = threadIdx.x >> 7;
  float s = 0.f, q = 0.f;
  for (int n = blockIdx.x*2 + sub; n < N; n += gridDim.x*2){
    float v = x2[(size_t)n*H + h];
    s += v; q = fmaf(v, v, q);
  }
  if (sub == 1){ S[h] = s; Q[h] = q; }
  __syncthreads();
  if (sub == 0){
    atomicAdd(&stats[h],     s + S[h]);
    atomicAdd(&stats[H + h], q + Q[h]);
  }
}

__global__ __launch_bounds__(256) void k_bnrelu(const float* __restrict__ x2,
    const float* __restrict__ stats, const float* __restrict__ gamma,
    const float* __restrict__ beta, u16* __restrict__ xb, int N, float invN){
  int i = blockIdx.x*256 + threadIdx.x;
  if (i >= N*32) return;               // 4 elems per thread
  int h = (i & 31) * 4;
  float4 v = ((const float4*)x2)[i];
  float vv[4] = {v.x, v.y, v.z, v.w};
  float r[4];
  #pragma unroll
  for (int j = 0; j < 4; j++){
    float mu  = stats[h+j] * invN;
    float var = fmaf(-mu, mu, stats[H + h + j] * invN);
    float sc  = rsqrtf(var + 1e-5f) * gamma[h+j];
    float bi  = beta[h+j];
    r[j] = fmaxf(fmaf(vv[j] - mu, sc, bi), 0.0f);
  }
  uint2 o; o.x = pack2(r[0], r[1]); o.y = pack2(r[2], r[3]);
  ((uint2*)xb)[i] = o;
}

// ---------------- attention pooling ----------------
__global__ __launch_bounds__(256) void k_scores(const u16* __restrict__ xb,
    const float* __restrict__ attn_W, const float* __restrict__ attn_b,
    float* __restrict__ escore, int N){
  __shared__ float xs[64][133];
  __shared__ float aw[H*C];
  int tid = threadIdx.x;
  int n0 = blockIdx.x * 64;
  #pragma unroll
  for (int j = 0; j < 8; j++){
    int u = tid + j*256;
    aw[u] = attn_W[u];
  }
  #pragma unroll
  for (int j = 0; j < 4; j++){
    int u = tid + j*256;               // 0..1023
    int row = u & 63, seg = u >> 6;    // 16 x (8 bf16) per row
    int node = n0 + row;
    uint4 rv = make_uint4(0,0,0,0);
    if (node < N) rv = ((const uint4*)(xb + (size_t)node*H))[seg];
    int k = seg*8;
    xs[row][k+0]=bf2f(rv.x&0xffff); xs[row][k+1]=bf2f(rv.x>>16);
    xs[row][k+2]=bf2f(rv.y&0xffff); xs[row][k+3]=bf2f(rv.y>>16);
    xs[row][k+4]=bf2f(rv.z&0xffff); xs[row][k+5]=bf2f(rv.z>>16);
    xs[row][k+6]=bf2f(rv.w&0xffff); xs[row][k+7]=bf2f(rv.w>>16);
  }
  __syncthreads();
  int c = tid & 15, sub = tid >> 4;
  float bias = attn_b[c];
  float acc[4] = {bias, bias, bias, bias};
  for (int k = 0; k < H; k++){
    float w = aw[k*C + c];
    acc[0] = fmaf(xs[sub     ][k], w, acc[0]);
    acc[1] = fmaf(xs[sub + 16][k], w, acc[1]);
    acc[2] = fmaf(xs[sub + 32][k], w, acc[2]);
    acc[3] = fmaf(xs[sub + 48][k], w, acc[3]);
  }
  #pragma unroll
  for (int j = 0; j < 4; j++){
    int node = n0 + sub + 16*j;
    if (node < N) escore[(size_t)node*C + c] = __expf(acc[j]);
  }
}

__global__ __launch_bounds__(256) void k_denom(const float* __restrict__ escore,
    const int* __restrict__ gs, float* __restrict__ gsum){
  int g = blockIdx.x;
  int c = threadIdx.x & 15, sub = threadIdx.x >> 4;
  int a = gs[g], b = gs[g+1];
  float s = 0.f;
  for (int n = a + sub; n < b; n += 16) s += escore[(size_t)n*C + c];
  __shared__ float part[16][17];
  part[sub][c] = s;
  for (int off2 = 8; off2 > 0; off2 >>= 1){
    __syncthreads();
    if (sub < off2) part[sub][c] += part[sub + off2][c];
  }
  __syncthreads();
  if (threadIdx.x < C) gsum[(size_t)g*C + threadIdx.x] = part[0][threadIdx.x];
}

__global__ __launch_bounds__(256) void k_clust(const u16* __restrict__ xb,
    const float* __restrict__ escore, const int* __restrict__ gs,
    float* __restrict__ clustsum){
  int g = blockIdx.x >> 4, b = blockIdx.x & 15;
  int h = threadIdx.x & 127, cg = threadIdx.x >> 7;
  int a = gs[g], e2 = gs[g+1];
  float acc[8] = {0,0,0,0,0,0,0,0};
  for (int n = a + b; n < e2; n += 16){
    float xv = bf2f(xb[(size_t)n*H + h]);
    const float4* ep = (const float4*)(escore + (size_t)n*C) + cg*2;
    float4 e0 = ep[0], e1 = ep[1];
    acc[0] = fmaf(e0.x, xv, acc[0]);
    acc[1] = fmaf(e0.y, xv, acc[1]);
    acc[2] = fmaf(e0.z, xv, acc[2]);
    acc[3] = fmaf(e0.w, xv, acc[3]);
    acc[4] = fmaf(e1.x, xv, acc[4]);
    acc[5] = fmaf(e1.y, xv, acc[5]);
    acc[6] = fmaf(e1.z, xv, acc[6]);
    acc[7] = fmaf(e1.w, xv, acc[7]);
  }
  int c0 = cg*8;
  #pragma unroll
  for (int r = 0; r < 8; r++)
    atomicAdd(&clustsum[((size_t)(g*C + c0 + r))*H + h], acc[r]);
}

__global__ __launch_bounds__(256) void k_out(const float* __restrict__ clustsum,
    const float* __restrict__ gsum, const float* __restrict__ out_W,
    const float* __restrict__ out_b, float* __restrict__ out){
  int o = threadIdx.x & 127, r = threadIdx.x >> 7;
  int row = blockIdx.x*2 + r;          // (g,c) flat
  float gden = gsum[row];
  float inv = gden > 0.f ? 1.0f / gden : 0.f;
  const float* cs = clustsum + (size_t)row*H;
  float acc = 0.f;
  for (int hh = 0; hh < H; hh++)
    acc = fmaf(cs[hh], out_W[hh*ODIM + o], acc);
  out[(size_t)row*ODIM + o] = fmaf(acc, inv, out_b[o]);
}

// ---------------- host ----------------
extern "C" void kernel_launch(void* const* d_in, const int* in_sizes, int n_in,
                              void* d_out, int out_size, void* d_ws, size_t ws_size,
                              hipStream_t stream){
  const float* emb    = (const float*)d_in[0];
  const float* Wl     = (const float*)d_in[1];
  const float* bl     = (const float*)d_in[2];
  const float* Wr     = (const float*)d_in[3];
  const float* gamma  = (const float*)d_in[4];
  const float* beta   = (const float*)d_in[5];
  const float* attn_W = (const float*)d_in[6];
  const float* attn_b = (const float*)d_in[7];
  const float* out_W  = (const float*)d_in[8];
  const float* out_b  = (const float*)d_in[9];
  const int* deg    = (const int*)d_in[10];
  const int* ei     = (const int*)d_in[11];
  const int* batch  = (const int*)d_in[12];
  float* out = (float*)d_out;

  const int N = in_sizes[10];
  const int E = in_sizes[11] / 2;
  const int L = in_sizes[1] / (H*H);
  const int B = out_size / (C*ODIM);

  size_t off = 0;
  auto alloc = [&](size_t bytes) -> void* {
    void* p = (char*)d_ws + off;
    off += (bytes + 255) & ~(size_t)255;
    return p;
  };
  u16*   xb     = (u16*)  alloc((size_t)N*H*2);
  u16*   meanb  = (u16*)  alloc((size_t)N*H*2);
  float* x2     = (float*)alloc((size_t)N*H*4);
  u16*   Wt     = (u16*)  alloc((size_t)L*H*256*2);
  float* escore = (float*)alloc((size_t)N*C*4);
  int*   col    = (int*)  alloc((size_t)E*4);
  int*   rowptr = (int*)  alloc((size_t)(N+1)*4);
  int*   bsum   = (int*)  alloc(64*4);
  int*   boff   = (int*)  alloc(64*4);
  int*   gs     = (int*)  alloc((size_t)(B+1)*4);
  float* gsum   = (float*)alloc((size_t)B*C*4);
  int*   rowfill= (int*)  alloc((size_t)N*4);
  int    Zw     = N + L*2*H + B*C*H;            // cnt | stats | clustsum (zeroed)
  int*   zbase  = (int*)  alloc((size_t)Zw*4);
  int*   cnt      = zbase;
  float* stats    = (float*)(zbase + N);
  float* clustsum = (float*)(zbase + N + L*2*H);

  int z4 = (Zw + 3) / 4;
  hipLaunchKernelGGL(k_zero,   dim3((z4+255)/256),   dim3(256), 0, stream, (int4*)zbase, z4);
  hipLaunchKernelGGL(k_embed,  dim3((N*32+255)/256), dim3(256), 0, stream, emb, deg, xb, N);
  hipLaunchKernelGGL(k_bounds, dim3((N+255)/256),    dim3(256), 0, stream, batch, gs, N, B);
  hipLaunchKernelGGL(k_wprep,  dim3(L*16),           dim3(256), 0, stream, Wl, Wr, Wt);
  hipLaunchKernelGGL(k_count,  dim3((E+255)/256),    dim3(256), 0, stream, ei, cnt, E);
  int nblk = (N + 1023)/1024;
  hipLaunchKernelGGL(k_scanA,  dim3(nblk), dim3(256), 0, stream, cnt, rowptr, bsum, N);
  hipLaunchKernelGGL(k_scanB,  dim3(1),    dim3(64),  0, stream, bsum, boff, nblk);
  hipLaunchKernelGGL(k_scanC,  dim3((N+255)/256), dim3(256), 0, stream, cnt, rowptr, rowfill, boff, N);
  hipLaunchKernelGGL(k_scatter,dim3((E+255)/256), dim3(256), 0, stream, ei, rowfill, col, E);

  float invN = 1.0f / (float)N;
  for (int l = 0; l < L; l++){
    hipLaunchKernelGGL(k_agg,    dim3((N+3)/4),  dim3(256), 0, stream, xb, rowptr, col, meanb, N);
    hipLaunchKernelGGL(k_linear, dim3((N+63)/64),dim3(256), 0, stream,
                       meanb, xb, Wt + (size_t)l*H*256, bl + (size_t)l*H, x2, N);
    hipLaunchKernelGGL(k_bnstats,dim3(256),      dim3(256), 0, stream, x2, stats + l*2*H, N);
    hipLaunchKernelGGL(k_bnrelu, dim3((N*32+255)/256), dim3(256), 0, stream,
                       x2, stats + l*2*H, gamma + (size_t)l*H, beta + (size_t)l*H, xb, N, invN);
  }
  hipLaunchKernelGGL(k_scores, dim3((N+63)/64), dim3(256), 0, stream, xb, attn_W, attn_b, escore, N);
  hipLaunchKernelGGL(k_denom,  dim3(B),         dim3(256), 0, stream, escore, gs, gsum);
  hipLaunchKernelGGL(k_clust,  dim3(B*16),      dim3(256), 0, stream, xb, escore, gs, clustsum);
  hipLaunchKernelGGL(k_out,    dim3(B*C/2),     dim3(256), 0, stream, clustsum, gsum, out_W, out_b, out);
}

// Round 4
// 493.996 us; speedup vs baseline: 1.6338x; 1.1866x over previous
//
#include <hip/hip_runtime.h>

typedef unsigned short u16;
typedef unsigned int   u32;

#define H    128
#define C    16
#define ODIM 128

typedef short bf16x8 __attribute__((ext_vector_type(8)));
typedef float f32x4  __attribute__((ext_vector_type(4)));

__device__ __forceinline__ float bf2f(u32 v){
  union { u32 i; float f; } t; t.i = v << 16; return t.f;
}
__device__ __forceinline__ u16 f2bf(float f){
  u32 u = __float_as_uint(f);
  u32 r = u + 0x7fffu + ((u >> 16) & 1u);   // RNE
  return (u16)(r >> 16);
}
__device__ __forceinline__ u32 pack2(float a, float b){
  return (u32)f2bf(a) | ((u32)f2bf(b) << 16);
}

// ---------------- init ----------------
__global__ __launch_bounds__(256) void k_zero(int4* p, int n4){
  int i = blockIdx.x*256 + threadIdx.x;
  if (i < n4) p[i] = make_int4(0,0,0,0);
}

__global__ __launch_bounds__(256) void k_embed(const float* __restrict__ emb,
    const int* __restrict__ deg, u16* __restrict__ xb, int N){
  int i = blockIdx.x*256 + threadIdx.x;
  if (i >= N*32) return;               // 4 values per thread
  int n = i >> 5, q = i & 31;
  int d = deg[n];
  float4 v = ((const float4*)(emb + (size_t)d*H))[q];
  uint2 o; o.x = pack2(v.x, v.y); o.y = pack2(v.z, v.w);
  ((uint2*)(xb + (size_t)n*H))[q] = o;
}

// graph start offsets from sorted batch
__global__ __launch_bounds__(256) void k_bounds(const int* __restrict__ batch,
    int* __restrict__ gs, int N, int B){
  int n = blockIdx.x*256 + threadIdx.x;
  if (n >= N) return;
  int b = batch[n];
  if (n == 0){ for (int g = 0; g <= b; g++) gs[g] = 0; }
  else {
    int pb = batch[n-1];
    for (int g = pb+1; g <= b; g++) gs[g] = n;
  }
  if (n == N-1){ for (int g = b+1; g <= B; g++) gs[g] = N; }
}

// W^T prep: Wt[l][h][k] bf16, k<128 = Wl[l][k][h], k>=128 = Wr[l][k-128][h]
__global__ __launch_bounds__(256) void k_wprep(const float* __restrict__ Wl,
    const float* __restrict__ Wr, u16* __restrict__ Wt){
  __shared__ u16 T[128][18];
  int b = blockIdx.x;
  int strip = b & 7, half = (b >> 3) & 1, l = b >> 4;
  const float* M = (half ? Wr : Wl) + (size_t)l*H*H;
  int k0 = strip * 16;
  int tid = threadIdx.x;
  #pragma unroll
  for (int j = 0; j < 8; j++){
    int u = tid + j*256;               // 0..2047 = 16 k x 128 h
    int kk = u >> 7, h = u & 127;
    T[h][kk] = f2bf(M[(size_t)(k0 + kk)*H + h]);
  }
  __syncthreads();
  #pragma unroll
  for (int j = 0; j < 8; j++){
    int u = tid + j*256;
    int h = u >> 4, k16 = u & 15;
    Wt[((size_t)(l*H + h))*256 + half*128 + k0 + k16] = T[h][k16];
  }
}

// ---------------- CSR build (no global atomics) ----------------
// bucket = dst >> 7 (128 nodes per bucket)

__global__ __launch_bounds__(256) void k_hist(const int* __restrict__ ei,
    int* __restrict__ blkhist, int NB, int E, int chunk){
  __shared__ int hist[400];
  int blk = blockIdx.x, tid = threadIdx.x;
  for (int b = tid; b < NB; b += 256) hist[b] = 0;
  __syncthreads();
  int start = blk*chunk, end = min(E, start + chunk);
  for (int e = start + tid; e < end; e += 256)
    atomicAdd(&hist[ei[E + e] >> 7], 1);
  __syncthreads();
  for (int b = tid; b < NB; b += 256) blkhist[b*64 + blk] = hist[b];
}

// generic scan over n ints (1024 per block)
__global__ __launch_bounds__(256) void k_scanA(const int* __restrict__ in,
    int* __restrict__ out, int* __restrict__ bsum, int n){
  __shared__ int wsum[4];
  int tid = threadIdx.x;
  int base = blockIdx.x*1024 + tid*4;
  int v0 = (base+0 < n) ? in[base+0] : 0;
  int v1 = (base+1 < n) ? in[base+1] : 0;
  int v2 = (base+2 < n) ? in[base+2] : 0;
  int v3 = (base+3 < n) ? in[base+3] : 0;
  int tsum = v0+v1+v2+v3;
  int lane = tid & 63, w = tid >> 6;
  int incl = tsum;
  for (int d = 1; d < 64; d <<= 1){
    int t = __shfl_up(incl, d, 64);
    if (lane >= d) incl += t;
  }
  if (lane == 63) wsum[w] = incl;
  __syncthreads();
  int woff = 0;
  for (int i = 0; i < w; i++) woff += wsum[i];
  int excl = woff + incl - tsum;
  if (base+0 < n) out[base+0] = excl;
  if (base+1 < n) out[base+1] = excl + v0;
  if (base+2 < n) out[base+2] = excl + v0 + v1;
  if (base+3 < n) out[base+3] = excl + v0 + v1 + v2;
  if (tid == 255) bsum[blockIdx.x] = woff + incl;
}

__global__ __launch_bounds__(64) void k_scanB(const int* __restrict__ bsum,
    int* __restrict__ boff, int nb){
  int tid = threadIdx.x;
  int v = (tid < nb) ? bsum[tid] : 0;
  int incl = v;
  for (int d = 1; d < 64; d <<= 1){
    int t = __shfl_up(incl, d, 64);
    if (tid >= d) incl += t;
  }
  boff[tid] = incl - v;
}

__global__ __launch_bounds__(256) void k_scanC(int* __restrict__ out,
    const int* __restrict__ boff, int n){
  int i = blockIdx.x*256 + threadIdx.x;
  if (i < n) out[i] += boff[i >> 10];
}

// place edges bucket-sorted as (src,dst) pairs
__global__ __launch_bounds__(256) void k_place(const int* __restrict__ ei,
    const int* __restrict__ bases, int2* __restrict__ pairs,
    int NB, int E, int chunk){
  __shared__ int cursor[400];
  int blk = blockIdx.x, tid = threadIdx.x;
  for (int b = tid; b < NB; b += 256) cursor[b] = bases[b*64 + blk];
  __syncthreads();
  int start = blk*chunk, end = min(E, start + chunk);
  for (int e = start + tid; e < end; e += 256){
    int s = ei[e], d = ei[E + e];
    int pos = atomicAdd(&cursor[d >> 7], 1);
    pairs[pos] = make_int2(s, d);
  }
}

// per bucket: per-node counts -> rowptr (direct), then node-sort col
__global__ __launch_bounds__(256) void k_cnt_place(const int2* __restrict__ pairs,
    const int* __restrict__ bases, int* __restrict__ rowptr,
    int* __restrict__ col, int NB, int N, int E){
  int b = blockIdx.x, tid = threadIdx.x;
  int bstart = bases[b*64];
  int bend   = (b+1 < NB) ? bases[(b+1)*64] : E;
  __shared__ int cnt[128], sc[128], rank[128];
  if (tid < 128) cnt[tid] = 0;
  __syncthreads();
  for (int e = bstart + tid; e < bend; e += 256)
    atomicAdd(&cnt[pairs[e].y & 127], 1);
  __syncthreads();
  if (tid < 128) sc[tid] = cnt[tid];
  for (int d = 1; d < 128; d <<= 1){
    int v = 0;
    __syncthreads();
    if (tid < 128 && tid >= d) v = sc[tid - d];
    __syncthreads();
    if (tid < 128) sc[tid] += v;
  }
  __syncthreads();
  if (tid < 128){
    int excl = sc[tid] - cnt[tid];
    rank[tid] = bstart + excl;
    int node = b*128 + tid;
    if (node < N) rowptr[node] = bstart + excl;
  }
  if (b == NB-1 && tid == 0) rowptr[N] = E;
  __syncthreads();
  for (int e = bstart + tid; e < bend; e += 256){
    int2 p = pairs[e];
    int pos = atomicAdd(&rank[p.y & 127], 1);
    col[pos] = p.x;
  }
}

// ---------------- per-layer ----------------
// wave per node: lane holds bf16 feature pair (2*lane, 2*lane+1); unroll 8
__global__ __launch_bounds__(256) void k_agg(const u16* __restrict__ x,
    const int* __restrict__ rowptr, const int* __restrict__ col,
    u16* __restrict__ meanb, int N){
  int wid  = (blockIdx.x*256 + threadIdx.x) >> 6;
  int lane = threadIdx.x & 63;
  if (wid >= N) return;
  int r0 = rowptr[wid], r1 = rowptr[wid+1];
  const u16* xl = x + lane*2;
  float ax = 0.f, ay = 0.f;
  int e = r0;
  for (; e + 8 <= r1; e += 8){
    u32 v0 = *(const u32*)(xl + (size_t)col[e+0]*H);
    u32 v1 = *(const u32*)(xl + (size_t)col[e+1]*H);
    u32 v2 = *(const u32*)(xl + (size_t)col[e+2]*H);
    u32 v3 = *(const u32*)(xl + (size_t)col[e+3]*H);
    u32 v4 = *(const u32*)(xl + (size_t)col[e+4]*H);
    u32 v5 = *(const u32*)(xl + (size_t)col[e+5]*H);
    u32 v6 = *(const u32*)(xl + (size_t)col[e+6]*H);
    u32 v7 = *(const u32*)(xl + (size_t)col[e+7]*H);
    ax += bf2f(v0 & 0xffff) + bf2f(v1 & 0xffff)
        + bf2f(v2 & 0xffff) + bf2f(v3 & 0xffff)
        + bf2f(v4 & 0xffff) + bf2f(v5 & 0xffff)
        + bf2f(v6 & 0xffff) + bf2f(v7 & 0xffff);
    ay += bf2f(v0 >> 16) + bf2f(v1 >> 16) + bf2f(v2 >> 16) + bf2f(v3 >> 16)
        + bf2f(v4 >> 16) + bf2f(v5 >> 16) + bf2f(v6 >> 16) + bf2f(v7 >> 16);
  }
  for (; e < r1; e++){
    u32 v = *(const u32*)(xl + (size_t)col[e]*H);
    ax += bf2f(v & 0xffff);
    ay += bf2f(v >> 16);
  }
  float invc = 1.0f / (float)max(r1 - r0, 1);
  *(u32*)(meanb + (size_t)wid*H + lane*2) = pack2(ax*invc, ay*invc);
}

// x2[n][h] = bl[h] + [meanb|xb] @ Wt^T via mfma_f32_16x16x32_bf16;
// fused BN-stat partial sums (sum, sumsq per h) -> global atomics.
__global__ __launch_bounds__(256) void k_linear(const u16* __restrict__ meanb,
    const u16* __restrict__ xb, const u16* __restrict__ Wt,
    const float* __restrict__ bl, float* __restrict__ x2,
    float* __restrict__ stats, int N){
  __shared__ u16 As[64][264];          // +8 pad -> bank-balanced b128
  __shared__ float Sh[128], Qh[128];
  int tid = threadIdx.x;
  if (tid < 128){ Sh[tid] = 0.f; Qh[tid] = 0.f; }
  int n0 = blockIdx.x * 64;
  #pragma unroll
  for (int j = 0; j < 16; j++){
    int u = tid + j*256;               // 0..4095 (4 bf16 each)
    int seg = u & 63, row = u >> 6;
    int node = n0 + row;
    uint2 v = make_uint2(0,0);
    if (node < N){
      if (seg < 32) v = ((const uint2*)(meanb + (size_t)node*H))[seg];
      else          v = ((const uint2*)(xb   + (size_t)node*H))[seg-32];
    }
    *(uint2*)&As[row][seg*4] = v;
  }
  __syncthreads();
  int lane = tid & 63, w = tid >> 6;
  int mlane = lane & 15, quad = lane >> 4;
  const u16* arow = &As[w*16 + mlane][0];
  f32x4 acc[8];
  #pragma unroll
  for (int t = 0; t < 8; t++) acc[t] = (f32x4){0.f, 0.f, 0.f, 0.f};
  #pragma unroll
  for (int kk = 0; kk < 8; kk++){
    bf16x8 a = *(const bf16x8*)(arow + kk*32 + quad*8);
    #pragma unroll
    for (int t = 0; t < 8; t++){
      const u16* bp = Wt + ((size_t)(t*16 + mlane))*256 + kk*32 + quad*8;
      bf16x8 b = *(const bf16x8*)bp;
      acc[t] = __builtin_amdgcn_mfma_f32_16x16x32_bf16(a, b, acc[t], 0, 0, 0);
    }
  }
  #pragma unroll
  for (int t = 0; t < 8; t++){
    int h = t*16 + mlane;
    float bv = bl[h];
    float s = 0.f, q = 0.f;
    #pragma unroll
    for (int r = 0; r < 4; r++){
      int node = n0 + w*16 + quad*4 + r;
      if (node < N){
        float v = acc[t][r] + bv;
        x2[(size_t)node*H + h] = v;
        s += v; q = fmaf(v, v, q);
      }
    }
    s += __shfl_xor(s, 16, 64); s += __shfl_xor(s, 32, 64);
    q += __shfl_xor(q, 16, 64); q += __shfl_xor(q, 32, 64);
    if (quad == 0){
      atomicAdd(&Sh[h], s);
      atomicAdd(&Qh[h], q);
    }
  }
  __syncthreads();
  if (tid < 128){
    atomicAdd(&stats[tid],     Sh[tid]);
    atomicAdd(&stats[H + tid], Qh[tid]);
  }
}

__global__ __launch_bounds__(256) void k_bnrelu(const float* __restrict__ x2,
    const float* __restrict__ stats, const float* __restrict__ gamma,
    const float* __restrict__ beta, u16* __restrict__ xb, int N, float invN){
  int i = blockIdx.x*256 + threadIdx.x;
  if (i >= N*32) return;               // 4 elems per thread
  int h = (i & 31) * 4;
  float4 v = ((const float4*)x2)[i];
  float vv[4] = {v.x, v.y, v.z, v.w};
  float r[4];
  #pragma unroll
  for (int j = 0; j < 4; j++){
    float mu  = stats[h+j] * invN;
    float var = fmaf(-mu, mu, stats[H + h + j] * invN);
    float sc  = rsqrtf(var + 1e-5f) * gamma[h+j];
    float bi  = beta[h+j];
    r[j] = fmaxf(fmaf(vv[j] - mu, sc, bi), 0.0f);
  }
  uint2 o; o.x = pack2(r[0], r[1]); o.y = pack2(r[2], r[3]);
  ((uint2*)xb)[i] = o;
}

// ---------------- attention pooling ----------------
__global__ __launch_bounds__(256) void k_scores(const u16* __restrict__ xb,
    const float* __restrict__ attn_W, const float* __restrict__ attn_b,
    float* __restrict__ escore, int N){
  __shared__ float xs[64][133];
  __shared__ float aw[H*C];
  int tid = threadIdx.x;
  int n0 = blockIdx.x * 64;
  #pragma unroll
  for (int j = 0; j < 8; j++){
    int u = tid + j*256;
    aw[u] = attn_W[u];
  }
  #pragma unroll
  for (int j = 0; j < 4; j++){
    int u = tid + j*256;               // 0..1023
    int row = u & 63, seg = u >> 6;    // 16 x (8 bf16) per row
    int node = n0 + row;
    uint4 rv = make_uint4(0,0,0,0);
    if (node < N) rv = ((const uint4*)(xb + (size_t)node*H))[seg];
    int k = seg*8;
    xs[row][k+0]=bf2f(rv.x&0xffff); xs[row][k+1]=bf2f(rv.x>>16);
    xs[row][k+2]=bf2f(rv.y&0xffff); xs[row][k+3]=bf2f(rv.y>>16);
    xs[row][k+4]=bf2f(rv.z&0xffff); xs[row][k+5]=bf2f(rv.z>>16);
    xs[row][k+6]=bf2f(rv.w&0xffff); xs[row][k+7]=bf2f(rv.w>>16);
  }
  __syncthreads();
  int c = tid & 15, sub = tid >> 4;
  float bias = attn_b[c];
  float acc[4] = {bias, bias, bias, bias};
  for (int k = 0; k < H; k++){
    float w = aw[k*C + c];
    acc[0] = fmaf(xs[sub     ][k], w, acc[0]);
    acc[1] = fmaf(xs[sub + 16][k], w, acc[1]);
    acc[2] = fmaf(xs[sub + 32][k], w, acc[2]);
    acc[3] = fmaf(xs[sub + 48][k], w, acc[3]);
  }
  #pragma unroll
  for (int j = 0; j < 4; j++){
    int node = n0 + sub + 16*j;
    if (node < N) escore[(size_t)node*C + c] = __expf(acc[j]);
  }
}

__global__ __launch_bounds__(256) void k_denom(const float* __restrict__ escore,
    const int* __restrict__ gs, float* __restrict__ gsum){
  int g = blockIdx.x;
  int c = threadIdx.x & 15, sub = threadIdx.x >> 4;
  int a = gs[g], b = gs[g+1];
  float s = 0.f;
  for (int n = a + sub; n < b; n += 16) s += escore[(size_t)n*C + c];
  __shared__ float part[16][17];
  part[sub][c] = s;
  for (int off2 = 8; off2 > 0; off2 >>= 1){
    __syncthreads();
    if (sub < off2) part[sub][c] += part[sub + off2][c];
  }
  __syncthreads();
  if (threadIdx.x < C) gsum[(size_t)g*C + threadIdx.x] = part[0][threadIdx.x];
}

// partial[g][b][c][h] = sum over nodes n = a+b, a+b+16, ... of escore[n][c]*x[n][h]
__global__ __launch_bounds__(256) void k_clust(const u16* __restrict__ xb,
    const float* __restrict__ escore, const int* __restrict__ gs,
    float* __restrict__ partial){
  int g = blockIdx.x >> 4, b = blockIdx.x & 15;
  int h = threadIdx.x & 127, cg = threadIdx.x >> 7;
  int a = gs[g], e2 = gs[g+1];
  float acc[8] = {0,0,0,0,0,0,0,0};
  for (int n = a + b; n < e2; n += 16){
    float xv = bf2f(xb[(size_t)n*H + h]);
    const float4* ep = (const float4*)(escore + (size_t)n*C) + cg*2;
    float4 e0 = ep[0], e1 = ep[1];
    acc[0] = fmaf(e0.x, xv, acc[0]);
    acc[1] = fmaf(e0.y, xv, acc[1]);
    acc[2] = fmaf(e0.z, xv, acc[2]);
    acc[3] = fmaf(e0.w, xv, acc[3]);
    acc[4] = fmaf(e1.x, xv, acc[4]);
    acc[5] = fmaf(e1.y, xv, acc[5]);
    acc[6] = fmaf(e1.z, xv, acc[6]);
    acc[7] = fmaf(e1.w, xv, acc[7]);
  }
  int c0 = cg*8;
  float* dst = partial + (((size_t)(g*16 + b))*C)*H + h;
  #pragma unroll
  for (int r = 0; r < 8; r++)
    dst[(size_t)(c0 + r)*H] = acc[r];
}

__global__ __launch_bounds__(256) void k_out(const float* __restrict__ partial,
    const float* __restrict__ gsum, const float* __restrict__ out_W,
    const float* __restrict__ out_b, float* __restrict__ out){
  __shared__ float cs[2][128];
  int tid = threadIdx.x;
  int r = tid >> 7, h = tid & 127;
  int row = blockIdx.x*2 + r;          // (g,c) flat
  int g = row >> 4, c = row & 15;
  float s = 0.f;
  for (int b = 0; b < 16; b++)
    s += partial[(((size_t)(g*16 + b))*C + c)*H + h];
  cs[r][h] = s;
  __syncthreads();
  float gden = gsum[row];
  float inv = gden > 0.f ? 1.0f / gden : 0.f;
  float acc = 0.f;
  for (int hh = 0; hh < H; hh++)
    acc = fmaf(cs[r][hh], out_W[hh*ODIM + h], acc);
  out[(size_t)row*ODIM + h] = fmaf(acc, inv, out_b[h]);
}

// ---------------- host ----------------
extern "C" void kernel_launch(void* const* d_in, const int* in_sizes, int n_in,
                              void* d_out, int out_size, void* d_ws, size_t ws_size,
                              hipStream_t stream){
  const float* emb    = (const float*)d_in[0];
  const float* Wl     = (const float*)d_in[1];
  const float* bl     = (const float*)d_in[2];
  const float* Wr     = (const float*)d_in[3];
  const float* gamma  = (const float*)d_in[4];
  const float* beta   = (const float*)d_in[5];
  const float* attn_W = (const float*)d_in[6];
  const float* attn_b = (const float*)d_in[7];
  const float* out_W  = (const float*)d_in[8];
  const float* out_b  = (const float*)d_in[9];
  const int* deg    = (const int*)d_in[10];
  const int* ei     = (const int*)d_in[11];
  const int* batch  = (const int*)d_in[12];
  float* out = (float*)d_out;

  const int N = in_sizes[10];
  const int E = in_sizes[11] / 2;
  const int L = in_sizes[1] / (H*H);
  const int B = out_size / (C*ODIM);
  const int NB = (N + 127) >> 7;        // buckets of 128 nodes
  const int n25 = NB * 64;              // blkhist elements
  const int chunk = (E + 63) >> 6;      // edges per hist/place block

  size_t off = 0;
  auto alloc = [&](size_t bytes) -> void* {
    void* p = (char*)d_ws + off;
    off += (bytes + 255) & ~(size_t)255;
    return p;
  };
  u16*   xb     = (u16*)  alloc((size_t)N*H*2);
  u16*   meanb  = (u16*)  alloc((size_t)N*H*2);
  float* x2     = (float*)alloc((size_t)N*H*4);  // aliased: pairs (CSR), partial (pooling)
  int2*  pairs  = (int2*)x2;
  float* partial= x2;
  u16*   Wt     = (u16*)  alloc((size_t)L*H*256*2);
  float* escore = (float*)alloc((size_t)N*C*4);
  int*   col    = (int*)  alloc((size_t)E*4);
  int*   rowptr = (int*)  alloc((size_t)(N+1)*4);
  int*   blkhist= (int*)  alloc((size_t)n25*4);
  int*   bases  = (int*)  alloc((size_t)n25*4);
  int*   bsum   = (int*)  alloc(64*4);
  int*   boff   = (int*)  alloc(64*4);
  int*   gs     = (int*)  alloc((size_t)(B+1)*4);
  float* gsum   = (float*)alloc((size_t)B*C*4);
  float* stats  = (float*)alloc((size_t)L*2*H*4);

  int z4 = (L*2*H + 3) / 4;
  hipLaunchKernelGGL(k_zero,   dim3((z4+255)/256),   dim3(256), 0, stream, (int4*)stats, z4);
  hipLaunchKernelGGL(k_embed,  dim3((N*32+255)/256), dim3(256), 0, stream, emb, deg, xb, N);
  hipLaunchKernelGGL(k_bounds, dim3((N+255)/256),    dim3(256), 0, stream, batch, gs, N, B);
  hipLaunchKernelGGL(k_wprep,  dim3(L*16),           dim3(256), 0, stream, Wl, Wr, Wt);
  // CSR build (atomic-free)
  hipLaunchKernelGGL(k_hist,   dim3(64),  dim3(256), 0, stream, ei, blkhist, NB, E, chunk);
  int nblk25 = (n25 + 1023) / 1024;
  hipLaunchKernelGGL(k_scanA,  dim3(nblk25), dim3(256), 0, stream, blkhist, bases, bsum, n25);
  hipLaunchKernelGGL(k_scanB,  dim3(1),      dim3(64),  0, stream, bsum, boff, nblk25);
  hipLaunchKernelGGL(k_scanC,  dim3((n25+255)/256), dim3(256), 0, stream, bases, boff, n25);
  hipLaunchKernelGGL(k_place,  dim3(64),  dim3(256), 0, stream, ei, bases, pairs, NB, E, chunk);
  hipLaunchKernelGGL(k_cnt_place, dim3(NB), dim3(256), 0, stream, pairs, bases, rowptr, col, NB, N, E);

  float invN = 1.0f / (float)N;
  for (int l = 0; l < L; l++){
    hipLaunchKernelGGL(k_agg,    dim3((N+3)/4),  dim3(256), 0, stream, xb, rowptr, col, meanb, N);
    hipLaunchKernelGGL(k_linear, dim3((N+63)/64),dim3(256), 0, stream,
                       meanb, xb, Wt + (size_t)l*H*256, bl + (size_t)l*H, x2,
                       stats + l*2*H, N);
    hipLaunchKernelGGL(k_bnrelu, dim3((N*32+255)/256), dim3(256), 0, stream,
                       x2, stats + l*2*H, gamma + (size_t)l*H, beta + (size_t)l*H, xb, N, invN);
  }
  hipLaunchKernelGGL(k_scores, dim3((N+63)/64), dim3(256), 0, stream, xb, attn_W, attn_b, escore, N);
  hipLaunchKernelGGL(k_denom,  dim3(B),         dim3(256), 0, stream, escore, gs, gsum);
  hipLaunchKernelGGL(k_clust,  dim3(B*16),      dim3(256), 0, stream, xb, escore, gs, partial);
  hipLaunchKernelGGL(k_out,    dim3(B*C/2),     dim3(256), 0, stream, partial, gsum, out_W, out_b, out);
}

// Round 5
// 461.706 us; speedup vs baseline: 1.7481x; 1.0699x over previous
//
#include <hip/hip_runtime.h>

typedef unsigned short u16;
typedef unsigned int   u32;

#define H    128
#define C    16
#define ODIM 128

typedef short bf16x8 __attribute__((ext_vector_type(8)));
typedef float f32x4  __attribute__((ext_vector_type(4)));

__device__ __forceinline__ float bf2f(u32 v){
  union { u32 i; float f; } t; t.i = v << 16; return t.f;
}
__device__ __forceinline__ u16 f2bf(float f){
  u32 u = __float_as_uint(f);
  u32 r = u + 0x7fffu + ((u >> 16) & 1u);   // RNE
  return (u16)(r >> 16);
}
__device__ __forceinline__ u32 pack2(float a, float b){
  return (u32)f2bf(a) | ((u32)f2bf(b) << 16);
}

// ---------------- init ----------------
__global__ __launch_bounds__(256) void k_embed(const float* __restrict__ emb,
    const int* __restrict__ deg, u16* __restrict__ xb, int N){
  int i = blockIdx.x*256 + threadIdx.x;
  if (i >= N*32) return;               // 4 values per thread
  int n = i >> 5, q = i & 31;
  int d = deg[n];
  float4 v = ((const float4*)(emb + (size_t)d*H))[q];
  uint2 o; o.x = pack2(v.x, v.y); o.y = pack2(v.z, v.w);
  ((uint2*)(xb + (size_t)n*H))[q] = o;
}

// graph start offsets from sorted batch
__global__ __launch_bounds__(256) void k_bounds(const int* __restrict__ batch,
    int* __restrict__ gs, int N, int B){
  int n = blockIdx.x*256 + threadIdx.x;
  if (n >= N) return;
  int b = batch[n];
  if (n == 0){ for (int g = 0; g <= b; g++) gs[g] = 0; }
  else {
    int pb = batch[n-1];
    for (int g = pb+1; g <= b; g++) gs[g] = n;
  }
  if (n == N-1){ for (int g = b+1; g <= B; g++) gs[g] = N; }
}

// W^T prep: Wt[l][h][k] bf16, k<128 = Wl[l][k][h], k>=128 = Wr[l][k-128][h]
__global__ __launch_bounds__(256) void k_wprep(const float* __restrict__ Wl,
    const float* __restrict__ Wr, u16* __restrict__ Wt){
  __shared__ u16 T[128][18];
  int b = blockIdx.x;
  int strip = b & 7, half = (b >> 3) & 1, l = b >> 4;
  const float* M = (half ? Wr : Wl) + (size_t)l*H*H;
  int k0 = strip * 16;
  int tid = threadIdx.x;
  #pragma unroll
  for (int j = 0; j < 8; j++){
    int u = tid + j*256;               // 0..2047 = 16 k x 128 h
    int kk = u >> 7, h = u & 127;
    T[h][kk] = f2bf(M[(size_t)(k0 + kk)*H + h]);
  }
  __syncthreads();
  #pragma unroll
  for (int j = 0; j < 8; j++){
    int u = tid + j*256;
    int h = u >> 4, k16 = u & 15;
    Wt[((size_t)(l*H + h))*256 + half*128 + k0 + k16] = T[h][k16];
  }
}

// ---------------- CSR build (no global atomics) ----------------
// bucket = dst >> 7 (128 nodes per bucket)

__global__ __launch_bounds__(256) void k_hist(const int* __restrict__ ei,
    int* __restrict__ blkhist, int NB, int E, int chunk){
  __shared__ int hist[400];
  int blk = blockIdx.x, tid = threadIdx.x;
  for (int b = tid; b < NB; b += 256) hist[b] = 0;
  __syncthreads();
  int start = blk*chunk, end = min(E, start + chunk);
  for (int e = start + tid; e < end; e += 256)
    atomicAdd(&hist[ei[E + e] >> 7], 1);
  __syncthreads();
  for (int b = tid; b < NB; b += 256) blkhist[b*64 + blk] = hist[b];
}

// generic scan over n ints (1024 per block)
__global__ __launch_bounds__(256) void k_scanA(const int* __restrict__ in,
    int* __restrict__ out, int* __restrict__ bsum, int n){
  __shared__ int wsum[4];
  int tid = threadIdx.x;
  int base = blockIdx.x*1024 + tid*4;
  int v0 = (base+0 < n) ? in[base+0] : 0;
  int v1 = (base+1 < n) ? in[base+1] : 0;
  int v2 = (base+2 < n) ? in[base+2] : 0;
  int v3 = (base+3 < n) ? in[base+3] : 0;
  int tsum = v0+v1+v2+v3;
  int lane = tid & 63, w = tid >> 6;
  int incl = tsum;
  for (int d = 1; d < 64; d <<= 1){
    int t = __shfl_up(incl, d, 64);
    if (lane >= d) incl += t;
  }
  if (lane == 63) wsum[w] = incl;
  __syncthreads();
  int woff = 0;
  for (int i = 0; i < w; i++) woff += wsum[i];
  int excl = woff + incl - tsum;
  if (base+0 < n) out[base+0] = excl;
  if (base+1 < n) out[base+1] = excl + v0;
  if (base+2 < n) out[base+2] = excl + v0 + v1;
  if (base+3 < n) out[base+3] = excl + v0 + v1 + v2;
  if (tid == 255) bsum[blockIdx.x] = woff + incl;
}

__global__ __launch_bounds__(64) void k_scanB(const int* __restrict__ bsum,
    int* __restrict__ boff, int nb){
  int tid = threadIdx.x;
  int v = (tid < nb) ? bsum[tid] : 0;
  int incl = v;
  for (int d = 1; d < 64; d <<= 1){
    int t = __shfl_up(incl, d, 64);
    if (tid >= d) incl += t;
  }
  boff[tid] = incl - v;
}

__global__ __launch_bounds__(256) void k_scanC(int* __restrict__ out,
    const int* __restrict__ boff, int n){
  int i = blockIdx.x*256 + threadIdx.x;
  if (i < n) out[i] += boff[i >> 10];
}

// place edges bucket-sorted as (src,dst) pairs
__global__ __launch_bounds__(256) void k_place(const int* __restrict__ ei,
    const int* __restrict__ bases, int2* __restrict__ pairs,
    int NB, int E, int chunk){
  __shared__ int cursor[400];
  int blk = blockIdx.x, tid = threadIdx.x;
  for (int b = tid; b < NB; b += 256) cursor[b] = bases[b*64 + blk];
  __syncthreads();
  int start = blk*chunk, end = min(E, start + chunk);
  for (int e = start + tid; e < end; e += 256){
    int s = ei[e], d = ei[E + e];
    int pos = atomicAdd(&cursor[d >> 7], 1);
    pairs[pos] = make_int2(s, d);
  }
}

// per bucket: per-node counts -> rowptr (direct), then node-sort col
__global__ __launch_bounds__(256) void k_cnt_place(const int2* __restrict__ pairs,
    const int* __restrict__ bases, int* __restrict__ rowptr,
    int* __restrict__ col, int NB, int N, int E){
  int b = blockIdx.x, tid = threadIdx.x;
  int bstart = bases[b*64];
  int bend   = (b+1 < NB) ? bases[(b+1)*64] : E;
  __shared__ int cnt[128], sc[128], rank[128];
  if (tid < 128) cnt[tid] = 0;
  __syncthreads();
  for (int e = bstart + tid; e < bend; e += 256)
    atomicAdd(&cnt[pairs[e].y & 127], 1);
  __syncthreads();
  if (tid < 128) sc[tid] = cnt[tid];
  for (int d = 1; d < 128; d <<= 1){
    int v = 0;
    __syncthreads();
    if (tid < 128 && tid >= d) v = sc[tid - d];
    __syncthreads();
    if (tid < 128) sc[tid] += v;
  }
  __syncthreads();
  if (tid < 128){
    int excl = sc[tid] - cnt[tid];
    rank[tid] = bstart + excl;
    int node = b*128 + tid;
    if (node < N) rowptr[node] = bstart + excl;
  }
  if (b == NB-1 && tid == 0) rowptr[N] = E;
  __syncthreads();
  for (int e = bstart + tid; e < bend; e += 256){
    int2 p = pairs[e];
    int pos = atomicAdd(&rank[p.y & 127], 1);
    col[pos] = p.x;
  }
}

// ---------------- per-layer ----------------
// wave per node, 4 edges in flight per VMEM instr: group = lane>>4 handles
// edges e = r0+grp, +4, ...; lane covers features fl*8..fl*8+7 (uint4).
__global__ __launch_bounds__(256) void k_agg(const u16* __restrict__ x,
    const int* __restrict__ rowptr, const int* __restrict__ col,
    u16* __restrict__ meanb, int N){
  int wid  = (blockIdx.x*256 + threadIdx.x) >> 6;
  int lane = threadIdx.x & 63;
  if (wid >= N) return;
  int r0 = rowptr[wid], r1 = rowptr[wid+1];
  int grp = lane >> 4, fl = lane & 15;
  const u16* xf = x + fl*8;
  float a0=0.f,a1=0.f,a2=0.f,a3=0.f,a4=0.f,a5=0.f,a6=0.f,a7=0.f;
  for (int e = r0 + grp; e < r1; e += 4){
    int s = col[e];
    uint4 v = *(const uint4*)(xf + (size_t)s*H);
    a0 += bf2f(v.x & 0xffff); a1 += bf2f(v.x >> 16);
    a2 += bf2f(v.y & 0xffff); a3 += bf2f(v.y >> 16);
    a4 += bf2f(v.z & 0xffff); a5 += bf2f(v.z >> 16);
    a6 += bf2f(v.w & 0xffff); a7 += bf2f(v.w >> 16);
  }
  a0 += __shfl_xor(a0,16,64); a1 += __shfl_xor(a1,16,64);
  a2 += __shfl_xor(a2,16,64); a3 += __shfl_xor(a3,16,64);
  a4 += __shfl_xor(a4,16,64); a5 += __shfl_xor(a5,16,64);
  a6 += __shfl_xor(a6,16,64); a7 += __shfl_xor(a7,16,64);
  a0 += __shfl_xor(a0,32,64); a1 += __shfl_xor(a1,32,64);
  a2 += __shfl_xor(a2,32,64); a3 += __shfl_xor(a3,32,64);
  a4 += __shfl_xor(a4,32,64); a5 += __shfl_xor(a5,32,64);
  a6 += __shfl_xor(a6,32,64); a7 += __shfl_xor(a7,32,64);
  if (grp == 0){
    float invc = 1.0f / (float)max(r1 - r0, 1);
    uint4 o;
    o.x = pack2(a0*invc, a1*invc);
    o.y = pack2(a2*invc, a3*invc);
    o.z = pack2(a4*invc, a5*invc);
    o.w = pack2(a6*invc, a7*invc);
    *(uint4*)(meanb + (size_t)wid*H + fl*8) = o;
  }
}

// x2[n][h] = bl[h] + [meanb|xb] @ Wt^T via mfma_f32_16x16x32_bf16;
// fused BN-stat partials -> pstats[blk][256] (coalesced store, no atomics).
__global__ __launch_bounds__(256) void k_linear(const u16* __restrict__ meanb,
    const u16* __restrict__ xb, const u16* __restrict__ Wt,
    const float* __restrict__ bl, float* __restrict__ x2,
    float* __restrict__ pstats, int N){
  __shared__ u16 As[64][264];          // +8 pad
  __shared__ float Sh[128], Qh[128];
  int tid = threadIdx.x;
  if (tid < 128){ Sh[tid] = 0.f; Qh[tid] = 0.f; }
  int n0 = blockIdx.x * 64;
  #pragma unroll
  for (int j = 0; j < 16; j++){
    int u = tid + j*256;               // 0..4095 (4 bf16 each)
    int seg = u & 63, row = u >> 6;
    int node = n0 + row;
    uint2 v = make_uint2(0,0);
    if (node < N){
      if (seg < 32) v = ((const uint2*)(meanb + (size_t)node*H))[seg];
      else          v = ((const uint2*)(xb   + (size_t)node*H))[seg-32];
    }
    *(uint2*)&As[row][seg*4] = v;
  }
  __syncthreads();
  int lane = tid & 63, w = tid >> 6;
  int mlane = lane & 15, quad = lane >> 4;
  const u16* arow = &As[w*16 + mlane][0];
  f32x4 acc[8];
  #pragma unroll
  for (int t = 0; t < 8; t++) acc[t] = (f32x4){0.f, 0.f, 0.f, 0.f};
  #pragma unroll
  for (int kk = 0; kk < 8; kk++){
    bf16x8 a = *(const bf16x8*)(arow + kk*32 + quad*8);
    #pragma unroll
    for (int t = 0; t < 8; t++){
      const u16* bp = Wt + ((size_t)(t*16 + mlane))*256 + kk*32 + quad*8;
      bf16x8 b = *(const bf16x8*)bp;
      acc[t] = __builtin_amdgcn_mfma_f32_16x16x32_bf16(a, b, acc[t], 0, 0, 0);
    }
  }
  #pragma unroll
  for (int t = 0; t < 8; t++){
    int h = t*16 + mlane;
    float bv = bl[h];
    float s = 0.f, q = 0.f;
    #pragma unroll
    for (int r = 0; r < 4; r++){
      int node = n0 + w*16 + quad*4 + r;
      if (node < N){
        float v = acc[t][r] + bv;
        x2[(size_t)node*H + h] = v;
        s += v; q = fmaf(v, v, q);
      }
    }
    s += __shfl_xor(s, 16, 64); s += __shfl_xor(s, 32, 64);
    q += __shfl_xor(q, 16, 64); q += __shfl_xor(q, 32, 64);
    if (quad == 0){
      atomicAdd(&Sh[h], s);       // LDS atomic: cheap, no contention issue
      atomicAdd(&Qh[h], q);
    }
  }
  __syncthreads();
  if (tid < 256){
    float v = (tid < 128) ? Sh[tid] : Qh[tid - 128];
    pstats[(size_t)blockIdx.x*256 + tid] = v;
  }
}

// reduce pstats[nblk][256] -> stats[256]; one block per stat index
__global__ __launch_bounds__(256) void k_statred(const float* __restrict__ pstats,
    float* __restrict__ stats, int nblk){
  __shared__ float red[4];
  int c = blockIdx.x, tid = threadIdx.x;
  float s = 0.f;
  for (int b = tid; b < nblk; b += 256)
    s += pstats[(size_t)b*256 + c];
  s += __shfl_xor(s, 1, 64);  s += __shfl_xor(s, 2, 64);
  s += __shfl_xor(s, 4, 64);  s += __shfl_xor(s, 8, 64);
  s += __shfl_xor(s, 16, 64); s += __shfl_xor(s, 32, 64);
  if ((tid & 63) == 0) red[tid >> 6] = s;
  __syncthreads();
  if (tid == 0) stats[c] = red[0] + red[1] + red[2] + red[3];
}

__global__ __launch_bounds__(256) void k_bnrelu(const float* __restrict__ x2,
    const float* __restrict__ stats, const float* __restrict__ gamma,
    const float* __restrict__ beta, u16* __restrict__ xb, int N, float invN){
  int i = blockIdx.x*256 + threadIdx.x;
  if (i >= N*32) return;               // 4 elems per thread
  int h = (i & 31) * 4;
  float4 v = ((const float4*)x2)[i];
  float vv[4] = {v.x, v.y, v.z, v.w};
  float r[4];
  #pragma unroll
  for (int j = 0; j < 4; j++){
    float mu  = stats[h+j] * invN;
    float var = fmaf(-mu, mu, stats[H + h + j] * invN);
    float sc  = rsqrtf(var + 1e-5f) * gamma[h+j];
    float bi  = beta[h+j];
    r[j] = fmaxf(fmaf(vv[j] - mu, sc, bi), 0.0f);
  }
  uint2 o; o.x = pack2(r[0], r[1]); o.y = pack2(r[2], r[3]);
  ((uint2*)xb)[i] = o;
}

// ---------------- attention pooling ----------------
__global__ __launch_bounds__(256) void k_scores(const u16* __restrict__ xb,
    const float* __restrict__ attn_W, const float* __restrict__ attn_b,
    float* __restrict__ escore, int N){
  __shared__ float xs[64][133];
  __shared__ float aw[H*C];
  int tid = threadIdx.x;
  int n0 = blockIdx.x * 64;
  #pragma unroll
  for (int j = 0; j < 8; j++){
    int u = tid + j*256;
    aw[u] = attn_W[u];
  }
  #pragma unroll
  for (int j = 0; j < 4; j++){
    int u = tid + j*256;               // 0..1023
    int row = u & 63, seg = u >> 6;    // 16 x (8 bf16) per row
    int node = n0 + row;
    uint4 rv = make_uint4(0,0,0,0);
    if (node < N) rv = ((const uint4*)(xb + (size_t)node*H))[seg];
    int k = seg*8;
    xs[row][k+0]=bf2f(rv.x&0xffff); xs[row][k+1]=bf2f(rv.x>>16);
    xs[row][k+2]=bf2f(rv.y&0xffff); xs[row][k+3]=bf2f(rv.y>>16);
    xs[row][k+4]=bf2f(rv.z&0xffff); xs[row][k+5]=bf2f(rv.z>>16);
    xs[row][k+6]=bf2f(rv.w&0xffff); xs[row][k+7]=bf2f(rv.w>>16);
  }
  __syncthreads();
  int c = tid & 15, sub = tid >> 4;
  float bias = attn_b[c];
  float acc[4] = {bias, bias, bias, bias};
  for (int k = 0; k < H; k++){
    float w = aw[k*C + c];
    acc[0] = fmaf(xs[sub     ][k], w, acc[0]);
    acc[1] = fmaf(xs[sub + 16][k], w, acc[1]);
    acc[2] = fmaf(xs[sub + 32][k], w, acc[2]);
    acc[3] = fmaf(xs[sub + 48][k], w, acc[3]);
  }
  #pragma unroll
  for (int j = 0; j < 4; j++){
    int node = n0 + sub + 16*j;
    if (node < N) escore[(size_t)node*C + c] = __expf(acc[j]);
  }
}

__global__ __launch_bounds__(256) void k_denom(const float* __restrict__ escore,
    const int* __restrict__ gs, float* __restrict__ gsum){
  int g = blockIdx.x;
  int c = threadIdx.x & 15, sub = threadIdx.x >> 4;
  int a = gs[g], b = gs[g+1];
  float s = 0.f;
  for (int n = a + sub; n < b; n += 16) s += escore[(size_t)n*C + c];
  __shared__ float part[16][17];
  part[sub][c] = s;
  for (int off2 = 8; off2 > 0; off2 >>= 1){
    __syncthreads();
    if (sub < off2) part[sub][c] += part[sub + off2][c];
  }
  __syncthreads();
  if (threadIdx.x < C) gsum[(size_t)g*C + threadIdx.x] = part[0][threadIdx.x];
}

// partial[g][b][c][h] = strided-node partial of escore[n][c]*x[n][h]
__global__ __launch_bounds__(256) void k_clust(const u16* __restrict__ xb,
    const float* __restrict__ escore, const int* __restrict__ gs,
    float* __restrict__ partial){
  int g = blockIdx.x >> 4, b = blockIdx.x & 15;
  int h = threadIdx.x & 127, cg = threadIdx.x >> 7;
  int a = gs[g], e2 = gs[g+1];
  float acc[8] = {0,0,0,0,0,0,0,0};
  for (int n = a + b; n < e2; n += 16){
    float xv = bf2f(xb[(size_t)n*H + h]);
    const float4* ep = (const float4*)(escore + (size_t)n*C) + cg*2;
    float4 e0 = ep[0], e1 = ep[1];
    acc[0] = fmaf(e0.x, xv, acc[0]);
    acc[1] = fmaf(e0.y, xv, acc[1]);
    acc[2] = fmaf(e0.z, xv, acc[2]);
    acc[3] = fmaf(e0.w, xv, acc[3]);
    acc[4] = fmaf(e1.x, xv, acc[4]);
    acc[5] = fmaf(e1.y, xv, acc[5]);
    acc[6] = fmaf(e1.z, xv, acc[6]);
    acc[7] = fmaf(e1.w, xv, acc[7]);
  }
  int c0 = cg*8;
  float* dst = partial + (((size_t)(g*16 + b))*C)*H + h;
  #pragma unroll
  for (int r = 0; r < 8; r++)
    dst[(size_t)(c0 + r)*H] = acc[r];
}

__global__ __launch_bounds__(256) void k_out(const float* __restrict__ partial,
    const float* __restrict__ gsum, const float* __restrict__ out_W,
    const float* __restrict__ out_b, float* __restrict__ out){
  __shared__ float cs[2][128];
  int tid = threadIdx.x;
  int r = tid >> 7, h = tid & 127;
  int row = blockIdx.x*2 + r;          // (g,c) flat
  int g = row >> 4, c = row & 15;
  float s = 0.f;
  for (int b = 0; b < 16; b++)
    s += partial[(((size_t)(g*16 + b))*C + c)*H + h];
  cs[r][h] = s;
  __syncthreads();
  float gden = gsum[row];
  float inv = gden > 0.f ? 1.0f / gden : 0.f;
  float acc = 0.f;
  for (int hh = 0; hh < H; hh++)
    acc = fmaf(cs[r][hh], out_W[hh*ODIM + h], acc);
  out[(size_t)row*ODIM + h] = fmaf(acc, inv, out_b[h]);
}

// ---------------- host ----------------
extern "C" void kernel_launch(void* const* d_in, const int* in_sizes, int n_in,
                              void* d_out, int out_size, void* d_ws, size_t ws_size,
                              hipStream_t stream){
  const float* emb    = (const float*)d_in[0];
  const float* Wl     = (const float*)d_in[1];
  const float* bl     = (const float*)d_in[2];
  const float* Wr     = (const float*)d_in[3];
  const float* gamma  = (const float*)d_in[4];
  const float* beta   = (const float*)d_in[5];
  const float* attn_W = (const float*)d_in[6];
  const float* attn_b = (const float*)d_in[7];
  const float* out_W  = (const float*)d_in[8];
  const float* out_b  = (const float*)d_in[9];
  const int* deg    = (const int*)d_in[10];
  const int* ei     = (const int*)d_in[11];
  const int* batch  = (const int*)d_in[12];
  float* out = (float*)d_out;

  const int N = in_sizes[10];
  const int E = in_sizes[11] / 2;
  const int L = in_sizes[1] / (H*H);
  const int B = out_size / (C*ODIM);
  const int NB = (N + 127) >> 7;        // buckets of 128 nodes
  const int n25 = NB * 64;              // blkhist elements
  const int chunk = (E + 63) >> 6;      // edges per hist/place block
  const int nblkL = (N + 63) / 64;      // k_linear grid

  size_t off = 0;
  auto alloc = [&](size_t bytes) -> void* {
    void* p = (char*)d_ws + off;
    off += (bytes + 255) & ~(size_t)255;
    return p;
  };
  u16*   xb     = (u16*)  alloc((size_t)N*H*2);
  u16*   meanb  = (u16*)  alloc((size_t)N*H*2);
  float* x2     = (float*)alloc((size_t)N*H*4);  // aliased: pairs (CSR), partial (pooling)
  int2*  pairs  = (int2*)x2;
  float* partial= x2;
  u16*   Wt     = (u16*)  alloc((size_t)L*H*256*2);
  float* escore = (float*)alloc((size_t)N*C*4);
  int*   col    = (int*)  alloc((size_t)E*4);
  int*   rowptr = (int*)  alloc((size_t)(N+1)*4);
  int*   blkhist= (int*)  alloc((size_t)n25*4);
  int*   bases  = (int*)  alloc((size_t)n25*4);
  int*   bsum   = (int*)  alloc(64*4);
  int*   boff   = (int*)  alloc(64*4);
  int*   gs     = (int*)  alloc((size_t)(B+1)*4);
  float* gsum   = (float*)alloc((size_t)B*C*4);
  float* stats  = (float*)alloc((size_t)L*2*H*4);
  float* pstats = (float*)alloc((size_t)nblkL*256*4);

  hipLaunchKernelGGL(k_embed,  dim3((N*32+255)/256), dim3(256), 0, stream, emb, deg, xb, N);
  hipLaunchKernelGGL(k_bounds, dim3((N+255)/256),    dim3(256), 0, stream, batch, gs, N, B);
  hipLaunchKernelGGL(k_wprep,  dim3(L*16),           dim3(256), 0, stream, Wl, Wr, Wt);
  // CSR build (atomic-free)
  hipLaunchKernelGGL(k_hist,   dim3(64),  dim3(256), 0, stream, ei, blkhist, NB, E, chunk);
  int nblk25 = (n25 + 1023) / 1024;
  hipLaunchKernelGGL(k_scanA,  dim3(nblk25), dim3(256), 0, stream, blkhist, bases, bsum, n25);
  hipLaunchKernelGGL(k_scanB,  dim3(1),      dim3(64),  0, stream, bsum, boff, nblk25);
  hipLaunchKernelGGL(k_scanC,  dim3((n25+255)/256), dim3(256), 0, stream, bases, boff, n25);
  hipLaunchKernelGGL(k_place,  dim3(64),  dim3(256), 0, stream, ei, bases, pairs, NB, E, chunk);
  hipLaunchKernelGGL(k_cnt_place, dim3(NB), dim3(256), 0, stream, pairs, bases, rowptr, col, NB, N, E);

  float invN = 1.0f / (float)N;
  for (int l = 0; l < L; l++){
    hipLaunchKernelGGL(k_agg,    dim3((N+3)/4),  dim3(256), 0, stream, xb, rowptr, col, meanb, N);
    hipLaunchKernelGGL(k_linear, dim3(nblkL),    dim3(256), 0, stream,
                       meanb, xb, Wt + (size_t)l*H*256, bl + (size_t)l*H, x2,
                       pstats, N);
    hipLaunchKernelGGL(k_statred,dim3(256),      dim3(256), 0, stream, pstats, stats + l*2*H, nblkL);
    hipLaunchKernelGGL(k_bnrelu, dim3((N*32+255)/256), dim3(256), 0, stream,
                       x2, stats + l*2*H, gamma + (size_t)l*H, beta + (size_t)l*H, xb, N, invN);
  }
  hipLaunchKernelGGL(k_scores, dim3((N+63)/64), dim3(256), 0, stream, xb, attn_W, attn_b, escore, N);
  hipLaunchKernelGGL(k_denom,  dim3(B),         dim3(256), 0, stream, escore, gs, gsum);
  hipLaunchKernelGGL(k_clust,  dim3(B*16),      dim3(256), 0, stream, xb, escore, gs, partial);
  hipLaunchKernelGGL(k_out,    dim3(B*C/2),     dim3(256), 0, stream, partial, gsum, out_W, out_b, out);
}

// Round 6
// 456.070 us; speedup vs baseline: 1.7697x; 1.0124x over previous
//
#include <hip/hip_runtime.h>

typedef unsigned short u16;
typedef unsigned int   u32;

#define H    128
#define C    16
#define ODIM 128

typedef short bf16x8 __attribute__((ext_vector_type(8)));
typedef float f32x4  __attribute__((ext_vector_type(4)));

__device__ __forceinline__ float bf2f(u32 v){
  union { u32 i; float f; } t; t.i = v << 16; return t.f;
}
__device__ __forceinline__ u16 f2bf(float f){
  u32 u = __float_as_uint(f);
  u32 r = u + 0x7fffu + ((u >> 16) & 1u);   // RNE
  return (u16)(r >> 16);
}
__device__ __forceinline__ u32 pack2(float a, float b){
  return (u32)f2bf(a) | ((u32)f2bf(b) << 16);
}

// ---------------- init ----------------
__global__ __launch_bounds__(256) void k_embed(const float* __restrict__ emb,
    const int* __restrict__ deg, u16* __restrict__ xb, int N){
  int i = blockIdx.x*256 + threadIdx.x;
  if (i >= N*32) return;               // 4 values per thread
  int n = i >> 5, q = i & 31;
  int d = deg[n];
  float4 v = ((const float4*)(emb + (size_t)d*H))[q];
  uint2 o; o.x = pack2(v.x, v.y); o.y = pack2(v.z, v.w);
  ((uint2*)(xb + (size_t)n*H))[q] = o;
}

// graph start offsets from sorted batch
__global__ __launch_bounds__(256) void k_bounds(const int* __restrict__ batch,
    int* __restrict__ gs, int N, int B){
  int n = blockIdx.x*256 + threadIdx.x;
  if (n >= N) return;
  int b = batch[n];
  if (n == 0){ for (int g = 0; g <= b; g++) gs[g] = 0; }
  else {
    int pb = batch[n-1];
    for (int g = pb+1; g <= b; g++) gs[g] = n;
  }
  if (n == N-1){ for (int g = b+1; g <= B; g++) gs[g] = N; }
}

// W^T prep: Wt[l][h][k] bf16, k<128 = Wl[l][k][h], k>=128 = Wr[l][k-128][h]
__global__ __launch_bounds__(256) void k_wprep(const float* __restrict__ Wl,
    const float* __restrict__ Wr, u16* __restrict__ Wt){
  __shared__ u16 T[128][18];
  int b = blockIdx.x;
  int strip = b & 7, half = (b >> 3) & 1, l = b >> 4;
  const float* M = (half ? Wr : Wl) + (size_t)l*H*H;
  int k0 = strip * 16;
  int tid = threadIdx.x;
  #pragma unroll
  for (int j = 0; j < 8; j++){
    int u = tid + j*256;               // 0..2047 = 16 k x 128 h
    int kk = u >> 7, h = u & 127;
    T[h][kk] = f2bf(M[(size_t)(k0 + kk)*H + h]);
  }
  __syncthreads();
  #pragma unroll
  for (int j = 0; j < 8; j++){
    int u = tid + j*256;
    int h = u >> 4, k16 = u & 15;
    Wt[((size_t)(l*H + h))*256 + half*128 + k0 + k16] = T[h][k16];
  }
}

// ---------------- CSR build (no global atomics) ----------------
// bucket = dst >> 7 (128 nodes per bucket)

__global__ __launch_bounds__(256) void k_hist(const int* __restrict__ ei,
    int* __restrict__ blkhist, int NB, int E, int chunk){
  __shared__ int hist[400];
  int blk = blockIdx.x, tid = threadIdx.x;
  for (int b = tid; b < NB; b += 256) hist[b] = 0;
  __syncthreads();
  int start = blk*chunk, end = min(E, start + chunk);
  for (int e = start + tid; e < end; e += 256)
    atomicAdd(&hist[ei[E + e] >> 7], 1);
  __syncthreads();
  for (int b = tid; b < NB; b += 256) blkhist[b*64 + blk] = hist[b];
}

// generic scan over n ints (1024 per block)
__global__ __launch_bounds__(256) void k_scanA(const int* __restrict__ in,
    int* __restrict__ out, int* __restrict__ bsum, int n){
  __shared__ int wsum[4];
  int tid = threadIdx.x;
  int base = blockIdx.x*1024 + tid*4;
  int v0 = (base+0 < n) ? in[base+0] : 0;
  int v1 = (base+1 < n) ? in[base+1] : 0;
  int v2 = (base+2 < n) ? in[base+2] : 0;
  int v3 = (base+3 < n) ? in[base+3] : 0;
  int tsum = v0+v1+v2+v3;
  int lane = tid & 63, w = tid >> 6;
  int incl = tsum;
  for (int d = 1; d < 64; d <<= 1){
    int t = __shfl_up(incl, d, 64);
    if (lane >= d) incl += t;
  }
  if (lane == 63) wsum[w] = incl;
  __syncthreads();
  int woff = 0;
  for (int i = 0; i < w; i++) woff += wsum[i];
  int excl = woff + incl - tsum;
  if (base+0 < n) out[base+0] = excl;
  if (base+1 < n) out[base+1] = excl + v0;
  if (base+2 < n) out[base+2] = excl + v0 + v1;
  if (base+3 < n) out[base+3] = excl + v0 + v1 + v2;
  if (tid == 255) bsum[blockIdx.x] = woff + incl;
}

__global__ __launch_bounds__(64) void k_scanB(const int* __restrict__ bsum,
    int* __restrict__ boff, int nb){
  int tid = threadIdx.x;
  int v = (tid < nb) ? bsum[tid] : 0;
  int incl = v;
  for (int d = 1; d < 64; d <<= 1){
    int t = __shfl_up(incl, d, 64);
    if (tid >= d) incl += t;
  }
  boff[tid] = incl - v;
}

__global__ __launch_bounds__(256) void k_scanC(int* __restrict__ out,
    const int* __restrict__ boff, int n){
  int i = blockIdx.x*256 + threadIdx.x;
  if (i < n) out[i] += boff[i >> 10];
}

// place edges bucket-sorted as (src,dst) pairs
__global__ __launch_bounds__(256) void k_place(const int* __restrict__ ei,
    const int* __restrict__ bases, int2* __restrict__ pairs,
    int NB, int E, int chunk){
  __shared__ int cursor[400];
  int blk = blockIdx.x, tid = threadIdx.x;
  for (int b = tid; b < NB; b += 256) cursor[b] = bases[b*64 + blk];
  __syncthreads();
  int start = blk*chunk, end = min(E, start + chunk);
  for (int e = start + tid; e < end; e += 256){
    int s = ei[e], d = ei[E + e];
    int pos = atomicAdd(&cursor[d >> 7], 1);
    pairs[pos] = make_int2(s, d);
  }
}

// per bucket: per-node counts -> rowptr (direct), then node-sort col
__global__ __launch_bounds__(256) void k_cnt_place(const int2* __restrict__ pairs,
    const int* __restrict__ bases, int* __restrict__ rowptr,
    int* __restrict__ col, int NB, int N, int E){
  int b = blockIdx.x, tid = threadIdx.x;
  int bstart = bases[b*64];
  int bend   = (b+1 < NB) ? bases[(b+1)*64] : E;
  __shared__ int cnt[128], sc[128], rank[128];
  if (tid < 128) cnt[tid] = 0;
  __syncthreads();
  for (int e = bstart + tid; e < bend; e += 256)
    atomicAdd(&cnt[pairs[e].y & 127], 1);
  __syncthreads();
  if (tid < 128) sc[tid] = cnt[tid];
  for (int d = 1; d < 128; d <<= 1){
    int v = 0;
    __syncthreads();
    if (tid < 128 && tid >= d) v = sc[tid - d];
    __syncthreads();
    if (tid < 128) sc[tid] += v;
  }
  __syncthreads();
  if (tid < 128){
    int excl = sc[tid] - cnt[tid];
    rank[tid] = bstart + excl;
    int node = b*128 + tid;
    if (node < N) rowptr[node] = bstart + excl;
  }
  if (b == NB-1 && tid == 0) rowptr[N] = E;
  __syncthreads();
  for (int e = bstart + tid; e < bend; e += 256){
    int2 p = pairs[e];
    int pos = atomicAdd(&rank[p.y & 127], 1);
    col[pos] = p.x;
  }
}

// ---------------- per-layer ----------------
// wave per node, 4 edges in flight per VMEM instr: group = lane>>4 handles
// edges e = r0+grp, +4, ...; lane covers features fl*8..fl*8+7 (uint4).
__global__ __launch_bounds__(256) void k_agg(const u16* __restrict__ x,
    const int* __restrict__ rowptr, const int* __restrict__ col,
    u16* __restrict__ meanb, int N){
  int wid  = (blockIdx.x*256 + threadIdx.x) >> 6;
  int lane = threadIdx.x & 63;
  if (wid >= N) return;
  int r0 = rowptr[wid], r1 = rowptr[wid+1];
  int grp = lane >> 4, fl = lane & 15;
  const u16* xf = x + fl*8;
  float a0=0.f,a1=0.f,a2=0.f,a3=0.f,a4=0.f,a5=0.f,a6=0.f,a7=0.f;
  for (int e = r0 + grp; e < r1; e += 4){
    int s = col[e];
    uint4 v = *(const uint4*)(xf + (size_t)s*H);
    a0 += bf2f(v.x & 0xffff); a1 += bf2f(v.x >> 16);
    a2 += bf2f(v.y & 0xffff); a3 += bf2f(v.y >> 16);
    a4 += bf2f(v.z & 0xffff); a5 += bf2f(v.z >> 16);
    a6 += bf2f(v.w & 0xffff); a7 += bf2f(v.w >> 16);
  }
  a0 += __shfl_xor(a0,16,64); a1 += __shfl_xor(a1,16,64);
  a2 += __shfl_xor(a2,16,64); a3 += __shfl_xor(a3,16,64);
  a4 += __shfl_xor(a4,16,64); a5 += __shfl_xor(a5,16,64);
  a6 += __shfl_xor(a6,16,64); a7 += __shfl_xor(a7,16,64);
  a0 += __shfl_xor(a0,32,64); a1 += __shfl_xor(a1,32,64);
  a2 += __shfl_xor(a2,32,64); a3 += __shfl_xor(a3,32,64);
  a4 += __shfl_xor(a4,32,64); a5 += __shfl_xor(a5,32,64);
  a6 += __shfl_xor(a6,32,64); a7 += __shfl_xor(a7,32,64);
  if (grp == 0){
    float invc = 1.0f / (float)max(r1 - r0, 1);
    uint4 o;
    o.x = pack2(a0*invc, a1*invc);
    o.y = pack2(a2*invc, a3*invc);
    o.z = pack2(a4*invc, a5*invc);
    o.w = pack2(a6*invc, a7*invc);
    *(uint4*)(meanb + (size_t)wid*H + fl*8) = o;
  }
}

// x2[n][h] = bl[h] + [meanb|xb] @ Wt^T via mfma_f32_16x16x32_bf16;
// B-fragment loads software-pipelined in registers (breg/bnext) so 8 L2
// loads are in flight per kk-step instead of load->wait->mfma serialization.
// Fused BN-stat partials -> pstats[blk][256] (no global atomics).
__global__ __launch_bounds__(256) void k_linear(const u16* __restrict__ meanb,
    const u16* __restrict__ xb, const u16* __restrict__ Wt,
    const float* __restrict__ bl, float* __restrict__ x2,
    float* __restrict__ pstats, int N){
  __shared__ u16 As[64][264];          // +8 pad
  __shared__ float Sh[128], Qh[128];
  int tid = threadIdx.x;
  if (tid < 128){ Sh[tid] = 0.f; Qh[tid] = 0.f; }
  int n0 = blockIdx.x * 64;
  #pragma unroll
  for (int j = 0; j < 8; j++){
    int u = tid + j*256;               // 0..2047, uint4 = 8 bf16 each
    int seg = u & 31, row = u >> 5;
    int node = n0 + row;
    uint4 v = make_uint4(0,0,0,0);
    if (node < N){
      if (seg < 16) v = ((const uint4*)(meanb + (size_t)node*H))[seg];
      else          v = ((const uint4*)(xb   + (size_t)node*H))[seg-16];
    }
    *(uint4*)&As[row][seg*8] = v;
  }
  __syncthreads();
  int lane = tid & 63, w = tid >> 6;
  int mlane = lane & 15, quad = lane >> 4;
  const u16* arow = &As[w*16 + mlane][quad*8];
  const u16* wbase = Wt + (size_t)mlane*256 + quad*8;   // t stride 16*256, kk stride 32
  f32x4 acc[8];
  #pragma unroll
  for (int t = 0; t < 8; t++) acc[t] = (f32x4){0.f, 0.f, 0.f, 0.f};
  bf16x8 breg[8], bnext[8];
  #pragma unroll
  for (int t = 0; t < 8; t++)
    breg[t] = *(const bf16x8*)(wbase + (size_t)t*16*256);
  bf16x8 a = *(const bf16x8*)(arow);
  #pragma unroll
  for (int kk = 0; kk < 8; kk++){
    bf16x8 anext;
    if (kk < 7){
      anext = *(const bf16x8*)(arow + (kk+1)*32);
      #pragma unroll
      for (int t = 0; t < 8; t++)
        bnext[t] = *(const bf16x8*)(wbase + (size_t)t*16*256 + (kk+1)*32);
    }
    #pragma unroll
    for (int t = 0; t < 8; t++)
      acc[t] = __builtin_amdgcn_mfma_f32_16x16x32_bf16(a, breg[t], acc[t], 0, 0, 0);
    if (kk < 7){
      a = anext;
      #pragma unroll
      for (int t = 0; t < 8; t++) breg[t] = bnext[t];
    }
  }
  #pragma unroll
  for (int t = 0; t < 8; t++){
    int h = t*16 + mlane;
    float bv = bl[h];
    float s = 0.f, q = 0.f;
    #pragma unroll
    for (int r = 0; r < 4; r++){
      int node = n0 + w*16 + quad*4 + r;
      if (node < N){
        float v = acc[t][r] + bv;
        x2[(size_t)node*H + h] = v;
        s += v; q = fmaf(v, v, q);
      }
    }
    s += __shfl_xor(s, 16, 64); s += __shfl_xor(s, 32, 64);
    q += __shfl_xor(q, 16, 64); q += __shfl_xor(q, 32, 64);
    if (quad == 0){
      atomicAdd(&Sh[h], s);
      atomicAdd(&Qh[h], q);
    }
  }
  __syncthreads();
  {
    float v = (tid < 128) ? Sh[tid] : Qh[tid - 128];
    pstats[(size_t)blockIdx.x*256 + tid] = v;
  }
}

// reduce pstats[nblk][256] -> stats[256]; one block per stat index
__global__ __launch_bounds__(256) void k_statred(const float* __restrict__ pstats,
    float* __restrict__ stats, int nblk){
  __shared__ float red[4];
  int c = blockIdx.x, tid = threadIdx.x;
  float s = 0.f;
  for (int b = tid; b < nblk; b += 256)
    s += pstats[(size_t)b*256 + c];
  s += __shfl_xor(s, 1, 64);  s += __shfl_xor(s, 2, 64);
  s += __shfl_xor(s, 4, 64);  s += __shfl_xor(s, 8, 64);
  s += __shfl_xor(s, 16, 64); s += __shfl_xor(s, 32, 64);
  if ((tid & 63) == 0) red[tid >> 6] = s;
  __syncthreads();
  if (tid == 0) stats[c] = red[0] + red[1] + red[2] + red[3];
}

__global__ __launch_bounds__(256) void k_bnrelu(const float* __restrict__ x2,
    const float* __restrict__ stats, const float* __restrict__ gamma,
    const float* __restrict__ beta, u16* __restrict__ xb, int N, float invN){
  int i = blockIdx.x*256 + threadIdx.x;
  if (i >= N*32) return;               // 4 elems per thread
  int h = (i & 31) * 4;
  float4 v = ((const float4*)x2)[i];
  float vv[4] = {v.x, v.y, v.z, v.w};
  float r[4];
  #pragma unroll
  for (int j = 0; j < 4; j++){
    float mu  = stats[h+j] * invN;
    float var = fmaf(-mu, mu, stats[H + h + j] * invN);
    float sc  = rsqrtf(var + 1e-5f) * gamma[h+j];
    float bi  = beta[h+j];
    r[j] = fmaxf(fmaf(vv[j] - mu, sc, bi), 0.0f);
  }
  uint2 o; o.x = pack2(r[0], r[1]); o.y = pack2(r[2], r[3]);
  ((uint2*)xb)[i] = o;
}

// ---------------- attention pooling ----------------
__global__ __launch_bounds__(256) void k_scores(const u16* __restrict__ xb,
    const float* __restrict__ attn_W, const float* __restrict__ attn_b,
    float* __restrict__ escore, int N){
  __shared__ float xs[64][133];
  __shared__ float aw[H*C];
  int tid = threadIdx.x;
  int n0 = blockIdx.x * 64;
  #pragma unroll
  for (int j = 0; j < 8; j++){
    int u = tid + j*256;
    aw[u] = attn_W[u];
  }
  #pragma unroll
  for (int j = 0; j < 4; j++){
    int u = tid + j*256;               // 0..1023
    int row = u & 63, seg = u >> 6;    // 16 x (8 bf16) per row
    int node = n0 + row;
    uint4 rv = make_uint4(0,0,0,0);
    if (node < N) rv = ((const uint4*)(xb + (size_t)node*H))[seg];
    int k = seg*8;
    xs[row][k+0]=bf2f(rv.x&0xffff); xs[row][k+1]=bf2f(rv.x>>16);
    xs[row][k+2]=bf2f(rv.y&0xffff); xs[row][k+3]=bf2f(rv.y>>16);
    xs[row][k+4]=bf2f(rv.z&0xffff); xs[row][k+5]=bf2f(rv.z>>16);
    xs[row][k+6]=bf2f(rv.w&0xffff); xs[row][k+7]=bf2f(rv.w>>16);
  }
  __syncthreads();
  int c = tid & 15, sub = tid >> 4;
  float bias = attn_b[c];
  float acc[4] = {bias, bias, bias, bias};
  for (int k = 0; k < H; k++){
    float w = aw[k*C + c];
    acc[0] = fmaf(xs[sub     ][k], w, acc[0]);
    acc[1] = fmaf(xs[sub + 16][k], w, acc[1]);
    acc[2] = fmaf(xs[sub + 32][k], w, acc[2]);
    acc[3] = fmaf(xs[sub + 48][k], w, acc[3]);
  }
  #pragma unroll
  for (int j = 0; j < 4; j++){
    int node = n0 + sub + 16*j;
    if (node < N) escore[(size_t)node*C + c] = __expf(acc[j]);
  }
}

__global__ __launch_bounds__(256) void k_denom(const float* __restrict__ escore,
    const int* __restrict__ gs, float* __restrict__ gsum){
  int g = blockIdx.x;
  int c = threadIdx.x & 15, sub = threadIdx.x >> 4;
  int a = gs[g], b = gs[g+1];
  float s = 0.f;
  for (int n = a + sub; n < b; n += 16) s += escore[(size_t)n*C + c];
  __shared__ float part[16][17];
  part[sub][c] = s;
  for (int off2 = 8; off2 > 0; off2 >>= 1){
    __syncthreads();
    if (sub < off2) part[sub][c] += part[sub + off2][c];
  }
  __syncthreads();
  if (threadIdx.x < C) gsum[(size_t)g*C + threadIdx.x] = part[0][threadIdx.x];
}

// partial[g][b][c][h] = strided-node partial of escore[n][c]*x[n][h]
__global__ __launch_bounds__(256) void k_clust(const u16* __restrict__ xb,
    const float* __restrict__ escore, const int* __restrict__ gs,
    float* __restrict__ partial){
  int g = blockIdx.x >> 4, b = blockIdx.x & 15;
  int h = threadIdx.x & 127, cg = threadIdx.x >> 7;
  int a = gs[g], e2 = gs[g+1];
  float acc[8] = {0,0,0,0,0,0,0,0};
  for (int n = a + b; n < e2; n += 16){
    float xv = bf2f(xb[(size_t)n*H + h]);
    const float4* ep = (const float4*)(escore + (size_t)n*C) + cg*2;
    float4 e0 = ep[0], e1 = ep[1];
    acc[0] = fmaf(e0.x, xv, acc[0]);
    acc[1] = fmaf(e0.y, xv, acc[1]);
    acc[2] = fmaf(e0.z, xv, acc[2]);
    acc[3] = fmaf(e0.w, xv, acc[3]);
    acc[4] = fmaf(e1.x, xv, acc[4]);
    acc[5] = fmaf(e1.y, xv, acc[5]);
    acc[6] = fmaf(e1.z, xv, acc[6]);
    acc[7] = fmaf(e1.w, xv, acc[7]);
  }
  int c0 = cg*8;
  float* dst = partial + (((size_t)(g*16 + b))*C)*H + h;
  #pragma unroll
  for (int r = 0; r < 8; r++)
    dst[(size_t)(c0 + r)*H] = acc[r];
}

__global__ __launch_bounds__(256) void k_out(const float* __restrict__ partial,
    const float* __restrict__ gsum, const float* __restrict__ out_W,
    const float* __restrict__ out_b, float* __restrict__ out){
  __shared__ float cs[2][128];
  int tid = threadIdx.x;
  int r = tid >> 7, h = tid & 127;
  int row = blockIdx.x*2 + r;          // (g,c) flat
  int g = row >> 4, c = row & 15;
  float s = 0.f;
  for (int b = 0; b < 16; b++)
    s += partial[(((size_t)(g*16 + b))*C + c)*H + h];
  cs[r][h] = s;
  __syncthreads();
  float gden = gsum[row];
  float inv = gden > 0.f ? 1.0f / gden : 0.f;
  float acc = 0.f;
  for (int hh = 0; hh < H; hh++)
    acc = fmaf(cs[r][hh], out_W[hh*ODIM + h], acc);
  out[(size_t)row*ODIM + h] = fmaf(acc, inv, out_b[h]);
}

// ---------------- host ----------------
extern "C" void kernel_launch(void* const* d_in, const int* in_sizes, int n_in,
                              void* d_out, int out_size, void* d_ws, size_t ws_size,
                              hipStream_t stream){
  const float* emb    = (const float*)d_in[0];
  const float* Wl     = (const float*)d_in[1];
  const float* bl     = (const float*)d_in[2];
  const float* Wr     = (const float*)d_in[3];
  const float* gamma  = (const float*)d_in[4];
  const float* beta   = (const float*)d_in[5];
  const float* attn_W = (const float*)d_in[6];
  const float* attn_b = (const float*)d_in[7];
  const float* out_W  = (const float*)d_in[8];
  const float* out_b  = (const float*)d_in[9];
  const int* deg    = (const int*)d_in[10];
  const int* ei     = (const int*)d_in[11];
  const int* batch  = (const int*)d_in[12];
  float* out = (float*)d_out;

  const int N = in_sizes[10];
  const int E = in_sizes[11] / 2;
  const int L = in_sizes[1] / (H*H);
  const int B = out_size / (C*ODIM);
  const int NB = (N + 127) >> 7;        // buckets of 128 nodes
  const int n25 = NB * 64;              // blkhist elements
  const int chunk = (E + 63) >> 6;      // edges per hist/place block
  const int nblkL = (N + 63) / 64;      // k_linear grid

  size_t off = 0;
  auto alloc = [&](size_t bytes) -> void* {
    void* p = (char*)d_ws + off;
    off += (bytes + 255) & ~(size_t)255;
    return p;
  };
  u16*   xb     = (u16*)  alloc((size_t)N*H*2);
  u16*   meanb  = (u16*)  alloc((size_t)N*H*2);
  float* x2     = (float*)alloc((size_t)N*H*4);  // aliased: pairs (CSR), partial (pooling)
  int2*  pairs  = (int2*)x2;
  float* partial= x2;
  u16*   Wt     = (u16*)  alloc((size_t)L*H*256*2);
  float* escore = (float*)alloc((size_t)N*C*4);
  int*   col    = (int*)  alloc((size_t)E*4);
  int*   rowptr = (int*)  alloc((size_t)(N+1)*4);
  int*   blkhist= (int*)  alloc((size_t)n25*4);
  int*   bases  = (int*)  alloc((size_t)n25*4);
  int*   bsum   = (int*)  alloc(64*4);
  int*   boff   = (int*)  alloc(64*4);
  int*   gs     = (int*)  alloc((size_t)(B+1)*4);
  float* gsum   = (float*)alloc((size_t)B*C*4);
  float* stats  = (float*)alloc((size_t)L*2*H*4);
  float* pstats = (float*)alloc((size_t)nblkL*256*4);

  hipLaunchKernelGGL(k_embed,  dim3((N*32+255)/256), dim3(256), 0, stream, emb, deg, xb, N);
  hipLaunchKernelGGL(k_bounds, dim3((N+255)/256),    dim3(256), 0, stream, batch, gs, N, B);
  hipLaunchKernelGGL(k_wprep,  dim3(L*16),           dim3(256), 0, stream, Wl, Wr, Wt);
  // CSR build (atomic-free)
  hipLaunchKernelGGL(k_hist,   dim3(64),  dim3(256), 0, stream, ei, blkhist, NB, E, chunk);
  int nblk25 = (n25 + 1023) / 1024;
  hipLaunchKernelGGL(k_scanA,  dim3(nblk25), dim3(256), 0, stream, blkhist, bases, bsum, n25);
  hipLaunchKernelGGL(k_scanB,  dim3(1),      dim3(64),  0, stream, bsum, boff, nblk25);
  hipLaunchKernelGGL(k_scanC,  dim3((n25+255)/256), dim3(256), 0, stream, bases, boff, n25);
  hipLaunchKernelGGL(k_place,  dim3(64),  dim3(256), 0, stream, ei, bases, pairs, NB, E, chunk);
  hipLaunchKernelGGL(k_cnt_place, dim3(NB), dim3(256), 0, stream, pairs, bases, rowptr, col, NB, N, E);

  float invN = 1.0f / (float)N;
  for (int l = 0; l < L; l++){
    hipLaunchKernelGGL(k_agg,    dim3((N+3)/4),  dim3(256), 0, stream, xb, rowptr, col, meanb, N);
    hipLaunchKernelGGL(k_linear, dim3(nblkL),    dim3(256), 0, stream,
                       meanb, xb, Wt + (size_t)l*H*256, bl + (size_t)l*H, x2,
                       pstats, N);
    hipLaunchKernelGGL(k_statred,dim3(256),      dim3(256), 0, stream, pstats, stats + l*2*H, nblkL);
    hipLaunchKernelGGL(k_bnrelu, dim3((N*32+255)/256), dim3(256), 0, stream,
                       x2, stats + l*2*H, gamma + (size_t)l*H, beta + (size_t)l*H, xb, N, invN);
  }
  hipLaunchKernelGGL(k_scores, dim3((N+63)/64), dim3(256), 0, stream, xb, attn_W, attn_b, escore, N);
  hipLaunchKernelGGL(k_denom,  dim3(B),         dim3(256), 0, stream, escore, gs, gsum);
  hipLaunchKernelGGL(k_clust,  dim3(B*16),      dim3(256), 0, stream, xb, escore, gs, partial);
  hipLaunchKernelGGL(k_out,    dim3(B*C/2),     dim3(256), 0, stream, partial, gsum, out_W, out_b, out);
}

// Round 7
// 396.410 us; speedup vs baseline: 2.0360x; 1.1505x over previous
//
#include <hip/hip_runtime.h>

typedef unsigned short u16;
typedef unsigned int   u32;

#define H    128
#define C    16
#define ODIM 128

typedef short bf16x8 __attribute__((ext_vector_type(8)));
typedef float f32x4  __attribute__((ext_vector_type(4)));

#define WSP 272   // Ws row stride (u16): 16B-aligned, breaks pow2 banks

__device__ __forceinline__ float bf2f(u32 v){
  union { u32 i; float f; } t; t.i = v << 16; return t.f;
}
__device__ __forceinline__ u16 f2bf(float f){
  u32 u = __float_as_uint(f);
  u32 r = u + 0x7fffu + ((u >> 16) & 1u);   // RNE
  return (u16)(r >> 16);
}
__device__ __forceinline__ u32 pack2(float a, float b){
  return (u32)f2bf(a) | ((u32)f2bf(b) << 16);
}

// ---------------- init ----------------
__global__ __launch_bounds__(256) void k_embed(const float* __restrict__ emb,
    const int* __restrict__ deg, u16* __restrict__ xb, int N){
  int i = blockIdx.x*256 + threadIdx.x;
  if (i >= N*32) return;               // 4 values per thread
  int n = i >> 5, q = i & 31;
  int d = deg[n];
  float4 v = ((const float4*)(emb + (size_t)d*H))[q];
  uint2 o; o.x = pack2(v.x, v.y); o.y = pack2(v.z, v.w);
  ((uint2*)(xb + (size_t)n*H))[q] = o;
}

// graph start offsets from sorted batch
__global__ __launch_bounds__(256) void k_bounds(const int* __restrict__ batch,
    int* __restrict__ gs, int N, int B){
  int n = blockIdx.x*256 + threadIdx.x;
  if (n >= N) return;
  int b = batch[n];
  if (n == 0){ for (int g = 0; g <= b; g++) gs[g] = 0; }
  else {
    int pb = batch[n-1];
    for (int g = pb+1; g <= b; g++) gs[g] = n;
  }
  if (n == N-1){ for (int g = b+1; g <= B; g++) gs[g] = N; }
}

// W^T prep: Wt[l][h][k] bf16, k<128 = Wl[l][k][h], k>=128 = Wr[l][k-128][h]
__global__ __launch_bounds__(256) void k_wprep(const float* __restrict__ Wl,
    const float* __restrict__ Wr, u16* __restrict__ Wt){
  __shared__ u16 T[128][18];
  int b = blockIdx.x;
  int strip = b & 7, half = (b >> 3) & 1, l = b >> 4;
  const float* M = (half ? Wr : Wl) + (size_t)l*H*H;
  int k0 = strip * 16;
  int tid = threadIdx.x;
  #pragma unroll
  for (int j = 0; j < 8; j++){
    int u = tid + j*256;               // 0..2047 = 16 k x 128 h
    int kk = u >> 7, h = u & 127;
    T[h][kk] = f2bf(M[(size_t)(k0 + kk)*H + h]);
  }
  __syncthreads();
  #pragma unroll
  for (int j = 0; j < 8; j++){
    int u = tid + j*256;
    int h = u >> 4, k16 = u & 15;
    Wt[((size_t)(l*H + h))*256 + half*128 + k0 + k16] = T[h][k16];
  }
}

// ---------------- CSR build (no global atomics) ----------------
// bucket = dst >> 7 (128 nodes per bucket)

__global__ __launch_bounds__(256) void k_hist(const int* __restrict__ ei,
    int* __restrict__ blkhist, int NB, int E, int chunk){
  __shared__ int hist[400];
  int blk = blockIdx.x, tid = threadIdx.x;
  for (int b = tid; b < NB; b += 256) hist[b] = 0;
  __syncthreads();
  int start = blk*chunk, end = min(E, start + chunk);
  for (int e = start + tid; e < end; e += 256)
    atomicAdd(&hist[ei[E + e] >> 7], 1);
  __syncthreads();
  for (int b = tid; b < NB; b += 256) blkhist[b*64 + blk] = hist[b];
}

// generic scan over n ints (1024 per block)
__global__ __launch_bounds__(256) void k_scanA(const int* __restrict__ in,
    int* __restrict__ out, int* __restrict__ bsum, int n){
  __shared__ int wsum[4];
  int tid = threadIdx.x;
  int base = blockIdx.x*1024 + tid*4;
  int v0 = (base+0 < n) ? in[base+0] : 0;
  int v1 = (base+1 < n) ? in[base+1] : 0;
  int v2 = (base+2 < n) ? in[base+2] : 0;
  int v3 = (base+3 < n) ? in[base+3] : 0;
  int tsum = v0+v1+v2+v3;
  int lane = tid & 63, w = tid >> 6;
  int incl = tsum;
  for (int d = 1; d < 64; d <<= 1){
    int t = __shfl_up(incl, d, 64);
    if (lane >= d) incl += t;
  }
  if (lane == 63) wsum[w] = incl;
  __syncthreads();
  int woff = 0;
  for (int i = 0; i < w; i++) woff += wsum[i];
  int excl = woff + incl - tsum;
  if (base+0 < n) out[base+0] = excl;
  if (base+1 < n) out[base+1] = excl + v0;
  if (base+2 < n) out[base+2] = excl + v0 + v1;
  if (base+3 < n) out[base+3] = excl + v0 + v1 + v2;
  if (tid == 255) bsum[blockIdx.x] = woff + incl;
}

__global__ __launch_bounds__(64) void k_scanB(const int* __restrict__ bsum,
    int* __restrict__ boff, int nb){
  int tid = threadIdx.x;
  int v = (tid < nb) ? bsum[tid] : 0;
  int incl = v;
  for (int d = 1; d < 64; d <<= 1){
    int t = __shfl_up(incl, d, 64);
    if (tid >= d) incl += t;
  }
  boff[tid] = incl - v;
}

__global__ __launch_bounds__(256) void k_scanC(int* __restrict__ out,
    const int* __restrict__ boff, int n){
  int i = blockIdx.x*256 + threadIdx.x;
  if (i < n) out[i] += boff[i >> 10];
}

// place edges bucket-sorted as (src,dst) pairs
__global__ __launch_bounds__(256) void k_place(const int* __restrict__ ei,
    const int* __restrict__ bases, int2* __restrict__ pairs,
    int NB, int E, int chunk){
  __shared__ int cursor[400];
  int blk = blockIdx.x, tid = threadIdx.x;
  for (int b = tid; b < NB; b += 256) cursor[b] = bases[b*64 + blk];
  __syncthreads();
  int start = blk*chunk, end = min(E, start + chunk);
  for (int e = start + tid; e < end; e += 256){
    int s = ei[e], d = ei[E + e];
    int pos = atomicAdd(&cursor[d >> 7], 1);
    pairs[pos] = make_int2(s, d);
  }
}

// per bucket: per-node counts -> rowptr (direct), then node-sort col
__global__ __launch_bounds__(256) void k_cnt_place(const int2* __restrict__ pairs,
    const int* __restrict__ bases, int* __restrict__ rowptr,
    int* __restrict__ col, int NB, int N, int E){
  int b = blockIdx.x, tid = threadIdx.x;
  int bstart = bases[b*64];
  int bend   = (b+1 < NB) ? bases[(b+1)*64] : E;
  __shared__ int cnt[128], sc[128], rank[128];
  if (tid < 128) cnt[tid] = 0;
  __syncthreads();
  for (int e = bstart + tid; e < bend; e += 256)
    atomicAdd(&cnt[pairs[e].y & 127], 1);
  __syncthreads();
  if (tid < 128) sc[tid] = cnt[tid];
  for (int d = 1; d < 128; d <<= 1){
    int v = 0;
    __syncthreads();
    if (tid < 128 && tid >= d) v = sc[tid - d];
    __syncthreads();
    if (tid < 128) sc[tid] += v;
  }
  __syncthreads();
  if (tid < 128){
    int excl = sc[tid] - cnt[tid];
    rank[tid] = bstart + excl;
    int node = b*128 + tid;
    if (node < N) rowptr[node] = bstart + excl;
  }
  if (b == NB-1 && tid == 0) rowptr[N] = E;
  __syncthreads();
  for (int e = bstart + tid; e < bend; e += 256){
    int2 p = pairs[e];
    int pos = atomicAdd(&rank[p.y & 127], 1);
    col[pos] = p.x;
  }
}

// ---------------- per-layer ----------------
// wave per node, 4 edges in flight per VMEM instr: group = lane>>4 handles
// edges e = r0+grp, +4, ...; lane covers features fl*8..fl*8+7 (uint4).
__global__ __launch_bounds__(256) void k_agg(const u16* __restrict__ x,
    const int* __restrict__ rowptr, const int* __restrict__ col,
    u16* __restrict__ meanb, int N){
  int wid  = (blockIdx.x*256 + threadIdx.x) >> 6;
  int lane = threadIdx.x & 63;
  if (wid >= N) return;
  int r0 = rowptr[wid], r1 = rowptr[wid+1];
  int grp = lane >> 4, fl = lane & 15;
  const u16* xf = x + fl*8;
  float a0=0.f,a1=0.f,a2=0.f,a3=0.f,a4=0.f,a5=0.f,a6=0.f,a7=0.f;
  for (int e = r0 + grp; e < r1; e += 4){
    int s = col[e];
    uint4 v = *(const uint4*)(xf + (size_t)s*H);
    a0 += bf2f(v.x & 0xffff); a1 += bf2f(v.x >> 16);
    a2 += bf2f(v.y & 0xffff); a3 += bf2f(v.y >> 16);
    a4 += bf2f(v.z & 0xffff); a5 += bf2f(v.z >> 16);
    a6 += bf2f(v.w & 0xffff); a7 += bf2f(v.w >> 16);
  }
  a0 += __shfl_xor(a0,16,64); a1 += __shfl_xor(a1,16,64);
  a2 += __shfl_xor(a2,16,64); a3 += __shfl_xor(a3,16,64);
  a4 += __shfl_xor(a4,16,64); a5 += __shfl_xor(a5,16,64);
  a6 += __shfl_xor(a6,16,64); a7 += __shfl_xor(a7,16,64);
  a0 += __shfl_xor(a0,32,64); a1 += __shfl_xor(a1,32,64);
  a2 += __shfl_xor(a2,32,64); a3 += __shfl_xor(a3,32,64);
  a4 += __shfl_xor(a4,32,64); a5 += __shfl_xor(a5,32,64);
  a6 += __shfl_xor(a6,32,64); a7 += __shfl_xor(a7,32,64);
  if (grp == 0){
    float invc = 1.0f / (float)max(r1 - r0, 1);
    uint4 o;
    o.x = pack2(a0*invc, a1*invc);
    o.y = pack2(a2*invc, a3*invc);
    o.z = pack2(a4*invc, a5*invc);
    o.w = pack2(a6*invc, a7*invc);
    *(uint4*)(meanb + (size_t)wid*H + fl*8) = o;
  }
}

// x2[n][h] = bl[h] + [meanb|xb] @ Wt^T via mfma_f32_16x16x32_bf16.
// Whole Wt (64 KB) staged in LDS per block; A-fragments loaded straight from
// global (8 independent 16B loads issued before the barrier, latency hidden
// by Wt staging). K-loop is pure ds_read_b128 + MFMA — no global latency.
// Fused BN-stat partials -> pstats[blk][256] (no global atomics).
__global__ __launch_bounds__(256) void k_linear(const u16* __restrict__ meanb,
    const u16* __restrict__ xb, const u16* __restrict__ Wt,
    const float* __restrict__ bl, float* __restrict__ x2,
    float* __restrict__ pstats, int N){
  __shared__ u16 Ws[128][WSP];         // 69.6 KB -> 2 blocks/CU
  __shared__ float Sh[128], Qh[128];
  int tid = threadIdx.x;
  if (tid < 128){ Sh[tid] = 0.f; Qh[tid] = 0.f; }
  int lane = tid & 63, w = tid >> 6;
  int mlane = lane & 15, quad = lane >> 4;
  int node = blockIdx.x*64 + w*16 + mlane;   // A row owned by this lane
  // A-fragments from global (reads may run past N into adjacent ws buffers:
  // finite garbage, only affects D rows of OOB nodes which are never stored)
  const u16* arow_m = meanb + (size_t)node*H + quad*8;
  const u16* arow_x = xb   + (size_t)node*H + quad*8;
  bf16x8 af[8];
  #pragma unroll
  for (int kk = 0; kk < 4; kk++){
    af[kk]     = *(const bf16x8*)(arow_m + kk*32);
    af[kk + 4] = *(const bf16x8*)(arow_x + kk*32);
  }
  // stage Wt -> LDS (coalesced uint4)
  #pragma unroll
  for (int j = 0; j < 16; j++){
    int u = tid + j*256;               // 0..4095 uint4
    int row = u >> 5, seg = u & 31;
    uint4 v = ((const uint4*)(Wt + (size_t)row*256))[seg];
    *(uint4*)&Ws[row][seg*8] = v;
  }
  __syncthreads();
  f32x4 acc[8];
  #pragma unroll
  for (int t = 0; t < 8; t++) acc[t] = (f32x4){0.f, 0.f, 0.f, 0.f};
  #pragma unroll
  for (int kk = 0; kk < 8; kk++){
    #pragma unroll
    for (int t = 0; t < 8; t++){
      bf16x8 b = *(const bf16x8*)&Ws[t*16 + mlane][kk*32 + quad*8];
      acc[t] = __builtin_amdgcn_mfma_f32_16x16x32_bf16(af[kk], b, acc[t], 0, 0, 0);
    }
  }
  #pragma unroll
  for (int t = 0; t < 8; t++){
    int h = t*16 + mlane;
    float bv = bl[h];
    float s = 0.f, q = 0.f;
    #pragma unroll
    for (int r = 0; r < 4; r++){
      int nd = blockIdx.x*64 + w*16 + quad*4 + r;
      if (nd < N){
        float v = acc[t][r] + bv;
        x2[(size_t)nd*H + h] = v;
        s += v; q = fmaf(v, v, q);
      }
    }
    s += __shfl_xor(s, 16, 64); s += __shfl_xor(s, 32, 64);
    q += __shfl_xor(q, 16, 64); q += __shfl_xor(q, 32, 64);
    if (quad == 0){
      atomicAdd(&Sh[h], s);
      atomicAdd(&Qh[h], q);
    }
  }
  __syncthreads();
  {
    float v = (tid < 128) ? Sh[tid] : Qh[tid - 128];
    pstats[(size_t)blockIdx.x*256 + tid] = v;
  }
}

// reduce pstats[nblk][256] -> stats[256]; one block per stat index
__global__ __launch_bounds__(256) void k_statred(const float* __restrict__ pstats,
    float* __restrict__ stats, int nblk){
  __shared__ float red[4];
  int c = blockIdx.x, tid = threadIdx.x;
  float s = 0.f;
  for (int b = tid; b < nblk; b += 256)
    s += pstats[(size_t)b*256 + c];
  s += __shfl_xor(s, 1, 64);  s += __shfl_xor(s, 2, 64);
  s += __shfl_xor(s, 4, 64);  s += __shfl_xor(s, 8, 64);
  s += __shfl_xor(s, 16, 64); s += __shfl_xor(s, 32, 64);
  if ((tid & 63) == 0) red[tid >> 6] = s;
  __syncthreads();
  if (tid == 0) stats[c] = red[0] + red[1] + red[2] + red[3];
}

__global__ __launch_bounds__(256) void k_bnrelu(const float* __restrict__ x2,
    const float* __restrict__ stats, const float* __restrict__ gamma,
    const float* __restrict__ beta, u16* __restrict__ xb, int N, float invN){
  int i = blockIdx.x*256 + threadIdx.x;
  if (i >= N*32) return;               // 4 elems per thread
  int h = (i & 31) * 4;
  float4 v = ((const float4*)x2)[i];
  float vv[4] = {v.x, v.y, v.z, v.w};
  float r[4];
  #pragma unroll
  for (int j = 0; j < 4; j++){
    float mu  = stats[h+j] * invN;
    float var = fmaf(-mu, mu, stats[H + h + j] * invN);
    float sc  = rsqrtf(var + 1e-5f) * gamma[h+j];
    float bi  = beta[h+j];
    r[j] = fmaxf(fmaf(vv[j] - mu, sc, bi), 0.0f);
  }
  uint2 o; o.x = pack2(r[0], r[1]); o.y = pack2(r[2], r[3]);
  ((uint2*)xb)[i] = o;
}

// ---------------- attention pooling ----------------
__global__ __launch_bounds__(256) void k_scores(const u16* __restrict__ xb,
    const float* __restrict__ attn_W, const float* __restrict__ attn_b,
    float* __restrict__ escore, int N){
  __shared__ float xs[64][133];
  __shared__ float aw[H*C];
  int tid = threadIdx.x;
  int n0 = blockIdx.x * 64;
  #pragma unroll
  for (int j = 0; j < 8; j++){
    int u = tid + j*256;
    aw[u] = attn_W[u];
  }
  #pragma unroll
  for (int j = 0; j < 4; j++){
    int u = tid + j*256;               // 0..1023
    int row = u & 63, seg = u >> 6;    // 16 x (8 bf16) per row
    int node = n0 + row;
    uint4 rv = make_uint4(0,0,0,0);
    if (node < N) rv = ((const uint4*)(xb + (size_t)node*H))[seg];
    int k = seg*8;
    xs[row][k+0]=bf2f(rv.x&0xffff); xs[row][k+1]=bf2f(rv.x>>16);
    xs[row][k+2]=bf2f(rv.y&0xffff); xs[row][k+3]=bf2f(rv.y>>16);
    xs[row][k+4]=bf2f(rv.z&0xffff); xs[row][k+5]=bf2f(rv.z>>16);
    xs[row][k+6]=bf2f(rv.w&0xffff); xs[row][k+7]=bf2f(rv.w>>16);
  }
  __syncthreads();
  int c = tid & 15, sub = tid >> 4;
  float bias = attn_b[c];
  float acc[4] = {bias, bias, bias, bias};
  for (int k = 0; k < H; k++){
    float w = aw[k*C + c];
    acc[0] = fmaf(xs[sub     ][k], w, acc[0]);
    acc[1] = fmaf(xs[sub + 16][k], w, acc[1]);
    acc[2] = fmaf(xs[sub + 32][k], w, acc[2]);
    acc[3] = fmaf(xs[sub + 48][k], w, acc[3]);
  }
  #pragma unroll
  for (int j = 0; j < 4; j++){
    int node = n0 + sub + 16*j;
    if (node < N) escore[(size_t)node*C + c] = __expf(acc[j]);
  }
}

__global__ __launch_bounds__(256) void k_denom(const float* __restrict__ escore,
    const int* __restrict__ gs, float* __restrict__ gsum){
  int g = blockIdx.x;
  int c = threadIdx.x & 15, sub = threadIdx.x >> 4;
  int a = gs[g], b = gs[g+1];
  float s = 0.f;
  for (int n = a + sub; n < b; n += 16) s += escore[(size_t)n*C + c];
  __shared__ float part[16][17];
  part[sub][c] = s;
  for (int off2 = 8; off2 > 0; off2 >>= 1){
    __syncthreads();
    if (sub < off2) part[sub][c] += part[sub + off2][c];
  }
  __syncthreads();
  if (threadIdx.x < C) gsum[(size_t)g*C + threadIdx.x] = part[0][threadIdx.x];
}

// partial[g][b][c][h] = strided-node partial of escore[n][c]*x[n][h]
__global__ __launch_bounds__(256) void k_clust(const u16* __restrict__ xb,
    const float* __restrict__ escore, const int* __restrict__ gs,
    float* __restrict__ partial){
  int g = blockIdx.x >> 4, b = blockIdx.x & 15;
  int h = threadIdx.x & 127, cg = threadIdx.x >> 7;
  int a = gs[g], e2 = gs[g+1];
  float acc[8] = {0,0,0,0,0,0,0,0};
  for (int n = a + b; n < e2; n += 16){
    float xv = bf2f(xb[(size_t)n*H + h]);
    const float4* ep = (const float4*)(escore + (size_t)n*C) + cg*2;
    float4 e0 = ep[0], e1 = ep[1];
    acc[0] = fmaf(e0.x, xv, acc[0]);
    acc[1] = fmaf(e0.y, xv, acc[1]);
    acc[2] = fmaf(e0.z, xv, acc[2]);
    acc[3] = fmaf(e0.w, xv, acc[3]);
    acc[4] = fmaf(e1.x, xv, acc[4]);
    acc[5] = fmaf(e1.y, xv, acc[5]);
    acc[6] = fmaf(e1.z, xv, acc[6]);
    acc[7] = fmaf(e1.w, xv, acc[7]);
  }
  int c0 = cg*8;
  float* dst = partial + (((size_t)(g*16 + b))*C)*H + h;
  #pragma unroll
  for (int r = 0; r < 8; r++)
    dst[(size_t)(c0 + r)*H] = acc[r];
}

__global__ __launch_bounds__(256) void k_out(const float* __restrict__ partial,
    const float* __restrict__ gsum, const float* __restrict__ out_W,
    const float* __restrict__ out_b, float* __restrict__ out){
  __shared__ float cs[2][128];
  int tid = threadIdx.x;
  int r = tid >> 7, h = tid & 127;
  int row = blockIdx.x*2 + r;          // (g,c) flat
  int g = row >> 4, c = row & 15;
  float s = 0.f;
  for (int b = 0; b < 16; b++)
    s += partial[(((size_t)(g*16 + b))*C + c)*H + h];
  cs[r][h] = s;
  __syncthreads();
  float gden = gsum[row];
  float inv = gden > 0.f ? 1.0f / gden : 0.f;
  float acc = 0.f;
  for (int hh = 0; hh < H; hh++)
    acc = fmaf(cs[r][hh], out_W[hh*ODIM + h], acc);
  out[(size_t)row*ODIM + h] = fmaf(acc, inv, out_b[h]);
}

// ---------------- host ----------------
extern "C" void kernel_launch(void* const* d_in, const int* in_sizes, int n_in,
                              void* d_out, int out_size, void* d_ws, size_t ws_size,
                              hipStream_t stream){
  const float* emb    = (const float*)d_in[0];
  const float* Wl     = (const float*)d_in[1];
  const float* bl     = (const float*)d_in[2];
  const float* Wr     = (const float*)d_in[3];
  const float* gamma  = (const float*)d_in[4];
  const float* beta   = (const float*)d_in[5];
  const float* attn_W = (const float*)d_in[6];
  const float* attn_b = (const float*)d_in[7];
  const float* out_W  = (const float*)d_in[8];
  const float* out_b  = (const float*)d_in[9];
  const int* deg    = (const int*)d_in[10];
  const int* ei     = (const int*)d_in[11];
  const int* batch  = (const int*)d_in[12];
  float* out = (float*)d_out;

  const int N = in_sizes[10];
  const int E = in_sizes[11] / 2;
  const int L = in_sizes[1] / (H*H);
  const int B = out_size / (C*ODIM);
  const int NB = (N + 127) >> 7;        // buckets of 128 nodes
  const int n25 = NB * 64;              // blkhist elements
  const int chunk = (E + 63) >> 6;      // edges per hist/place block
  const int nblkL = (N + 63) / 64;      // k_linear grid

  size_t off = 0;
  auto alloc = [&](size_t bytes) -> void* {
    void* p = (char*)d_ws + off;
    off += (bytes + 255) & ~(size_t)255;
    return p;
  };
  u16*   xb     = (u16*)  alloc((size_t)N*H*2);
  u16*   meanb  = (u16*)  alloc((size_t)N*H*2);
  float* x2     = (float*)alloc((size_t)N*H*4);  // aliased: pairs (CSR), partial (pooling)
  int2*  pairs  = (int2*)x2;
  float* partial= x2;
  u16*   Wt     = (u16*)  alloc((size_t)L*H*256*2);
  float* escore = (float*)alloc((size_t)N*C*4);
  int*   col    = (int*)  alloc((size_t)E*4);
  int*   rowptr = (int*)  alloc((size_t)(N+1)*4);
  int*   blkhist= (int*)  alloc((size_t)n25*4);
  int*   bases  = (int*)  alloc((size_t)n25*4);
  int*   bsum   = (int*)  alloc(64*4);
  int*   boff   = (int*)  alloc(64*4);
  int*   gs     = (int*)  alloc((size_t)(B+1)*4);
  float* gsum   = (float*)alloc((size_t)B*C*4);
  float* stats  = (float*)alloc((size_t)L*2*H*4);
  float* pstats = (float*)alloc((size_t)nblkL*256*4);

  hipLaunchKernelGGL(k_embed,  dim3((N*32+255)/256), dim3(256), 0, stream, emb, deg, xb, N);
  hipLaunchKernelGGL(k_bounds, dim3((N+255)/256),    dim3(256), 0, stream, batch, gs, N, B);
  hipLaunchKernelGGL(k_wprep,  dim3(L*16),           dim3(256), 0, stream, Wl, Wr, Wt);
  // CSR build (atomic-free)
  hipLaunchKernelGGL(k_hist,   dim3(64),  dim3(256), 0, stream, ei, blkhist, NB, E, chunk);
  int nblk25 = (n25 + 1023) / 1024;
  hipLaunchKernelGGL(k_scanA,  dim3(nblk25), dim3(256), 0, stream, blkhist, bases, bsum, n25);
  hipLaunchKernelGGL(k_scanB,  dim3(1),      dim3(64),  0, stream, bsum, boff, nblk25);
  hipLaunchKernelGGL(k_scanC,  dim3((n25+255)/256), dim3(256), 0, stream, bases, boff, n25);
  hipLaunchKernelGGL(k_place,  dim3(64),  dim3(256), 0, stream, ei, bases, pairs, NB, E, chunk);
  hipLaunchKernelGGL(k_cnt_place, dim3(NB), dim3(256), 0, stream, pairs, bases, rowptr, col, NB, N, E);

  float invN = 1.0f / (float)N;
  for (int l = 0; l < L; l++){
    hipLaunchKernelGGL(k_agg,    dim3((N+3)/4),  dim3(256), 0, stream, xb, rowptr, col, meanb, N);
    hipLaunchKernelGGL(k_linear, dim3(nblkL),    dim3(256), 0, stream,
                       meanb, xb, Wt + (size_t)l*H*256, bl + (size_t)l*H, x2,
                       pstats, N);
    hipLaunchKernelGGL(k_statred,dim3(256),      dim3(256), 0, stream, pstats, stats + l*2*H, nblkL);
    hipLaunchKernelGGL(k_bnrelu, dim3((N*32+255)/256), dim3(256), 0, stream,
                       x2, stats + l*2*H, gamma + (size_t)l*H, beta + (size_t)l*H, xb, N, invN);
  }
  hipLaunchKernelGGL(k_scores, dim3((N+63)/64), dim3(256), 0, stream, xb, attn_W, attn_b, escore, N);
  hipLaunchKernelGGL(k_denom,  dim3(B),         dim3(256), 0, stream, escore, gs, gsum);
  hipLaunchKernelGGL(k_clust,  dim3(B*16),      dim3(256), 0, stream, xb, escore, gs, partial);
  hipLaunchKernelGGL(k_out,    dim3(B*C/2),     dim3(256), 0, stream, partial, gsum, out_W, out_b, out);
}

// Round 8
// 347.717 us; speedup vs baseline: 2.3211x; 1.1400x over previous
//
#include <hip/hip_runtime.h>

typedef unsigned short u16;
typedef unsigned int   u32;

#define H    128
#define C    16
#define ODIM 128

typedef short bf16x8 __attribute__((ext_vector_type(8)));
typedef float f32x4  __attribute__((ext_vector_type(4)));

#define WSP 272   // Ws row stride (u16)
#define NP  256   // CSR partitions

__device__ __forceinline__ float bf2f(u32 v){
  union { u32 i; float f; } t; t.i = v << 16; return t.f;
}
__device__ __forceinline__ u16 f2bf(float f){
  u32 u = __float_as_uint(f);
  u32 r = u + 0x7fffu + ((u >> 16) & 1u);   // RNE
  return (u16)(r >> 16);
}
__device__ __forceinline__ u32 pack2(float a, float b){
  return (u32)f2bf(a) | ((u32)f2bf(b) << 16);
}

// ---------------- fused setup: embed | bounds | wprep | hist ----------------
__global__ __launch_bounds__(256) void k_setup(const float* __restrict__ emb,
    const int* __restrict__ deg, u16* __restrict__ xb,
    const int* __restrict__ batch, int* __restrict__ gs,
    const float* __restrict__ Wl, const float* __restrict__ Wr,
    u16* __restrict__ Wt, const int* __restrict__ ei,
    int* __restrict__ blkhist, int N, int B, int NB, int E, int chunk,
    int g0, int g1, int g2){
  __shared__ __align__(16) char smem[4608];
  int bid = blockIdx.x, tid = threadIdx.x;
  if (bid < g0){
    // ---- embed ----
    int i = bid*256 + tid;
    if (i < N*32){
      int n = i >> 5, q = i & 31;
      int d = deg[n];
      float4 v = ((const float4*)(emb + (size_t)d*H))[q];
      uint2 o; o.x = pack2(v.x, v.y); o.y = pack2(v.z, v.w);
      ((uint2*)(xb + (size_t)n*H))[q] = o;
    }
  } else if (bid < g1){
    // ---- bounds ----
    int n = (bid - g0)*256 + tid;
    if (n < N){
      int b = batch[n];
      if (n == 0){ for (int g = 0; g <= b; g++) gs[g] = 0; }
      else {
        int pb = batch[n-1];
        for (int g = pb+1; g <= b; g++) gs[g] = n;
      }
      if (n == N-1){ for (int g = b+1; g <= B; g++) gs[g] = N; }
    }
  } else if (bid < g2){
    // ---- wprep: Wt[l][h][k] ----
    u16 (*T)[18] = (u16(*)[18])smem;
    int b = bid - g1;
    int strip = b & 7, half = (b >> 3) & 1, l = b >> 4;
    const float* M = (half ? Wr : Wl) + (size_t)l*H*H;
    int k0 = strip * 16;
    #pragma unroll
    for (int j = 0; j < 8; j++){
      int u = tid + j*256;
      int kk = u >> 7, h = u & 127;
      T[h][kk] = f2bf(M[(size_t)(k0 + kk)*H + h]);
    }
    __syncthreads();
    #pragma unroll
    for (int j = 0; j < 8; j++){
      int u = tid + j*256;
      int h = u >> 4, k16 = u & 15;
      Wt[((size_t)(l*H + h))*256 + half*128 + k0 + k16] = T[h][k16];
    }
  } else {
    // ---- hist ----
    int* hist = (int*)smem;
    int blk = bid - g2;
    for (int b = tid; b < NB; b += 256) hist[b] = 0;
    __syncthreads();
    int start = blk*chunk, end = min(E, start + chunk);
    for (int e = start + tid; e < end; e += 256)
      atomicAdd(&hist[ei[E + e] >> 7], 1);
    __syncthreads();
    for (int b = tid; b < NB; b += 256) blkhist[b*NP + blk] = hist[b];
  }
}

// generic scan over n ints (1024 per block)
__global__ __launch_bounds__(256) void k_scanA(const int* __restrict__ in,
    int* __restrict__ out, int* __restrict__ bsum, int n){
  __shared__ int wsum[4];
  int tid = threadIdx.x;
  int base = blockIdx.x*1024 + tid*4;
  int v0 = (base+0 < n) ? in[base+0] : 0;
  int v1 = (base+1 < n) ? in[base+1] : 0;
  int v2 = (base+2 < n) ? in[base+2] : 0;
  int v3 = (base+3 < n) ? in[base+3] : 0;
  int tsum = v0+v1+v2+v3;
  int lane = tid & 63, w = tid >> 6;
  int incl = tsum;
  for (int d = 1; d < 64; d <<= 1){
    int t = __shfl_up(incl, d, 64);
    if (lane >= d) incl += t;
  }
  if (lane == 63) wsum[w] = incl;
  __syncthreads();
  int woff = 0;
  for (int i = 0; i < w; i++) woff += wsum[i];
  int excl = woff + incl - tsum;
  if (base+0 < n) out[base+0] = excl;
  if (base+1 < n) out[base+1] = excl + v0;
  if (base+2 < n) out[base+2] = excl + v0 + v1;
  if (base+3 < n) out[base+3] = excl + v0 + v1 + v2;
  if (tid == 255) bsum[blockIdx.x] = woff + incl;
}

// scan of up to 256 block sums
__global__ __launch_bounds__(256) void k_scanB(const int* __restrict__ bsum,
    int* __restrict__ boff, int nb){
  __shared__ int ws[4];
  int tid = threadIdx.x;
  int v = (tid < nb) ? bsum[tid] : 0;
  int lane = tid & 63, w = tid >> 6;
  int incl = v;
  for (int d = 1; d < 64; d <<= 1){
    int t = __shfl_up(incl, d, 64);
    if (lane >= d) incl += t;
  }
  if (lane == 63) ws[w] = incl;
  __syncthreads();
  int woff = 0;
  for (int i = 0; i < w; i++) woff += ws[i];
  boff[tid] = woff + incl - v;
}

__global__ __launch_bounds__(256) void k_scanC(int* __restrict__ out,
    const int* __restrict__ boff, int n){
  int i = blockIdx.x*256 + threadIdx.x;
  if (i < n) out[i] += boff[i >> 10];
}

// place edges bucket-sorted as (src,dst) pairs
__global__ __launch_bounds__(256) void k_place(const int* __restrict__ ei,
    const int* __restrict__ bases, int2* __restrict__ pairs,
    int NB, int E, int chunk){
  __shared__ int cursor[400];
  int blk = blockIdx.x, tid = threadIdx.x;
  for (int b = tid; b < NB; b += 256) cursor[b] = bases[b*NP + blk];
  __syncthreads();
  int start = blk*chunk, end = min(E, start + chunk);
  for (int e = start + tid; e < end; e += 256){
    int s = ei[e], d = ei[E + e];
    int pos = atomicAdd(&cursor[d >> 7], 1);
    pairs[pos] = make_int2(s, d);
  }
}

// per bucket: per-node counts -> rowptr (direct), then node-sort col
__global__ __launch_bounds__(256) void k_cnt_place(const int2* __restrict__ pairs,
    const int* __restrict__ bases, int* __restrict__ rowptr,
    int* __restrict__ col, int NB, int N, int E){
  int b = blockIdx.x, tid = threadIdx.x;
  int bstart = bases[b*NP];
  int bend   = (b+1 < NB) ? bases[(b+1)*NP] : E;
  __shared__ int cnt[128], sc[128], rank[128];
  if (tid < 128) cnt[tid] = 0;
  __syncthreads();
  for (int e = bstart + tid; e < bend; e += 256)
    atomicAdd(&cnt[pairs[e].y & 127], 1);
  __syncthreads();
  if (tid < 128) sc[tid] = cnt[tid];
  for (int d = 1; d < 128; d <<= 1){
    int v = 0;
    __syncthreads();
    if (tid < 128 && tid >= d) v = sc[tid - d];
    __syncthreads();
    if (tid < 128) sc[tid] += v;
  }
  __syncthreads();
  if (tid < 128){
    int excl = sc[tid] - cnt[tid];
    rank[tid] = bstart + excl;
    int node = b*128 + tid;
    if (node < N) rowptr[node] = bstart + excl;
  }
  if (b == NB-1 && tid == 0) rowptr[N] = E;
  __syncthreads();
  for (int e = bstart + tid; e < bend; e += 256){
    int2 p = pairs[e];
    int pos = atomicAdd(&rank[p.y & 127], 1);
    col[pos] = p.x;
  }
}

// ---------------- per-layer ----------------
// wave per node, 8 edges in flight (4 groups x unroll 2, uint4 per lane)
__global__ __launch_bounds__(256) void k_agg(const u16* __restrict__ x,
    const int* __restrict__ rowptr, const int* __restrict__ col,
    u16* __restrict__ meanb, int N){
  int wid  = (blockIdx.x*256 + threadIdx.x) >> 6;
  int lane = threadIdx.x & 63;
  if (wid >= N) return;
  int r0 = rowptr[wid], r1 = rowptr[wid+1];
  int grp = lane >> 4, fl = lane & 15;
  const u16* xf = x + fl*8;
  float a0=0.f,a1=0.f,a2=0.f,a3=0.f,a4=0.f,a5=0.f,a6=0.f,a7=0.f;
  int e = r0 + grp;
  for (; e + 4 < r1; e += 8){
    int s0 = col[e], s1 = col[e+4];
    uint4 v = *(const uint4*)(xf + (size_t)s0*H);
    uint4 u = *(const uint4*)(xf + (size_t)s1*H);
    a0 += bf2f(v.x & 0xffff) + bf2f(u.x & 0xffff);
    a1 += bf2f(v.x >> 16)    + bf2f(u.x >> 16);
    a2 += bf2f(v.y & 0xffff) + bf2f(u.y & 0xffff);
    a3 += bf2f(v.y >> 16)    + bf2f(u.y >> 16);
    a4 += bf2f(v.z & 0xffff) + bf2f(u.z & 0xffff);
    a5 += bf2f(v.z >> 16)    + bf2f(u.z >> 16);
    a6 += bf2f(v.w & 0xffff) + bf2f(u.w & 0xffff);
    a7 += bf2f(v.w >> 16)    + bf2f(u.w >> 16);
  }
  if (e < r1){
    uint4 v = *(const uint4*)(xf + (size_t)col[e]*H);
    a0 += bf2f(v.x & 0xffff); a1 += bf2f(v.x >> 16);
    a2 += bf2f(v.y & 0xffff); a3 += bf2f(v.y >> 16);
    a4 += bf2f(v.z & 0xffff); a5 += bf2f(v.z >> 16);
    a6 += bf2f(v.w & 0xffff); a7 += bf2f(v.w >> 16);
  }
  a0 += __shfl_xor(a0,16,64); a1 += __shfl_xor(a1,16,64);
  a2 += __shfl_xor(a2,16,64); a3 += __shfl_xor(a3,16,64);
  a4 += __shfl_xor(a4,16,64); a5 += __shfl_xor(a5,16,64);
  a6 += __shfl_xor(a6,16,64); a7 += __shfl_xor(a7,16,64);
  a0 += __shfl_xor(a0,32,64); a1 += __shfl_xor(a1,32,64);
  a2 += __shfl_xor(a2,32,64); a3 += __shfl_xor(a3,32,64);
  a4 += __shfl_xor(a4,32,64); a5 += __shfl_xor(a5,32,64);
  a6 += __shfl_xor(a6,32,64); a7 += __shfl_xor(a7,32,64);
  if (grp == 0){
    float invc = 1.0f / (float)max(r1 - r0, 1);
    uint4 o;
    o.x = pack2(a0*invc, a1*invc);
    o.y = pack2(a2*invc, a3*invc);
    o.z = pack2(a4*invc, a5*invc);
    o.w = pack2(a6*invc, a7*invc);
    *(uint4*)(meanb + (size_t)wid*H + fl*8) = o;
  }
}

// x2[n][h] = bl[h] + [meanb|xb] @ Wt^T via mfma_f32_16x16x32_bf16.
// Wt staged whole in LDS; A-fragments direct from global (latency overlapped
// with staging). Fused BN-stat partials -> pstats[blk][256].
__global__ __launch_bounds__(256) void k_linear(const u16* __restrict__ meanb,
    const u16* __restrict__ xb, const u16* __restrict__ Wt,
    const float* __restrict__ bl, float* __restrict__ x2,
    float* __restrict__ pstats, int N){
  __shared__ u16 Ws[128][WSP];         // 69.6 KB -> 2 blocks/CU
  __shared__ float Sh[128], Qh[128];
  int tid = threadIdx.x;
  if (tid < 128){ Sh[tid] = 0.f; Qh[tid] = 0.f; }
  int lane = tid & 63, w = tid >> 6;
  int mlane = lane & 15, quad = lane >> 4;
  int node = blockIdx.x*64 + w*16 + mlane;
  const u16* arow_m = meanb + (size_t)node*H + quad*8;
  const u16* arow_x = xb   + (size_t)node*H + quad*8;
  bf16x8 af[8];
  #pragma unroll
  for (int kk = 0; kk < 4; kk++){
    af[kk]     = *(const bf16x8*)(arow_m + kk*32);
    af[kk + 4] = *(const bf16x8*)(arow_x + kk*32);
  }
  #pragma unroll
  for (int j = 0; j < 16; j++){
    int u = tid + j*256;
    int row = u >> 5, seg = u & 31;
    uint4 v = ((const uint4*)(Wt + (size_t)row*256))[seg];
    *(uint4*)&Ws[row][seg*8] = v;
  }
  __syncthreads();
  f32x4 acc[8];
  #pragma unroll
  for (int t = 0; t < 8; t++) acc[t] = (f32x4){0.f, 0.f, 0.f, 0.f};
  #pragma unroll
  for (int kk = 0; kk < 8; kk++){
    #pragma unroll
    for (int t = 0; t < 8; t++){
      bf16x8 b = *(const bf16x8*)&Ws[t*16 + mlane][kk*32 + quad*8];
      acc[t] = __builtin_amdgcn_mfma_f32_16x16x32_bf16(af[kk], b, acc[t], 0, 0, 0);
    }
  }
  #pragma unroll
  for (int t = 0; t < 8; t++){
    int h = t*16 + mlane;
    float bv = bl[h];
    float s = 0.f, q = 0.f;
    #pragma unroll
    for (int r = 0; r < 4; r++){
      int nd = blockIdx.x*64 + w*16 + quad*4 + r;
      if (nd < N){
        float v = acc[t][r] + bv;
        x2[(size_t)nd*H + h] = v;
        s += v; q = fmaf(v, v, q);
      }
    }
    s += __shfl_xor(s, 16, 64); s += __shfl_xor(s, 32, 64);
    q += __shfl_xor(q, 16, 64); q += __shfl_xor(q, 32, 64);
    if (quad == 0){
      atomicAdd(&Sh[h], s);
      atomicAdd(&Qh[h], q);
    }
  }
  __syncthreads();
  {
    float v = (tid < 128) ? Sh[tid] : Qh[tid - 128];
    pstats[(size_t)blockIdx.x*256 + tid] = v;
  }
}

// reduce pstats[nblk][256] -> stats[256]
__global__ __launch_bounds__(256) void k_statred(const float* __restrict__ pstats,
    float* __restrict__ stats, int nblk){
  __shared__ float red[4];
  int c = blockIdx.x, tid = threadIdx.x;
  float s = 0.f;
  for (int b = tid; b < nblk; b += 256)
    s += pstats[(size_t)b*256 + c];
  s += __shfl_xor(s, 1, 64);  s += __shfl_xor(s, 2, 64);
  s += __shfl_xor(s, 4, 64);  s += __shfl_xor(s, 8, 64);
  s += __shfl_xor(s, 16, 64); s += __shfl_xor(s, 32, 64);
  if ((tid & 63) == 0) red[tid >> 6] = s;
  __syncthreads();
  if (tid == 0) stats[c] = red[0] + red[1] + red[2] + red[3];
}

// BN+ReLU; when do_scores!=0 also computes escore for this block's 8 nodes
// from LDS (fuses k_scores, saves a full xb re-read).
__global__ __launch_bounds__(256) void k_bnrelu(const float* __restrict__ x2,
    const float* __restrict__ stats, const float* __restrict__ gamma,
    const float* __restrict__ beta, u16* __restrict__ xb, int N, float invN,
    const float* __restrict__ attn_W, const float* __restrict__ attn_b,
    float* __restrict__ escore, int do_scores){
  __shared__ float xs[8][132];
  __shared__ float aw[H*C];
  __shared__ float ab[C];
  int tid = threadIdx.x;
  int i = blockIdx.x*256 + tid;
  bool active = (i < N*32);
  int h = (tid & 31) * 4;            // tid&31 spans features, i>>5 = node
  float r[4] = {0.f, 0.f, 0.f, 0.f};
  if (active){
    float4 v = ((const float4*)x2)[i];
    float vv[4] = {v.x, v.y, v.z, v.w};
    #pragma unroll
    for (int j = 0; j < 4; j++){
      float mu  = stats[h+j] * invN;
      float var = fmaf(-mu, mu, stats[H + h + j] * invN);
      float sc  = rsqrtf(var + 1e-5f) * gamma[h+j];
      float bi  = beta[h+j];
      r[j] = fmaxf(fmaf(vv[j] - mu, sc, bi), 0.0f);
    }
    uint2 o; o.x = pack2(r[0], r[1]); o.y = pack2(r[2], r[3]);
    ((uint2*)xb)[i] = o;
  }
  if (do_scores){
    #pragma unroll
    for (int j = 0; j < 8; j++) aw[tid + j*256] = attn_W[tid + j*256];
    if (tid < C) ab[tid] = attn_b[tid];
    int ln = tid >> 5;               // local node 0..7
    if (active){
      xs[ln][h+0]=r[0]; xs[ln][h+1]=r[1]; xs[ln][h+2]=r[2]; xs[ln][h+3]=r[3];
    }
    __syncthreads();
    if (tid < 128){
      int n2 = tid >> 4, c = tid & 15;
      int node = blockIdx.x*8 + n2;
      if (node < N){
        float acc = ab[c];
        #pragma unroll 4
        for (int k = 0; k < H; k++)
          acc = fmaf(xs[n2][k], aw[k*C + c], acc);
        escore[(size_t)node*C + c] = __expf(acc);
      }
    }
  }
}

__global__ __launch_bounds__(256) void k_denom(const float* __restrict__ escore,
    const int* __restrict__ gs, float* __restrict__ gsum){
  int g = blockIdx.x;
  int c = threadIdx.x & 15, sub = threadIdx.x >> 4;
  int a = gs[g], b = gs[g+1];
  float s = 0.f;
  for (int n = a + sub; n < b; n += 16) s += escore[(size_t)n*C + c];
  __shared__ float part[16][17];
  part[sub][c] = s;
  for (int off2 = 8; off2 > 0; off2 >>= 1){
    __syncthreads();
    if (sub < off2) part[sub][c] += part[sub + off2][c];
  }
  __syncthreads();
  if (threadIdx.x < C) gsum[(size_t)g*C + threadIdx.x] = part[0][threadIdx.x];
}

// partial[g][b][c][h] = strided-node partial of escore[n][c]*x[n][h]
__global__ __launch_bounds__(256) void k_clust(const u16* __restrict__ xb,
    const float* __restrict__ escore, const int* __restrict__ gs,
    float* __restrict__ partial){
  int g = blockIdx.x >> 4, b = blockIdx.x & 15;
  int h = threadIdx.x & 127, cg = threadIdx.x >> 7;
  int a = gs[g], e2 = gs[g+1];
  float acc[8] = {0,0,0,0,0,0,0,0};
  for (int n = a + b; n < e2; n += 16){
    float xv = bf2f(xb[(size_t)n*H + h]);
    const float4* ep = (const float4*)(escore + (size_t)n*C) + cg*2;
    float4 e0 = ep[0], e1 = ep[1];
    acc[0] = fmaf(e0.x, xv, acc[0]);
    acc[1] = fmaf(e0.y, xv, acc[1]);
    acc[2] = fmaf(e0.z, xv, acc[2]);
    acc[3] = fmaf(e0.w, xv, acc[3]);
    acc[4] = fmaf(e1.x, xv, acc[4]);
    acc[5] = fmaf(e1.y, xv, acc[5]);
    acc[6] = fmaf(e1.z, xv, acc[6]);
    acc[7] = fmaf(e1.w, xv, acc[7]);
  }
  int c0 = cg*8;
  float* dst = partial + (((size_t)(g*16 + b))*C)*H + h;
  #pragma unroll
  for (int r = 0; r < 8; r++)
    dst[(size_t)(c0 + r)*H] = acc[r];
}

__global__ __launch_bounds__(256) void k_out(const float* __restrict__ partial,
    const float* __restrict__ gsum, const float* __restrict__ out_W,
    const float* __restrict__ out_b, float* __restrict__ out){
  __shared__ float cs[2][128];
  int tid = threadIdx.x;
  int r = tid >> 7, h = tid & 127;
  int row = blockIdx.x*2 + r;          // (g,c) flat
  int g = row >> 4, c = row & 15;
  float s = 0.f;
  for (int b = 0; b < 16; b++)
    s += partial[(((size_t)(g*16 + b))*C + c)*H + h];
  cs[r][h] = s;
  __syncthreads();
  float gden = gsum[row];
  float inv = gden > 0.f ? 1.0f / gden : 0.f;
  float acc = 0.f;
  for (int hh = 0; hh < H; hh++)
    acc = fmaf(cs[r][hh], out_W[hh*ODIM + h], acc);
  out[(size_t)row*ODIM + h] = fmaf(acc, inv, out_b[h]);
}

// ---------------- host ----------------
extern "C" void kernel_launch(void* const* d_in, const int* in_sizes, int n_in,
                              void* d_out, int out_size, void* d_ws, size_t ws_size,
                              hipStream_t stream){
  const float* emb    = (const float*)d_in[0];
  const float* Wl     = (const float*)d_in[1];
  const float* bl     = (const float*)d_in[2];
  const float* Wr     = (const float*)d_in[3];
  const float* gamma  = (const float*)d_in[4];
  const float* beta   = (const float*)d_in[5];
  const float* attn_W = (const float*)d_in[6];
  const float* attn_b = (const float*)d_in[7];
  const float* out_W  = (const float*)d_in[8];
  const float* out_b  = (const float*)d_in[9];
  const int* deg    = (const int*)d_in[10];
  const int* ei     = (const int*)d_in[11];
  const int* batch  = (const int*)d_in[12];
  float* out = (float*)d_out;

  const int N = in_sizes[10];
  const int E = in_sizes[11] / 2;
  const int L = in_sizes[1] / (H*H);
  const int B = out_size / (C*ODIM);
  const int NB = (N + 127) >> 7;        // buckets of 128 nodes
  const int nbh = NB * NP;              // blkhist elements
  const int chunk = (E + NP - 1) / NP;  // edges per hist/place block
  const int nblkL = (N + 63) / 64;      // k_linear grid

  size_t off = 0;
  auto alloc = [&](size_t bytes) -> void* {
    void* p = (char*)d_ws + off;
    off += (bytes + 255) & ~(size_t)255;
    return p;
  };
  u16*   xb     = (u16*)  alloc((size_t)N*H*2);
  u16*   meanb  = (u16*)  alloc((size_t)N*H*2);
  float* x2     = (float*)alloc((size_t)N*H*4);  // aliased: pairs (CSR), partial (pooling)
  int2*  pairs  = (int2*)x2;
  float* partial= x2;
  u16*   Wt     = (u16*)  alloc((size_t)L*H*256*2);
  float* escore = (float*)alloc((size_t)N*C*4);
  int*   col    = (int*)  alloc((size_t)E*4);
  int*   rowptr = (int*)  alloc((size_t)(N+1)*4);
  int*   blkhist= (int*)  alloc((size_t)nbh*4);
  int*   bases  = (int*)  alloc((size_t)nbh*4);
  int*   bsum   = (int*)  alloc(256*4);
  int*   boff   = (int*)  alloc(256*4);
  int*   gs     = (int*)  alloc((size_t)(B+1)*4);
  float* gsum   = (float*)alloc((size_t)B*C*4);
  float* stats  = (float*)alloc((size_t)L*2*H*4);
  float* pstats = (float*)alloc((size_t)nblkL*256*4);

  // fused setup
  int g0 = (N*32 + 255)/256;            // embed blocks
  int g1 = g0 + (N + 255)/256;          // + bounds
  int g2 = g1 + L*16;                   // + wprep
  int gT = g2 + NP;                     // + hist
  hipLaunchKernelGGL(k_setup, dim3(gT), dim3(256), 0, stream,
                     emb, deg, xb, batch, gs, Wl, Wr, Wt, ei, blkhist,
                     N, B, NB, E, chunk, g0, g1, g2);
  int nblkS = (nbh + 1023) / 1024;
  hipLaunchKernelGGL(k_scanA,  dim3(nblkS), dim3(256), 0, stream, blkhist, bases, bsum, nbh);
  hipLaunchKernelGGL(k_scanB,  dim3(1),     dim3(256), 0, stream, bsum, boff, nblkS);
  hipLaunchKernelGGL(k_scanC,  dim3((nbh+255)/256), dim3(256), 0, stream, bases, boff, nbh);
  hipLaunchKernelGGL(k_place,  dim3(NP), dim3(256), 0, stream, ei, bases, pairs, NB, E, chunk);
  hipLaunchKernelGGL(k_cnt_place, dim3(NB), dim3(256), 0, stream, pairs, bases, rowptr, col, NB, N, E);

  float invN = 1.0f / (float)N;
  for (int l = 0; l < L; l++){
    hipLaunchKernelGGL(k_agg,    dim3((N+3)/4),  dim3(256), 0, stream, xb, rowptr, col, meanb, N);
    hipLaunchKernelGGL(k_linear, dim3(nblkL),    dim3(256), 0, stream,
                       meanb, xb, Wt + (size_t)l*H*256, bl + (size_t)l*H, x2,
                       pstats, N);
    hipLaunchKernelGGL(k_statred,dim3(256),      dim3(256), 0, stream, pstats, stats + l*2*H, nblkL);
    hipLaunchKernelGGL(k_bnrelu, dim3((N*32+255)/256), dim3(256), 0, stream,
                       x2, stats + l*2*H, gamma + (size_t)l*H, beta + (size_t)l*H,
                       xb, N, invN, attn_W, attn_b, escore, (l == L-1) ? 1 : 0);
  }
  hipLaunchKernelGGL(k_denom,  dim3(B),     dim3(256), 0, stream, escore, gs, gsum);
  hipLaunchKernelGGL(k_clust,  dim3(B*16),  dim3(256), 0, stream, xb, escore, gs, partial);
  hipLaunchKernelGGL(k_out,    dim3(B*C/2), dim3(256), 0, stream, partial, gsum, out_W, out_b, out);
}

// Round 9
// 337.470 us; speedup vs baseline: 2.3916x; 1.0304x over previous
//
#include <hip/hip_runtime.h>

typedef unsigned short u16;
typedef unsigned int   u32;

#define H    128
#define C    16
#define ODIM 128

typedef short bf16x8 __attribute__((ext_vector_type(8)));
typedef float f32x4  __attribute__((ext_vector_type(4)));
typedef float f32x2v __attribute__((ext_vector_type(2)));

#define WSP 272   // Ws row stride (u16)
#define NP  256   // CSR partitions

__device__ __forceinline__ float bf2f(u32 v){
  union { u32 i; float f; } t; t.i = v << 16; return t.f;
}
__device__ __forceinline__ u16 f2bf(float f){
  u32 u = __float_as_uint(f);
  u32 r = u + 0x7fffu + ((u >> 16) & 1u);   // RNE
  return (u16)(r >> 16);
}
__device__ __forceinline__ u32 pack2(float a, float b){
  return (u32)f2bf(a) | ((u32)f2bf(b) << 16);
}
__device__ __forceinline__ u32 pack_fp8x4(float a, float b, float c, float d){
  int p = __builtin_amdgcn_cvt_pk_fp8_f32(a, b, 0, false);
  p     = __builtin_amdgcn_cvt_pk_fp8_f32(c, d, p, true);
  return (u32)p;
}

// ---------------- fused setup: embed | bounds | wprep | hist ----------------
__global__ __launch_bounds__(256) void k_setup(const float* __restrict__ emb,
    const int* __restrict__ deg, u16* __restrict__ xb, u32* __restrict__ xq,
    const int* __restrict__ batch, int* __restrict__ gs,
    const float* __restrict__ Wl, const float* __restrict__ Wr,
    u16* __restrict__ Wt, const int* __restrict__ ei,
    int* __restrict__ blkhist, int N, int B, int NB, int E, int chunk,
    int g0, int g1, int g2){
  __shared__ __align__(16) char smem[4608];
  int bid = blockIdx.x, tid = threadIdx.x;
  if (bid < g0){
    // ---- embed ----
    int i = bid*256 + tid;
    if (i < N*32){
      int n = i >> 5, q = i & 31;
      int d = deg[n];
      float4 v = ((const float4*)(emb + (size_t)d*H))[q];
      uint2 o; o.x = pack2(v.x, v.y); o.y = pack2(v.z, v.w);
      ((uint2*)(xb + (size_t)n*H))[q] = o;
      xq[i] = pack_fp8x4(v.x, v.y, v.z, v.w);
    }
  } else if (bid < g1){
    // ---- bounds ----
    int n = (bid - g0)*256 + tid;
    if (n < N){
      int b = batch[n];
      if (n == 0){ for (int g = 0; g <= b; g++) gs[g] = 0; }
      else {
        int pb = batch[n-1];
        for (int g = pb+1; g <= b; g++) gs[g] = n;
      }
      if (n == N-1){ for (int g = b+1; g <= B; g++) gs[g] = N; }
    }
  } else if (bid < g2){
    // ---- wprep: Wt[l][h][k] ----
    u16 (*T)[18] = (u16(*)[18])smem;
    int b = bid - g1;
    int strip = b & 7, half = (b >> 3) & 1, l = b >> 4;
    const float* M = (half ? Wr : Wl) + (size_t)l*H*H;
    int k0 = strip * 16;
    #pragma unroll
    for (int j = 0; j < 8; j++){
      int u = tid + j*256;
      int kk = u >> 7, h = u & 127;
      T[h][kk] = f2bf(M[(size_t)(k0 + kk)*H + h]);
    }
    __syncthreads();
    #pragma unroll
    for (int j = 0; j < 8; j++){
      int u = tid + j*256;
      int h = u >> 4, k16 = u & 15;
      Wt[((size_t)(l*H + h))*256 + half*128 + k0 + k16] = T[h][k16];
    }
  } else {
    // ---- hist ----
    int* hist = (int*)smem;
    int blk = bid - g2;
    for (int b = tid; b < NB; b += 256) hist[b] = 0;
    __syncthreads();
    int start = blk*chunk, end = min(E, start + chunk);
    for (int e = start + tid; e < end; e += 256)
      atomicAdd(&hist[ei[E + e] >> 7], 1);
    __syncthreads();
    for (int b = tid; b < NB; b += 256) blkhist[b*NP + blk] = hist[b];
  }
}

// generic scan over n ints (1024 per block)
__global__ __launch_bounds__(256) void k_scanA(const int* __restrict__ in,
    int* __restrict__ out, int* __restrict__ bsum, int n){
  __shared__ int wsum[4];
  int tid = threadIdx.x;
  int base = blockIdx.x*1024 + tid*4;
  int v0 = (base+0 < n) ? in[base+0] : 0;
  int v1 = (base+1 < n) ? in[base+1] : 0;
  int v2 = (base+2 < n) ? in[base+2] : 0;
  int v3 = (base+3 < n) ? in[base+3] : 0;
  int tsum = v0+v1+v2+v3;
  int lane = tid & 63, w = tid >> 6;
  int incl = tsum;
  for (int d = 1; d < 64; d <<= 1){
    int t = __shfl_up(incl, d, 64);
    if (lane >= d) incl += t;
  }
  if (lane == 63) wsum[w] = incl;
  __syncthreads();
  int woff = 0;
  for (int i = 0; i < w; i++) woff += wsum[i];
  int excl = woff + incl - tsum;
  if (base+0 < n) out[base+0] = excl;
  if (base+1 < n) out[base+1] = excl + v0;
  if (base+2 < n) out[base+2] = excl + v0 + v1;
  if (base+3 < n) out[base+3] = excl + v0 + v1 + v2;
  if (tid == 255) bsum[blockIdx.x] = woff + incl;
}

// scan of up to 256 block sums
__global__ __launch_bounds__(256) void k_scanB(const int* __restrict__ bsum,
    int* __restrict__ boff, int nb){
  __shared__ int ws[4];
  int tid = threadIdx.x;
  int v = (tid < nb) ? bsum[tid] : 0;
  int lane = tid & 63, w = tid >> 6;
  int incl = v;
  for (int d = 1; d < 64; d <<= 1){
    int t = __shfl_up(incl, d, 64);
    if (lane >= d) incl += t;
  }
  if (lane == 63) ws[w] = incl;
  __syncthreads();
  int woff = 0;
  for (int i = 0; i < w; i++) woff += ws[i];
  boff[tid] = woff + incl - v;
}

__global__ __launch_bounds__(256) void k_scanC(int* __restrict__ out,
    const int* __restrict__ boff, int n){
  int i = blockIdx.x*256 + threadIdx.x;
  if (i < n) out[i] += boff[i >> 10];
}

// place edges bucket-sorted as (src,dst) pairs
__global__ __launch_bounds__(256) void k_place(const int* __restrict__ ei,
    const int* __restrict__ bases, int2* __restrict__ pairs,
    int NB, int E, int chunk){
  __shared__ int cursor[400];
  int blk = blockIdx.x, tid = threadIdx.x;
  for (int b = tid; b < NB; b += 256) cursor[b] = bases[b*NP + blk];
  __syncthreads();
  int start = blk*chunk, end = min(E, start + chunk);
  for (int e = start + tid; e < end; e += 256){
    int s = ei[e], d = ei[E + e];
    int pos = atomicAdd(&cursor[d >> 7], 1);
    pairs[pos] = make_int2(s, d);
  }
}

// per bucket: per-node counts -> rowptr (direct), then node-sort col
__global__ __launch_bounds__(256) void k_cnt_place(const int2* __restrict__ pairs,
    const int* __restrict__ bases, int* __restrict__ rowptr,
    int* __restrict__ col, int NB, int N, int E){
  int b = blockIdx.x, tid = threadIdx.x;
  int bstart = bases[b*NP];
  int bend   = (b+1 < NB) ? bases[(b+1)*NP] : E;
  __shared__ int cnt[128], sc[128], rank[128];
  if (tid < 128) cnt[tid] = 0;
  __syncthreads();
  for (int e = bstart + tid; e < bend; e += 256)
    atomicAdd(&cnt[pairs[e].y & 127], 1);
  __syncthreads();
  if (tid < 128) sc[tid] = cnt[tid];
  for (int d = 1; d < 128; d <<= 1){
    int v = 0;
    __syncthreads();
    if (tid < 128 && tid >= d) v = sc[tid - d];
    __syncthreads();
    if (tid < 128) sc[tid] += v;
  }
  __syncthreads();
  if (tid < 128){
    int excl = sc[tid] - cnt[tid];
    rank[tid] = bstart + excl;
    int node = b*128 + tid;
    if (node < N) rowptr[node] = bstart + excl;
  }
  if (b == NB-1 && tid == 0) rowptr[N] = E;
  __syncthreads();
  for (int e = bstart + tid; e < bend; e += 256){
    int2 p = pairs[e];
    int pos = atomicAdd(&rank[p.y & 127], 1);
    col[pos] = p.x;
  }
}

// ---------------- per-layer ----------------
// wave per node; gather from fp8 shadow xq (128 B/row). 4 groups x unroll 2 =
// 8 edges in flight; lane covers features fl*8..fl*8+7 (uint2 + HW fp8 cvt).
__global__ __launch_bounds__(256) void k_agg(const u32* __restrict__ xq,
    const int* __restrict__ rowptr, const int* __restrict__ col,
    u16* __restrict__ meanb, int N){
  int wid  = (blockIdx.x*256 + threadIdx.x) >> 6;
  int lane = threadIdx.x & 63;
  if (wid >= N) return;
  int r0 = rowptr[wid], r1 = rowptr[wid+1];
  int grp = lane >> 4, fl = lane & 15;
  const u32* xf = xq + fl*2;
  float a0=0.f,a1=0.f,a2=0.f,a3=0.f,a4=0.f,a5=0.f,a6=0.f,a7=0.f;
  int e = r0 + grp;
  for (; e + 4 < r1; e += 8){
    uint2 v = *(const uint2*)(xf + (size_t)col[e]*32);
    uint2 u = *(const uint2*)(xf + (size_t)col[e+4]*32);
    f32x2v p0 = __builtin_amdgcn_cvt_pk_f32_fp8((int)v.x, false);
    f32x2v p1 = __builtin_amdgcn_cvt_pk_f32_fp8((int)v.x, true);
    f32x2v p2 = __builtin_amdgcn_cvt_pk_f32_fp8((int)v.y, false);
    f32x2v p3 = __builtin_amdgcn_cvt_pk_f32_fp8((int)v.y, true);
    f32x2v q0 = __builtin_amdgcn_cvt_pk_f32_fp8((int)u.x, false);
    f32x2v q1 = __builtin_amdgcn_cvt_pk_f32_fp8((int)u.x, true);
    f32x2v q2 = __builtin_amdgcn_cvt_pk_f32_fp8((int)u.y, false);
    f32x2v q3 = __builtin_amdgcn_cvt_pk_f32_fp8((int)u.y, true);
    a0 += p0.x + q0.x; a1 += p0.y + q0.y;
    a2 += p1.x + q1.x; a3 += p1.y + q1.y;
    a4 += p2.x + q2.x; a5 += p2.y + q2.y;
    a6 += p3.x + q3.x; a7 += p3.y + q3.y;
  }
  if (e < r1){
    uint2 v = *(const uint2*)(xf + (size_t)col[e]*32);
    f32x2v p0 = __builtin_amdgcn_cvt_pk_f32_fp8((int)v.x, false);
    f32x2v p1 = __builtin_amdgcn_cvt_pk_f32_fp8((int)v.x, true);
    f32x2v p2 = __builtin_amdgcn_cvt_pk_f32_fp8((int)v.y, false);
    f32x2v p3 = __builtin_amdgcn_cvt_pk_f32_fp8((int)v.y, true);
    a0 += p0.x; a1 += p0.y; a2 += p1.x; a3 += p1.y;
    a4 += p2.x; a5 += p2.y; a6 += p3.x; a7 += p3.y;
  }
  a0 += __shfl_xor(a0,16,64); a1 += __shfl_xor(a1,16,64);
  a2 += __shfl_xor(a2,16,64); a3 += __shfl_xor(a3,16,64);
  a4 += __shfl_xor(a4,16,64); a5 += __shfl_xor(a5,16,64);
  a6 += __shfl_xor(a6,16,64); a7 += __shfl_xor(a7,16,64);
  a0 += __shfl_xor(a0,32,64); a1 += __shfl_xor(a1,32,64);
  a2 += __shfl_xor(a2,32,64); a3 += __shfl_xor(a3,32,64);
  a4 += __shfl_xor(a4,32,64); a5 += __shfl_xor(a5,32,64);
  a6 += __shfl_xor(a6,32,64); a7 += __shfl_xor(a7,32,64);
  if (grp == 0){
    float invc = 1.0f / (float)max(r1 - r0, 1);
    uint4 o;
    o.x = pack2(a0*invc, a1*invc);
    o.y = pack2(a2*invc, a3*invc);
    o.z = pack2(a4*invc, a5*invc);
    o.w = pack2(a6*invc, a7*invc);
    *(uint4*)(meanb + (size_t)wid*H + fl*8) = o;
  }
}

// x2[n][h] = bl[h] + [meanb|xb] @ Wt^T via mfma_f32_16x16x32_bf16.
// Wt staged whole in LDS; A-fragments direct from global. Fused BN-stat
// partials -> pstats[blk][256].
__global__ __launch_bounds__(256) void k_linear(const u16* __restrict__ meanb,
    const u16* __restrict__ xb, const u16* __restrict__ Wt,
    const float* __restrict__ bl, float* __restrict__ x2,
    float* __restrict__ pstats, int N){
  __shared__ u16 Ws[128][WSP];         // 69.6 KB -> 2 blocks/CU
  __shared__ float Sh[128], Qh[128];
  int tid = threadIdx.x;
  if (tid < 128){ Sh[tid] = 0.f; Qh[tid] = 0.f; }
  int lane = tid & 63, w = tid >> 6;
  int mlane = lane & 15, quad = lane >> 4;
  int node = blockIdx.x*64 + w*16 + mlane;
  const u16* arow_m = meanb + (size_t)node*H + quad*8;
  const u16* arow_x = xb   + (size_t)node*H + quad*8;
  bf16x8 af[8];
  #pragma unroll
  for (int kk = 0; kk < 4; kk++){
    af[kk]     = *(const bf16x8*)(arow_m + kk*32);
    af[kk + 4] = *(const bf16x8*)(arow_x + kk*32);
  }
  #pragma unroll
  for (int j = 0; j < 16; j++){
    int u = tid + j*256;
    int row = u >> 5, seg = u & 31;
    uint4 v = ((const uint4*)(Wt + (size_t)row*256))[seg];
    *(uint4*)&Ws[row][seg*8] = v;
  }
  __syncthreads();
  f32x4 acc[8];
  #pragma unroll
  for (int t = 0; t < 8; t++) acc[t] = (f32x4){0.f, 0.f, 0.f, 0.f};
  #pragma unroll
  for (int kk = 0; kk < 8; kk++){
    #pragma unroll
    for (int t = 0; t < 8; t++){
      bf16x8 b = *(const bf16x8*)&Ws[t*16 + mlane][kk*32 + quad*8];
      acc[t] = __builtin_amdgcn_mfma_f32_16x16x32_bf16(af[kk], b, acc[t], 0, 0, 0);
    }
  }
  #pragma unroll
  for (int t = 0; t < 8; t++){
    int h = t*16 + mlane;
    float bv = bl[h];
    float s = 0.f, q = 0.f;
    #pragma unroll
    for (int r = 0; r < 4; r++){
      int nd = blockIdx.x*64 + w*16 + quad*4 + r;
      if (nd < N){
        float v = acc[t][r] + bv;
        x2[(size_t)nd*H + h] = v;
        s += v; q = fmaf(v, v, q);
      }
    }
    s += __shfl_xor(s, 16, 64); s += __shfl_xor(s, 32, 64);
    q += __shfl_xor(q, 16, 64); q += __shfl_xor(q, 32, 64);
    if (quad == 0){
      atomicAdd(&Sh[h], s);
      atomicAdd(&Qh[h], q);
    }
  }
  __syncthreads();
  {
    float v = (tid < 128) ? Sh[tid] : Qh[tid - 128];
    pstats[(size_t)blockIdx.x*256 + tid] = v;
  }
}

// reduce pstats[nblk][256] -> stats[256]
__global__ __launch_bounds__(256) void k_statred(const float* __restrict__ pstats,
    float* __restrict__ stats, int nblk){
  __shared__ float red[4];
  int c = blockIdx.x, tid = threadIdx.x;
  float s = 0.f;
  for (int b = tid; b < nblk; b += 256)
    s += pstats[(size_t)b*256 + c];
  s += __shfl_xor(s, 1, 64);  s += __shfl_xor(s, 2, 64);
  s += __shfl_xor(s, 4, 64);  s += __shfl_xor(s, 8, 64);
  s += __shfl_xor(s, 16, 64); s += __shfl_xor(s, 32, 64);
  if ((tid & 63) == 0) red[tid >> 6] = s;
  __syncthreads();
  if (tid == 0) stats[c] = red[0] + red[1] + red[2] + red[3];
}

// BN+ReLU; writes xb (bf16) + xq (fp8 shadow for gather); when do_scores!=0
// also computes escore for this block's 8 nodes from LDS (fused k_scores).
__global__ __launch_bounds__(256) void k_bnrelu(const float* __restrict__ x2,
    const float* __restrict__ stats, const float* __restrict__ gamma,
    const float* __restrict__ beta, u16* __restrict__ xb, u32* __restrict__ xq,
    int N, float invN,
    const float* __restrict__ attn_W, const float* __restrict__ attn_b,
    float* __restrict__ escore, int do_scores){
  __shared__ float xs[8][132];
  __shared__ float aw[H*C];
  __shared__ float ab[C];
  int tid = threadIdx.x;
  int i = blockIdx.x*256 + tid;
  bool active = (i < N*32);
  int h = (tid & 31) * 4;
  float r[4] = {0.f, 0.f, 0.f, 0.f};
  if (active){
    float4 v = ((const float4*)x2)[i];
    float vv[4] = {v.x, v.y, v.z, v.w};
    #pragma unroll
    for (int j = 0; j < 4; j++){
      float mu  = stats[h+j] * invN;
      float var = fmaf(-mu, mu, stats[H + h + j] * invN);
      float sc  = rsqrtf(var + 1e-5f) * gamma[h+j];
      float bi  = beta[h+j];
      r[j] = fmaxf(fmaf(vv[j] - mu, sc, bi), 0.0f);
    }
    uint2 o; o.x = pack2(r[0], r[1]); o.y = pack2(r[2], r[3]);
    ((uint2*)xb)[i] = o;
    xq[i] = pack_fp8x4(r[0], r[1], r[2], r[3]);
  }
  if (do_scores){
    #pragma unroll
    for (int j = 0; j < 8; j++) aw[tid + j*256] = attn_W[tid + j*256];
    if (tid < C) ab[tid] = attn_b[tid];
    int ln = tid >> 5;
    if (active){
      xs[ln][h+0]=r[0]; xs[ln][h+1]=r[1]; xs[ln][h+2]=r[2]; xs[ln][h+3]=r[3];
    }
    __syncthreads();
    if (tid < 128){
      int n2 = tid >> 4, c = tid & 15;
      int node = blockIdx.x*8 + n2;
      if (node < N){
        float acc = ab[c];
        #pragma unroll 4
        for (int k = 0; k < H; k++)
          acc = fmaf(xs[n2][k], aw[k*C + c], acc);
        escore[(size_t)node*C + c] = __expf(acc);
      }
    }
  }
}

__global__ __launch_bounds__(256) void k_denom(const float* __restrict__ escore,
    const int* __restrict__ gs, float* __restrict__ gsum){
  int g = blockIdx.x;
  int c = threadIdx.x & 15, sub = threadIdx.x >> 4;
  int a = gs[g], b = gs[g+1];
  float s = 0.f;
  for (int n = a + sub; n < b; n += 16) s += escore[(size_t)n*C + c];
  __shared__ float part[16][17];
  part[sub][c] = s;
  for (int off2 = 8; off2 > 0; off2 >>= 1){
    __syncthreads();
    if (sub < off2) part[sub][c] += part[sub + off2][c];
  }
  __syncthreads();
  if (threadIdx.x < C) gsum[(size_t)g*C + threadIdx.x] = part[0][threadIdx.x];
}

// partial[g][b][c][h] = strided-node partial of escore[n][c]*x[n][h]
__global__ __launch_bounds__(256) void k_clust(const u16* __restrict__ xb,
    const float* __restrict__ escore, const int* __restrict__ gs,
    float* __restrict__ partial){
  int g = blockIdx.x >> 4, b = blockIdx.x & 15;
  int h = threadIdx.x & 127, cg = threadIdx.x >> 7;
  int a = gs[g], e2 = gs[g+1];
  float acc[8] = {0,0,0,0,0,0,0,0};
  for (int n = a + b; n < e2; n += 16){
    float xv = bf2f(xb[(size_t)n*H + h]);
    const float4* ep = (const float4*)(escore + (size_t)n*C) + cg*2;
    float4 e0 = ep[0], e1 = ep[1];
    acc[0] = fmaf(e0.x, xv, acc[0]);
    acc[1] = fmaf(e0.y, xv, acc[1]);
    acc[2] = fmaf(e0.z, xv, acc[2]);
    acc[3] = fmaf(e0.w, xv, acc[3]);
    acc[4] = fmaf(e1.x, xv, acc[4]);
    acc[5] = fmaf(e1.y, xv, acc[5]);
    acc[6] = fmaf(e1.z, xv, acc[6]);
    acc[7] = fmaf(e1.w, xv, acc[7]);
  }
  int c0 = cg*8;
  float* dst = partial + (((size_t)(g*16 + b))*C)*H + h;
  #pragma unroll
  for (int r = 0; r < 8; r++)
    dst[(size_t)(c0 + r)*H] = acc[r];
}

__global__ __launch_bounds__(256) void k_out(const float* __restrict__ partial,
    const float* __restrict__ gsum, const float* __restrict__ out_W,
    const float* __restrict__ out_b, float* __restrict__ out){
  __shared__ float cs[2][128];
  int tid = threadIdx.x;
  int r = tid >> 7, h = tid & 127;
  int row = blockIdx.x*2 + r;          // (g,c) flat
  int g = row >> 4, c = row & 15;
  float s = 0.f;
  for (int b = 0; b < 16; b++)
    s += partial[(((size_t)(g*16 + b))*C + c)*H + h];
  cs[r][h] = s;
  __syncthreads();
  float gden = gsum[row];
  float inv = gden > 0.f ? 1.0f / gden : 0.f;
  float acc = 0.f;
  for (int hh = 0; hh < H; hh++)
    acc = fmaf(cs[r][hh], out_W[hh*ODIM + h], acc);
  out[(size_t)row*ODIM + h] = fmaf(acc, inv, out_b[h]);
}

// ---------------- host ----------------
extern "C" void kernel_launch(void* const* d_in, const int* in_sizes, int n_in,
                              void* d_out, int out_size, void* d_ws, size_t ws_size,
                              hipStream_t stream){
  const float* emb    = (const float*)d_in[0];
  const float* Wl     = (const float*)d_in[1];
  const float* bl     = (const float*)d_in[2];
  const float* Wr     = (const float*)d_in[3];
  const float* gamma  = (const float*)d_in[4];
  const float* beta   = (const float*)d_in[5];
  const float* attn_W = (const float*)d_in[6];
  const float* attn_b = (const float*)d_in[7];
  const float* out_W  = (const float*)d_in[8];
  const float* out_b  = (const float*)d_in[9];
  const int* deg    = (const int*)d_in[10];
  const int* ei     = (const int*)d_in[11];
  const int* batch  = (const int*)d_in[12];
  float* out = (float*)d_out;

  const int N = in_sizes[10];
  const int E = in_sizes[11] / 2;
  const int L = in_sizes[1] / (H*H);
  const int B = out_size / (C*ODIM);
  const int NB = (N + 127) >> 7;        // buckets of 128 nodes
  const int nbh = NB * NP;              // blkhist elements
  const int chunk = (E + NP - 1) / NP;  // edges per hist/place block
  const int nblkL = (N + 63) / 64;      // k_linear grid

  size_t off = 0;
  auto alloc = [&](size_t bytes) -> void* {
    void* p = (char*)d_ws + off;
    off += (bytes + 255) & ~(size_t)255;
    return p;
  };
  u16*   xb     = (u16*)  alloc((size_t)N*H*2);
  u32*   xq     = (u32*)  alloc((size_t)N*H);    // fp8 shadow of xb
  u16*   meanb  = (u16*)  alloc((size_t)N*H*2);
  float* x2     = (float*)alloc((size_t)N*H*4);  // aliased: pairs (CSR), partial (pooling)
  int2*  pairs  = (int2*)x2;
  float* partial= x2;
  u16*   Wt     = (u16*)  alloc((size_t)L*H*256*2);
  float* escore = (float*)alloc((size_t)N*C*4);
  int*   col    = (int*)  alloc((size_t)E*4);
  int*   rowptr = (int*)  alloc((size_t)(N+1)*4);
  int*   blkhist= (int*)  alloc((size_t)nbh*4);
  int*   bases  = (int*)  alloc((size_t)nbh*4);
  int*   bsum   = (int*)  alloc(256*4);
  int*   boff   = (int*)  alloc(256*4);
  int*   gs     = (int*)  alloc((size_t)(B+1)*4);
  float* gsum   = (float*)alloc((size_t)B*C*4);
  float* stats  = (float*)alloc((size_t)L*2*H*4);
  float* pstats = (float*)alloc((size_t)nblkL*256*4);

  // fused setup
  int g0 = (N*32 + 255)/256;            // embed blocks
  int g1 = g0 + (N + 255)/256;          // + bounds
  int g2 = g1 + L*16;                   // + wprep
  int gT = g2 + NP;                     // + hist
  hipLaunchKernelGGL(k_setup, dim3(gT), dim3(256), 0, stream,
                     emb, deg, xb, xq, batch, gs, Wl, Wr, Wt, ei, blkhist,
                     N, B, NB, E, chunk, g0, g1, g2);
  int nblkS = (nbh + 1023) / 1024;
  hipLaunchKernelGGL(k_scanA,  dim3(nblkS), dim3(256), 0, stream, blkhist, bases, bsum, nbh);
  hipLaunchKernelGGL(k_scanB,  dim3(1),     dim3(256), 0, stream, bsum, boff, nblkS);
  hipLaunchKernelGGL(k_scanC,  dim3((nbh+255)/256), dim3(256), 0, stream, bases, boff, nbh);
  hipLaunchKernelGGL(k_place,  dim3(NP), dim3(256), 0, stream, ei, bases, pairs, NB, E, chunk);
  hipLaunchKernelGGL(k_cnt_place, dim3(NB), dim3(256), 0, stream, pairs, bases, rowptr, col, NB, N, E);

  float invN = 1.0f / (float)N;
  for (int l = 0; l < L; l++){
    hipLaunchKernelGGL(k_agg,    dim3((N+3)/4),  dim3(256), 0, stream, xq, rowptr, col, meanb, N);
    hipLaunchKernelGGL(k_linear, dim3(nblkL),    dim3(256), 0, stream,
                       meanb, xb, Wt + (size_t)l*H*256, bl + (size_t)l*H, x2,
                       pstats, N);
    hipLaunchKernelGGL(k_statred,dim3(256),      dim3(256), 0, stream, pstats, stats + l*2*H, nblkL);
    hipLaunchKernelGGL(k_bnrelu, dim3((N*32+255)/256), dim3(256), 0, stream,
                       x2, stats + l*2*H, gamma + (size_t)l*H, beta + (size_t)l*H,
                       xb, xq, N, invN, attn_W, attn_b, escore, (l == L-1) ? 1 : 0);
  }
  hipLaunchKernelGGL(k_denom,  dim3(B),     dim3(256), 0, stream, escore, gs, gsum);
  hipLaunchKernelGGL(k_clust,  dim3(B*16),  dim3(256), 0, stream, xb, escore, gs, partial);
  hipLaunchKernelGGL(k_out,    dim3(B*C/2), dim3(256), 0, stream, partial, gsum, out_W, out_b, out);
}

// Round 10
// 334.019 us; speedup vs baseline: 2.4163x; 1.0103x over previous
//
#include <hip/hip_runtime.h>

typedef unsigned short u16;
typedef unsigned int   u32;

#define H    128
#define C    16
#define ODIM 128

typedef short bf16x8 __attribute__((ext_vector_type(8)));
typedef float f32x4  __attribute__((ext_vector_type(4)));
typedef float f32x2v __attribute__((ext_vector_type(2)));

#define WSP 272   // Ws row stride (u16)
#define NP  256   // CSR partitions

__device__ __forceinline__ float bf2f(u32 v){
  union { u32 i; float f; } t; t.i = v << 16; return t.f;
}
__device__ __forceinline__ u16 f2bf(float f){
  u32 u = __float_as_uint(f);
  u32 r = u + 0x7fffu + ((u >> 16) & 1u);   // RNE
  return (u16)(r >> 16);
}
__device__ __forceinline__ u32 pack2(float a, float b){
  return (u32)f2bf(a) | ((u32)f2bf(b) << 16);
}
__device__ __forceinline__ u32 pack_fp8x4(float a, float b, float c, float d){
  int p = __builtin_amdgcn_cvt_pk_fp8_f32(a, b, 0, false);
  p     = __builtin_amdgcn_cvt_pk_fp8_f32(c, d, p, true);
  return (u32)p;
}

// ---------------- fused setup: embed | bounds | wprep | hist ----------------
__global__ __launch_bounds__(256) void k_setup(const float* __restrict__ emb,
    const int* __restrict__ deg, u16* __restrict__ xb, u32* __restrict__ xq,
    const int* __restrict__ batch, int* __restrict__ gs,
    const float* __restrict__ Wl, const float* __restrict__ Wr,
    u16* __restrict__ Wt, const int* __restrict__ ei,
    int* __restrict__ blkhist, int N, int B, int NB, int E, int chunk,
    int g0, int g1, int g2){
  __shared__ __align__(16) char smem[4608];
  int bid = blockIdx.x, tid = threadIdx.x;
  if (bid < g0){
    // ---- embed ----
    int i = bid*256 + tid;
    if (i < N*32){
      int n = i >> 5, q = i & 31;
      int d = deg[n];
      float4 v = ((const float4*)(emb + (size_t)d*H))[q];
      uint2 o; o.x = pack2(v.x, v.y); o.y = pack2(v.z, v.w);
      ((uint2*)(xb + (size_t)n*H))[q] = o;
      xq[i] = pack_fp8x4(v.x, v.y, v.z, v.w);
    }
  } else if (bid < g1){
    // ---- bounds ----
    int n = (bid - g0)*256 + tid;
    if (n < N){
      int b = batch[n];
      if (n == 0){ for (int g = 0; g <= b; g++) gs[g] = 0; }
      else {
        int pb = batch[n-1];
        for (int g = pb+1; g <= b; g++) gs[g] = n;
      }
      if (n == N-1){ for (int g = b+1; g <= B; g++) gs[g] = N; }
    }
  } else if (bid < g2){
    // ---- wprep: Wt[l][h][k] ----
    u16 (*T)[18] = (u16(*)[18])smem;
    int b = bid - g1;
    int strip = b & 7, half = (b >> 3) & 1, l = b >> 4;
    const float* M = (half ? Wr : Wl) + (size_t)l*H*H;
    int k0 = strip * 16;
    #pragma unroll
    for (int j = 0; j < 8; j++){
      int u = tid + j*256;
      int kk = u >> 7, h = u & 127;
      T[h][kk] = f2bf(M[(size_t)(k0 + kk)*H + h]);
    }
    __syncthreads();
    #pragma unroll
    for (int j = 0; j < 8; j++){
      int u = tid + j*256;
      int h = u >> 4, k16 = u & 15;
      Wt[((size_t)(l*H + h))*256 + half*128 + k0 + k16] = T[h][k16];
    }
  } else {
    // ---- hist ----
    int* hist = (int*)smem;
    int blk = bid - g2;
    for (int b = tid; b < NB; b += 256) hist[b] = 0;
    __syncthreads();
    int start = blk*chunk, end = min(E, start + chunk);
    for (int e = start + tid; e < end; e += 256)
      atomicAdd(&hist[ei[E + e] >> 7], 1);
    __syncthreads();
    for (int b = tid; b < NB; b += 256) blkhist[b*NP + blk] = hist[b];
  }
}

// generic scan over n ints (1024 per block)
__global__ __launch_bounds__(256) void k_scanA(const int* __restrict__ in,
    int* __restrict__ out, int* __restrict__ bsum, int n){
  __shared__ int wsum[4];
  int tid = threadIdx.x;
  int base = blockIdx.x*1024 + tid*4;
  int v0 = (base+0 < n) ? in[base+0] : 0;
  int v1 = (base+1 < n) ? in[base+1] : 0;
  int v2 = (base+2 < n) ? in[base+2] : 0;
  int v3 = (base+3 < n) ? in[base+3] : 0;
  int tsum = v0+v1+v2+v3;
  int lane = tid & 63, w = tid >> 6;
  int incl = tsum;
  for (int d = 1; d < 64; d <<= 1){
    int t = __shfl_up(incl, d, 64);
    if (lane >= d) incl += t;
  }
  if (lane == 63) wsum[w] = incl;
  __syncthreads();
  int woff = 0;
  for (int i = 0; i < w; i++) woff += wsum[i];
  int excl = woff + incl - tsum;
  if (base+0 < n) out[base+0] = excl;
  if (base+1 < n) out[base+1] = excl + v0;
  if (base+2 < n) out[base+2] = excl + v0 + v1;
  if (base+3 < n) out[base+3] = excl + v0 + v1 + v2;
  if (tid == 255) bsum[blockIdx.x] = woff + incl;
}

// scan of up to 256 block sums
__global__ __launch_bounds__(256) void k_scanB(const int* __restrict__ bsum,
    int* __restrict__ boff, int nb){
  __shared__ int ws[4];
  int tid = threadIdx.x;
  int v = (tid < nb) ? bsum[tid] : 0;
  int lane = tid & 63, w = tid >> 6;
  int incl = v;
  for (int d = 1; d < 64; d <<= 1){
    int t = __shfl_up(incl, d, 64);
    if (lane >= d) incl += t;
  }
  if (lane == 63) ws[w] = incl;
  __syncthreads();
  int woff = 0;
  for (int i = 0; i < w; i++) woff += ws[i];
  boff[tid] = woff + incl - v;
}

// place edges bucket-sorted as (src,dst) pairs; boff folded into cursor init
__global__ __launch_bounds__(256) void k_place(const int* __restrict__ ei,
    const int* __restrict__ bases, const int* __restrict__ boff,
    int2* __restrict__ pairs, int NB, int E, int chunk){
  __shared__ int cursor[400];
  int blk = blockIdx.x, tid = threadIdx.x;
  for (int b = tid; b < NB; b += 256){
    int i = b*NP + blk;
    cursor[b] = bases[i] + boff[i >> 10];
  }
  __syncthreads();
  int start = blk*chunk, end = min(E, start + chunk);
  for (int e = start + tid; e < end; e += 256){
    int s = ei[e], d = ei[E + e];
    int pos = atomicAdd(&cursor[d >> 7], 1);
    pairs[pos] = make_int2(s, d);
  }
}

// per bucket: per-node counts -> rowptr (direct), then node-sort col
__global__ __launch_bounds__(256) void k_cnt_place(const int2* __restrict__ pairs,
    const int* __restrict__ bases, const int* __restrict__ boff,
    int* __restrict__ rowptr, int* __restrict__ col, int NB, int N, int E){
  int b = blockIdx.x, tid = threadIdx.x;
  int i0 = b*NP;
  int bstart = bases[i0] + boff[i0 >> 10];
  int bend = E;
  if (b+1 < NB){ int i1 = (b+1)*NP; bend = bases[i1] + boff[i1 >> 10]; }
  __shared__ int cnt[128], sc[128], rank[128];
  if (tid < 128) cnt[tid] = 0;
  __syncthreads();
  for (int e = bstart + tid; e < bend; e += 256)
    atomicAdd(&cnt[pairs[e].y & 127], 1);
  __syncthreads();
  if (tid < 128) sc[tid] = cnt[tid];
  for (int d = 1; d < 128; d <<= 1){
    int v = 0;
    __syncthreads();
    if (tid < 128 && tid >= d) v = sc[tid - d];
    __syncthreads();
    if (tid < 128) sc[tid] += v;
  }
  __syncthreads();
  if (tid < 128){
    int excl = sc[tid] - cnt[tid];
    rank[tid] = bstart + excl;
    int node = b*128 + tid;
    if (node < N) rowptr[node] = bstart + excl;
  }
  if (b == NB-1 && tid == 0) rowptr[N] = E;
  __syncthreads();
  for (int e = bstart + tid; e < bend; e += 256){
    int2 p = pairs[e];
    int pos = atomicAdd(&rank[p.y & 127], 1);
    col[pos] = p.x;
  }
}

// ---------------- per-layer ----------------
// wave per node; fp8 row = 128 B = 8 lanes x uint4 -> 8 edges per VMEM
// instruction (8 groups of 8 lanes), unroll 2 = 16 edges in flight.
// Lane covers features fl*16 .. fl*16+15.
__device__ __forceinline__ void dec16(float* a, uint4 v){
  f32x2v p;
  p = __builtin_amdgcn_cvt_pk_f32_fp8((int)v.x, false); a[0]+=p.x; a[1]+=p.y;
  p = __builtin_amdgcn_cvt_pk_f32_fp8((int)v.x, true ); a[2]+=p.x; a[3]+=p.y;
  p = __builtin_amdgcn_cvt_pk_f32_fp8((int)v.y, false); a[4]+=p.x; a[5]+=p.y;
  p = __builtin_amdgcn_cvt_pk_f32_fp8((int)v.y, true ); a[6]+=p.x; a[7]+=p.y;
  p = __builtin_amdgcn_cvt_pk_f32_fp8((int)v.z, false); a[8]+=p.x; a[9]+=p.y;
  p = __builtin_amdgcn_cvt_pk_f32_fp8((int)v.z, true ); a[10]+=p.x; a[11]+=p.y;
  p = __builtin_amdgcn_cvt_pk_f32_fp8((int)v.w, false); a[12]+=p.x; a[13]+=p.y;
  p = __builtin_amdgcn_cvt_pk_f32_fp8((int)v.w, true ); a[14]+=p.x; a[15]+=p.y;
}

__global__ __launch_bounds__(256) void k_agg(const u32* __restrict__ xq,
    const int* __restrict__ rowptr, const int* __restrict__ col,
    u16* __restrict__ meanb, int N){
  int wid  = (blockIdx.x*256 + threadIdx.x) >> 6;
  int lane = threadIdx.x & 63;
  if (wid >= N) return;
  int r0 = rowptr[wid], r1 = rowptr[wid+1];
  int grp = lane >> 3, fl = lane & 7;   // 8 groups x 8 lanes
  const u32* xf = xq + fl*4;            // 4 u32 = 16 fp8 features
  float a[16];
  #pragma unroll
  for (int j = 0; j < 16; j++) a[j] = 0.f;
  int e = r0 + grp;
  for (; e + 8 < r1; e += 16){
    uint4 v = *(const uint4*)(xf + (size_t)col[e]*32);
    uint4 u = *(const uint4*)(xf + (size_t)col[e+8]*32);
    dec16(a, v);
    dec16(a, u);
  }
  if (e < r1){
    uint4 v = *(const uint4*)(xf + (size_t)col[e]*32);
    dec16(a, v);
  }
  #pragma unroll
  for (int j = 0; j < 16; j++){
    a[j] += __shfl_xor(a[j], 8, 64);
    a[j] += __shfl_xor(a[j], 16, 64);
    a[j] += __shfl_xor(a[j], 32, 64);
  }
  if (grp == 0){
    float invc = 1.0f / (float)max(r1 - r0, 1);
    uint4 o0, o1;
    o0.x = pack2(a[0]*invc,  a[1]*invc);
    o0.y = pack2(a[2]*invc,  a[3]*invc);
    o0.z = pack2(a[4]*invc,  a[5]*invc);
    o0.w = pack2(a[6]*invc,  a[7]*invc);
    o1.x = pack2(a[8]*invc,  a[9]*invc);
    o1.y = pack2(a[10]*invc, a[11]*invc);
    o1.z = pack2(a[12]*invc, a[13]*invc);
    o1.w = pack2(a[14]*invc, a[15]*invc);
    u16* mp = meanb + (size_t)wid*H + fl*16;
    *(uint4*)mp       = o0;
    *(uint4*)(mp + 8) = o1;
  }
}

// x2[n][h] = bl[h] + [meanb|xb] @ Wt^T via mfma_f32_16x16x32_bf16.
// Wt staged whole in LDS; A-fragments direct from global. Fused BN-stat
// partials -> pstats[blk][256].
__global__ __launch_bounds__(256) void k_linear(const u16* __restrict__ meanb,
    const u16* __restrict__ xb, const u16* __restrict__ Wt,
    const float* __restrict__ bl, float* __restrict__ x2,
    float* __restrict__ pstats, int N){
  __shared__ u16 Ws[128][WSP];         // 69.6 KB -> 2 blocks/CU
  __shared__ float Sh[128], Qh[128];
  int tid = threadIdx.x;
  if (tid < 128){ Sh[tid] = 0.f; Qh[tid] = 0.f; }
  int lane = tid & 63, w = tid >> 6;
  int mlane = lane & 15, quad = lane >> 4;
  int node = blockIdx.x*64 + w*16 + mlane;
  const u16* arow_m = meanb + (size_t)node*H + quad*8;
  const u16* arow_x = xb   + (size_t)node*H + quad*8;
  bf16x8 af[8];
  #pragma unroll
  for (int kk = 0; kk < 4; kk++){
    af[kk]     = *(const bf16x8*)(arow_m + kk*32);
    af[kk + 4] = *(const bf16x8*)(arow_x + kk*32);
  }
  #pragma unroll
  for (int j = 0; j < 16; j++){
    int u = tid + j*256;
    int row = u >> 5, seg = u & 31;
    uint4 v = ((const uint4*)(Wt + (size_t)row*256))[seg];
    *(uint4*)&Ws[row][seg*8] = v;
  }
  __syncthreads();
  f32x4 acc[8];
  #pragma unroll
  for (int t = 0; t < 8; t++) acc[t] = (f32x4){0.f, 0.f, 0.f, 0.f};
  #pragma unroll
  for (int kk = 0; kk < 8; kk++){
    #pragma unroll
    for (int t = 0; t < 8; t++){
      bf16x8 b = *(const bf16x8*)&Ws[t*16 + mlane][kk*32 + quad*8];
      acc[t] = __builtin_amdgcn_mfma_f32_16x16x32_bf16(af[kk], b, acc[t], 0, 0, 0);
    }
  }
  #pragma unroll
  for (int t = 0; t < 8; t++){
    int h = t*16 + mlane;
    float bv = bl[h];
    float s = 0.f, q = 0.f;
    #pragma unroll
    for (int r = 0; r < 4; r++){
      int nd = blockIdx.x*64 + w*16 + quad*4 + r;
      if (nd < N){
        float v = acc[t][r] + bv;
        x2[(size_t)nd*H + h] = v;
        s += v; q = fmaf(v, v, q);
      }
    }
    s += __shfl_xor(s, 16, 64); s += __shfl_xor(s, 32, 64);
    q += __shfl_xor(q, 16, 64); q += __shfl_xor(q, 32, 64);
    if (quad == 0){
      atomicAdd(&Sh[h], s);
      atomicAdd(&Qh[h], q);
    }
  }
  __syncthreads();
  {
    float v = (tid < 128) ? Sh[tid] : Qh[tid - 128];
    pstats[(size_t)blockIdx.x*256 + tid] = v;
  }
}

// reduce pstats[nblk][256] -> stats[256]
__global__ __launch_bounds__(256) void k_statred(const float* __restrict__ pstats,
    float* __restrict__ stats, int nblk){
  __shared__ float red[4];
  int c = blockIdx.x, tid = threadIdx.x;
  float s = 0.f;
  for (int b = tid; b < nblk; b += 256)
    s += pstats[(size_t)b*256 + c];
  s += __shfl_xor(s, 1, 64);  s += __shfl_xor(s, 2, 64);
  s += __shfl_xor(s, 4, 64);  s += __shfl_xor(s, 8, 64);
  s += __shfl_xor(s, 16, 64); s += __shfl_xor(s, 32, 64);
  if ((tid & 63) == 0) red[tid >> 6] = s;
  __syncthreads();
  if (tid == 0) stats[c] = red[0] + red[1] + red[2] + red[3];
}

// BN+ReLU; writes xb (bf16) + xq (fp8 shadow for gather); when do_scores!=0
// also computes escore for this block's 8 nodes from LDS (fused k_scores).
__global__ __launch_bounds__(256) void k_bnrelu(const float* __restrict__ x2,
    const float* __restrict__ stats, const float* __restrict__ gamma,
    const float* __restrict__ beta, u16* __restrict__ xb, u32* __restrict__ xq,
    int N, float invN,
    const float* __restrict__ attn_W, const float* __restrict__ attn_b,
    float* __restrict__ escore, int do_scores){
  __shared__ float xs[8][132];
  __shared__ float aw[H*C];
  __shared__ float ab[C];
  int tid = threadIdx.x;
  int i = blockIdx.x*256 + tid;
  bool active = (i < N*32);
  int h = (tid & 31) * 4;
  float r[4] = {0.f, 0.f, 0.f, 0.f};
  if (active){
    float4 v = ((const float4*)x2)[i];
    float vv[4] = {v.x, v.y, v.z, v.w};
    #pragma unroll
    for (int j = 0; j < 4; j++){
      float mu  = stats[h+j] * invN;
      float var = fmaf(-mu, mu, stats[H + h + j] * invN);
      float sc  = rsqrtf(var + 1e-5f) * gamma[h+j];
      float bi  = beta[h+j];
      r[j] = fmaxf(fmaf(vv[j] - mu, sc, bi), 0.0f);
    }
    uint2 o; o.x = pack2(r[0], r[1]); o.y = pack2(r[2], r[3]);
    ((uint2*)xb)[i] = o;
    xq[i] = pack_fp8x4(r[0], r[1], r[2], r[3]);
  }
  if (do_scores){
    #pragma unroll
    for (int j = 0; j < 8; j++) aw[tid + j*256] = attn_W[tid + j*256];
    if (tid < C) ab[tid] = attn_b[tid];
    int ln = tid >> 5;
    if (active){
      xs[ln][h+0]=r[0]; xs[ln][h+1]=r[1]; xs[ln][h+2]=r[2]; xs[ln][h+3]=r[3];
    }
    __syncthreads();
    if (tid < 128){
      int n2 = tid >> 4, c = tid & 15;
      int node = blockIdx.x*8 + n2;
      if (node < N){
        float acc = ab[c];
        #pragma unroll 4
        for (int k = 0; k < H; k++)
          acc = fmaf(xs[n2][k], aw[k*C + c], acc);
        escore[(size_t)node*C + c] = __expf(acc);
      }
    }
  }
}

// partial[g][b][c][h] = strided-node partial of escore[n][c]*x[n][h]
__global__ __launch_bounds__(256) void k_clust(const u16* __restrict__ xb,
    const float* __restrict__ escore, const int* __restrict__ gs,
    float* __restrict__ partial){
  int g = blockIdx.x >> 4, b = blockIdx.x & 15;
  int h = threadIdx.x & 127, cg = threadIdx.x >> 7;
  int a = gs[g], e2 = gs[g+1];
  float acc[8] = {0,0,0,0,0,0,0,0};
  for (int n = a + b; n < e2; n += 16){
    float xv = bf2f(xb[(size_t)n*H + h]);
    const float4* ep = (const float4*)(escore + (size_t)n*C) + cg*2;
    float4 e0 = ep[0], e1 = ep[1];
    acc[0] = fmaf(e0.x, xv, acc[0]);
    acc[1] = fmaf(e0.y, xv, acc[1]);
    acc[2] = fmaf(e0.z, xv, acc[2]);
    acc[3] = fmaf(e0.w, xv, acc[3]);
    acc[4] = fmaf(e1.x, xv, acc[4]);
    acc[5] = fmaf(e1.y, xv, acc[5]);
    acc[6] = fmaf(e1.z, xv, acc[6]);
    acc[7] = fmaf(e1.w, xv, acc[7]);
  }
  int c0 = cg*8;
  float* dst = partial + (((size_t)(g*16 + b))*C)*H + h;
  #pragma unroll
  for (int r = 0; r < 8; r++)
    dst[(size_t)(c0 + r)*H] = acc[r];
}

// k_out with fused denom (sum of escore over the graph's nodes per cluster)
__global__ __launch_bounds__(256) void k_out(const float* __restrict__ partial,
    const float* __restrict__ escore, const int* __restrict__ gs,
    const float* __restrict__ out_W, const float* __restrict__ out_b,
    float* __restrict__ out){
  __shared__ float cs[2][128];
  __shared__ float dsum[4];
  int tid = threadIdx.x;
  int r = tid >> 7, h = tid & 127;
  int row = blockIdx.x*2 + r;          // (g,c) flat
  int g = row >> 4, c = row & 15;
  int a = gs[g], b2 = gs[g+1];
  // denom
  float s = 0.f;
  for (int n = a + h; n < b2; n += 128) s += escore[(size_t)n*C + c];
  s += __shfl_xor(s, 1, 64);  s += __shfl_xor(s, 2, 64);
  s += __shfl_xor(s, 4, 64);  s += __shfl_xor(s, 8, 64);
  s += __shfl_xor(s, 16, 64); s += __shfl_xor(s, 32, 64);
  if ((tid & 63) == 0) dsum[tid >> 6] = s;
  // cluster sum reduce
  float p = 0.f;
  for (int b = 0; b < 16; b++)
    p += partial[(((size_t)(g*16 + b))*C + c)*H + h];
  cs[r][h] = p;
  __syncthreads();
  float gden = dsum[r*2] + dsum[r*2 + 1];
  float inv = gden > 0.f ? 1.0f / gden : 0.f;
  float acc = 0.f;
  for (int hh = 0; hh < H; hh++)
    acc = fmaf(cs[r][hh], out_W[hh*ODIM + h], acc);
  out[(size_t)row*ODIM + h] = fmaf(acc, inv, out_b[h]);
}

// ---------------- host ----------------
extern "C" void kernel_launch(void* const* d_in, const int* in_sizes, int n_in,
                              void* d_out, int out_size, void* d_ws, size_t ws_size,
                              hipStream_t stream){
  const float* emb    = (const float*)d_in[0];
  const float* Wl     = (const float*)d_in[1];
  const float* bl     = (const float*)d_in[2];
  const float* Wr     = (const float*)d_in[3];
  const float* gamma  = (const float*)d_in[4];
  const float* beta   = (const float*)d_in[5];
  const float* attn_W = (const float*)d_in[6];
  const float* attn_b = (const float*)d_in[7];
  const float* out_W  = (const float*)d_in[8];
  const float* out_b  = (const float*)d_in[9];
  const int* deg    = (const int*)d_in[10];
  const int* ei     = (const int*)d_in[11];
  const int* batch  = (const int*)d_in[12];
  float* out = (float*)d_out;

  const int N = in_sizes[10];
  const int E = in_sizes[11] / 2;
  const int L = in_sizes[1] / (H*H);
  const int B = out_size / (C*ODIM);
  const int NB = (N + 127) >> 7;        // buckets of 128 nodes
  const int nbh = NB * NP;              // blkhist elements
  const int chunk = (E + NP - 1) / NP;  // edges per hist/place block
  const int nblkL = (N + 63) / 64;      // k_linear grid

  size_t off = 0;
  auto alloc = [&](size_t bytes) -> void* {
    void* p = (char*)d_ws + off;
    off += (bytes + 255) & ~(size_t)255;
    return p;
  };
  u16*   xb     = (u16*)  alloc((size_t)N*H*2);
  u32*   xq     = (u32*)  alloc((size_t)N*H);    // fp8 shadow of xb
  u16*   meanb  = (u16*)  alloc((size_t)N*H*2);
  float* x2     = (float*)alloc((size_t)N*H*4);  // aliased: pairs (CSR), partial (pooling)
  int2*  pairs  = (int2*)x2;
  float* partial= x2;
  u16*   Wt     = (u16*)  alloc((size_t)L*H*256*2);
  float* escore = (float*)alloc((size_t)N*C*4);
  int*   col    = (int*)  alloc((size_t)E*4);
  int*   rowptr = (int*)  alloc((size_t)(N+1)*4);
  int*   blkhist= (int*)  alloc((size_t)nbh*4);
  int*   bases  = (int*)  alloc((size_t)nbh*4);
  int*   bsum   = (int*)  alloc(256*4);
  int*   boff   = (int*)  alloc(256*4);
  int*   gs     = (int*)  alloc((size_t)(B+1)*4);
  float* stats  = (float*)alloc((size_t)L*2*H*4);
  float* pstats = (float*)alloc((size_t)nblkL*256*4);

  // fused setup
  int g0 = (N*32 + 255)/256;            // embed blocks
  int g1 = g0 + (N + 255)/256;          // + bounds
  int g2 = g1 + L*16;                   // + wprep
  int gT = g2 + NP;                     // + hist
  hipLaunchKernelGGL(k_setup, dim3(gT), dim3(256), 0, stream,
                     emb, deg, xb, xq, batch, gs, Wl, Wr, Wt, ei, blkhist,
                     N, B, NB, E, chunk, g0, g1, g2);
  int nblkS = (nbh + 1023) / 1024;
  hipLaunchKernelGGL(k_scanA,  dim3(nblkS), dim3(256), 0, stream, blkhist, bases, bsum, nbh);
  hipLaunchKernelGGL(k_scanB,  dim3(1),     dim3(256), 0, stream, bsum, boff, nblkS);
  hipLaunchKernelGGL(k_place,  dim3(NP), dim3(256), 0, stream, ei, bases, boff, pairs, NB, E, chunk);
  hipLaunchKernelGGL(k_cnt_place, dim3(NB), dim3(256), 0, stream, pairs, bases, boff, rowptr, col, NB, N, E);

  float invN = 1.0f / (float)N;
  for (int l = 0; l < L; l++){
    hipLaunchKernelGGL(k_agg,    dim3((N+3)/4),  dim3(256), 0, stream, xq, rowptr, col, meanb, N);
    hipLaunchKernelGGL(k_linear, dim3(nblkL),    dim3(256), 0, stream,
                       meanb, xb, Wt + (size_t)l*H*256, bl + (size_t)l*H, x2,
                       pstats, N);
    hipLaunchKernelGGL(k_statred,dim3(256),      dim3(256), 0, stream, pstats, stats + l*2*H, nblkL);
    hipLaunchKernelGGL(k_bnrelu, dim3((N*32+255)/256), dim3(256), 0, stream,
                       x2, stats + l*2*H, gamma + (size_t)l*H, beta + (size_t)l*H,
                       xb, xq, N, invN, attn_W, attn_b, escore, (l == L-1) ? 1 : 0);
  }
  hipLaunchKernelGGL(k_clust,  dim3(B*16),  dim3(256), 0, stream, xb, escore, gs, partial);
  hipLaunchKernelGGL(k_out,    dim3(B*C/2), dim3(256), 0, stream, partial, escore, gs, out_W, out_b, out);
}